// Round 1
// baseline (477.610 us; speedup 1.0000x reference)
//
#include <hip/hip_runtime.h>
#include <hip/hip_bf16.h>

typedef __attribute__((ext_vector_type(8))) short s16x8;
typedef __attribute__((ext_vector_type(4))) float f32x4;
typedef __hip_bfloat16 bf16_t;

// ---------------------------------------------------------------- helpers
__device__ __forceinline__ void gload_lds16(const void* g, void* l) {
  __builtin_amdgcn_global_load_lds(
      (__attribute__((address_space(1))) void*)(g),
      (__attribute__((address_space(3))) void*)(l), 16, 0, 0);
}

// ---------------------------------------------------------------- weight prep
__global__ void cast_bf16_k(const float* __restrict__ x, bf16_t* __restrict__ y, int n) {
  int i = (blockIdx.x * 256 + threadIdx.x) * 8;
  if (i >= n) return;
  float4 a = *(const float4*)(x + i);
  float4 b = *(const float4*)(x + i + 4);
  union { bf16_t h[8]; s16x8 v; } u;
  u.h[0] = __float2bfloat16(a.x); u.h[1] = __float2bfloat16(a.y);
  u.h[2] = __float2bfloat16(a.z); u.h[3] = __float2bfloat16(a.w);
  u.h[4] = __float2bfloat16(b.x); u.h[5] = __float2bfloat16(b.y);
  u.h[6] = __float2bfloat16(b.z); u.h[7] = __float2bfloat16(b.w);
  *(s16x8*)(y + i) = u.v;
}

// Wk_red[d][:] = sum_h Wqkv[1024+h*64+d][:]; likewise Wv_red from rows 2048+.
// Output rows appended after the 1024 q rows of Wqkv_bf (contiguous 1152xK).
__global__ void reduce_kv_k(const float* __restrict__ Wqkv, bf16_t* __restrict__ Wred) {
  int d   = blockIdx.x & 63;
  int isv = blockIdx.x >> 6;            // 0 = k, 1 = v
  int col = threadIdx.x * 4;
  const float* base = Wqkv + (size_t)(1024 + isv * 1024 + d) * 1024 + col;
  float4 s = {0.f, 0.f, 0.f, 0.f};
#pragma unroll
  for (int h = 0; h < 16; ++h) {
    float4 t = *(const float4*)(base + (size_t)h * 64 * 1024);
    s.x += t.x; s.y += t.y; s.z += t.z; s.w += t.w;
  }
  union { bf16_t h[4]; uint2 u; } o;
  o.h[0] = __float2bfloat16(s.x); o.h[1] = __float2bfloat16(s.y);
  o.h[2] = __float2bfloat16(s.z); o.h[3] = __float2bfloat16(s.w);
  *(uint2*)(Wred + (size_t)(isv * 64 + d) * 1024 + col) = o.u;
}

__global__ void bias_prep_k(const float* __restrict__ bqkv, float* __restrict__ br) {
  int i = blockIdx.x * 256 + threadIdx.x;
  if (i >= 1152) return;
  if (i < 1024) { br[i] = bqkv[i]; return; }
  int d = i - 1024;
  int off = (d < 64) ? (1024 + d) : (2048 + (d - 64));
  float s = 0.f;
#pragma unroll
  for (int h = 0; h < 16; ++h) s += bqkv[off + h * 64];
  br[i] = s;
}

// ---------------------------------------------------------------- layernorm + cast
__global__ __launch_bounds__(256) void ln_cast_k(const float* __restrict__ x,
                                                 const float* __restrict__ g,
                                                 const float* __restrict__ bb,
                                                 bf16_t* __restrict__ y) {
  int row = blockIdx.x, tid = threadIdx.x;
  float4 v = *(const float4*)(x + (size_t)row * 1024 + tid * 4);
  float s = v.x + v.y + v.z + v.w;
  float q = v.x * v.x + v.y * v.y + v.z * v.z + v.w * v.w;
#pragma unroll
  for (int off = 1; off < 64; off <<= 1) {
    s += __shfl_xor(s, off, 64);
    q += __shfl_xor(q, off, 64);
  }
  __shared__ float ss[4], qq[4];
  int wave = tid >> 6, lane = tid & 63;
  if (lane == 0) { ss[wave] = s; qq[wave] = q; }
  __syncthreads();
  s = ss[0] + ss[1] + ss[2] + ss[3];
  q = qq[0] + qq[1] + qq[2] + qq[3];
  float mu  = s * (1.0f / 1024.0f);
  float var = q * (1.0f / 1024.0f) - mu * mu;
  float rstd = rsqrtf(var + 1e-5f);
  float4 gg = *(const float4*)(g + tid * 4);
  float4 bv = *(const float4*)(bb + tid * 4);
  union { bf16_t h[4]; uint2 u; } o;
  o.h[0] = __float2bfloat16((v.x - mu) * rstd * gg.x + bv.x);
  o.h[1] = __float2bfloat16((v.y - mu) * rstd * gg.y + bv.y);
  o.h[2] = __float2bfloat16((v.z - mu) * rstd * gg.z + bv.z);
  o.h[3] = __float2bfloat16((v.w - mu) * rstd * gg.w + bv.w);
  *(uint2*)(y + (size_t)row * 1024 + tid * 4) = o.u;
}

// ---------------------------------------------------------------- GEMM (m97 structure)
// C[M][N] = A[M][K](bf16) @ Bw[N][K](bf16)^T + bias, epilogue per EPI.
// EPI 0: QKV split  (q bf16 [row][col<1024]; ksum [b][t][d]; vT [b][d][t])
// EPI 1: f32 out += resid (residual write)
// EPI 2: tanh -> bf16
// EPI 3: f32 out
template <int EPI>
__global__ __launch_bounds__(256) void gemm_bt(
    const bf16_t* __restrict__ A, const bf16_t* __restrict__ Bw,
    const float* __restrict__ bias, void* __restrict__ out0,
    const float* __restrict__ resid, bf16_t* __restrict__ oks,
    bf16_t* __restrict__ ovt, int M, int N, int K) {
  __shared__ __align__(16) bf16_t As[128 * 32];
  __shared__ __align__(16) bf16_t Bs[128 * 32];
  const int tid  = threadIdx.x;
  const int lane = tid & 63;
  const int wave = tid >> 6;
  const int l15 = lane & 15, lg = lane >> 4;
  const int wr = (wave >> 1) * 64, wc = (wave & 1) * 64;
  const int bm = blockIdx.y * 128, bn = blockIdx.x * 128;
  const size_t Kz = (size_t)K;
  const int srow = lane >> 2;        // 0..15
  const int scol = (lane & 3) * 8;   // 0,8,16,24

  f32x4 acc[4][4];
#pragma unroll
  for (int m = 0; m < 4; ++m)
#pragma unroll
    for (int n = 0; n < 4; ++n) acc[m][n] = (f32x4){0.f, 0.f, 0.f, 0.f};

  const bf16_t* Ab = A + (size_t)bm * Kz;
  const bf16_t* Bb = Bw + (size_t)bn * Kz;

  for (int k0 = 0; k0 < K; k0 += 32) {
    __syncthreads();
#pragma unroll
    for (int j = 0; j < 2; ++j) {
      const int cw = wave * 2 + j;
      gload_lds16(Ab + (size_t)(cw * 16 + srow) * Kz + k0 + scol, As + cw * 512);
      gload_lds16(Bb + (size_t)(cw * 16 + srow) * Kz + k0 + scol, Bs + cw * 512);
    }
    __syncthreads();  // compiler drains vmcnt before barrier -> LDS tiles ready
    s16x8 af[4], bfv[4];
#pragma unroll
    for (int m = 0; m < 4; ++m)
      af[m] = *(const s16x8*)&As[(wr + m * 16 + l15) * 32 + lg * 8];
#pragma unroll
    for (int n = 0; n < 4; ++n)
      bfv[n] = *(const s16x8*)&Bs[(wc + n * 16 + l15) * 32 + lg * 8];
#pragma unroll
    for (int m = 0; m < 4; ++m)
#pragma unroll
      for (int n = 0; n < 4; ++n)
        acc[m][n] = __builtin_amdgcn_mfma_f32_16x16x32_bf16(af[m], bfv[n], acc[m][n], 0, 0, 0);
  }

#pragma unroll
  for (int m = 0; m < 4; ++m) {
    const int row0 = bm + wr + m * 16 + lg * 4;
#pragma unroll
    for (int n = 0; n < 4; ++n) {
      const int col = bn + wc + n * 16 + l15;
      const float bcol = bias[col];
#pragma unroll
      for (int r = 0; r < 4; ++r) {
        const int rw = row0 + r;
        float c = acc[m][n][r] + bcol;
        if constexpr (EPI == 0) {
          if (col < 1024) {
            ((bf16_t*)out0)[(size_t)rw * 1024 + col] = __float2bfloat16(c);
          } else if (col < 1088) {
            int d = col - 1024, b = rw >> 11, t = rw & 2047;
            oks[((size_t)(b << 11) + t) * 64 + d] = __float2bfloat16(c);
          } else {
            int d = col - 1088, b = rw >> 11, t = rw & 2047;
            ovt[((size_t)b * 64 + d) * 2048 + t] = __float2bfloat16(c);
          }
        } else if constexpr (EPI == 1) {
          ((float*)out0)[(size_t)rw * N + col] = c + resid[(size_t)rw * N + col];
        } else if constexpr (EPI == 2) {
          ((bf16_t*)out0)[(size_t)rw * N + col] = __float2bfloat16(tanhf(c));
        } else {
          ((float*)out0)[(size_t)rw * N + col] = c;
        }
      }
    }
  }
}

// ---------------------------------------------------------------- flash attention
// Per block: one (b, h, 64-row s-tile). 4 waves x 16 rows. K/V shared across h.
__global__ __launch_bounds__(256) void attn_k(const bf16_t* __restrict__ q,
                                              const bf16_t* __restrict__ ksp,
                                              const bf16_t* __restrict__ vtp,
                                              bf16_t* __restrict__ o) {
  __shared__ __align__(16) bf16_t Plds[4][16][72];
  const int tid = threadIdx.x, lane = tid & 63, wave = tid >> 6;
  const int l15 = lane & 15, lg = lane >> 4;
  const int sb = blockIdx.x & 31;
  const int h  = (blockIdx.x >> 5) & 15;
  const int b  = blockIdx.x >> 9;
  const int srow_wave = sb * 64 + wave * 16;

  s16x8 qf[2];
  {
    const size_t qoff = (size_t)(b * 2048 + srow_wave + l15) * 1024 + h * 64;
    qf[0] = *(const s16x8*)(q + qoff + lg * 8);
    qf[1] = *(const s16x8*)(q + qoff + 32 + lg * 8);
  }

  float m_run[4] = {-1e30f, -1e30f, -1e30f, -1e30f};
  float l_run[4] = {0.f, 0.f, 0.f, 0.f};
  f32x4 ao[4];
#pragma unroll
  for (int n = 0; n < 4; ++n) ao[n] = (f32x4){0.f, 0.f, 0.f, 0.f};

  const bf16_t* ksb = ksp + (size_t)b * 2048 * 64;
  const bf16_t* vtb = vtp + (size_t)b * 64 * 2048;
  const int ntiles = sb + 1;

  for (int tt = 0; tt < ntiles; ++tt) {
    const int t0 = tt * 64;
    f32x4 sc[4];
#pragma unroll
    for (int n = 0; n < 4; ++n) sc[n] = (f32x4){0.f, 0.f, 0.f, 0.f};
#pragma unroll
    for (int ks2 = 0; ks2 < 2; ++ks2) {
#pragma unroll
      for (int n = 0; n < 4; ++n) {
        s16x8 kf = *(const s16x8*)(ksb + (size_t)(t0 + n * 16 + l15) * 64 + ks2 * 32 + lg * 8);
        sc[n] = __builtin_amdgcn_mfma_f32_16x16x32_bf16(qf[ks2], kf, sc[n], 0, 0, 0);
      }
    }
    // scale + causal mask + row max (rows spread over 16-lane groups)
    float pv[4][4];
    float mx[4] = {-1e30f, -1e30f, -1e30f, -1e30f};
    const int sg = srow_wave + lg * 4;
#pragma unroll
    for (int n = 0; n < 4; ++n) {
      const int tg = t0 + n * 16 + l15;
#pragma unroll
      for (int r = 0; r < 4; ++r) {
        float v = sc[n][r] * 0.125f;
        if (tg > sg + r) v = -1e30f;
        pv[n][r] = v;
        mx[r] = fmaxf(mx[r], v);
      }
    }
#pragma unroll
    for (int r = 0; r < 4; ++r) {
#pragma unroll
      for (int off = 1; off < 16; off <<= 1) mx[r] = fmaxf(mx[r], __shfl_xor(mx[r], off, 64));
    }
#pragma unroll
    for (int r = 0; r < 4; ++r) {
      float mn = fmaxf(m_run[r], mx[r]);
      float alpha = __expf(m_run[r] - mn);
      m_run[r] = mn;
      float srow = 0.f;
#pragma unroll
      for (int n = 0; n < 4; ++n) {
        float e = __expf(pv[n][r] - mn);
        pv[n][r] = e;
        srow += e;
      }
#pragma unroll
      for (int off = 1; off < 16; off <<= 1) srow += __shfl_xor(srow, off, 64);
      l_run[r] = l_run[r] * alpha + srow;
#pragma unroll
      for (int n2 = 0; n2 < 4; ++n2) ao[n2][r] *= alpha;
    }
    // P -> per-wave-private LDS (A-operand layout for PV)
#pragma unroll
    for (int n = 0; n < 4; ++n)
#pragma unroll
      for (int r = 0; r < 4; ++r)
        Plds[wave][lg * 4 + r][n * 16 + l15] = __float2bfloat16(pv[n][r]);
#pragma unroll
    for (int ks2 = 0; ks2 < 2; ++ks2) {
      s16x8 pa = *(const s16x8*)&Plds[wave][l15][ks2 * 32 + lg * 8];
#pragma unroll
      for (int n2 = 0; n2 < 4; ++n2) {
        s16x8 vf = *(const s16x8*)(vtb + (size_t)(n2 * 16 + l15) * 2048 + t0 + ks2 * 32 + lg * 8);
        ao[n2] = __builtin_amdgcn_mfma_f32_16x16x32_bf16(pa, vf, ao[n2], 0, 0, 0);
      }
    }
  }
#pragma unroll
  for (int n2 = 0; n2 < 4; ++n2) {
    const int col = h * 64 + n2 * 16 + l15;
#pragma unroll
    for (int r = 0; r < 4; ++r) {
      const int row = b * 2048 + srow_wave + lg * 4 + r;
      o[(size_t)row * 1024 + col] = __float2bfloat16(ao[n2][r] / l_run[r]);
    }
  }
}

// ---------------------------------------------------------------- launch
extern "C" void kernel_launch(void* const* d_in, const int* in_sizes, int n_in,
                              void* d_out, int out_size, void* d_ws, size_t ws_size,
                              hipStream_t stream) {
  (void)in_sizes; (void)n_in; (void)out_size; (void)ws_size;
  const float* hidden = (const float*)d_in[0];
  const float* Wqkv   = (const float*)d_in[1];
  const float* bqkv   = (const float*)d_in[2];
  const float* Wout   = (const float*)d_in[3];
  const float* bout   = (const float*)d_in[4];
  const float* g1     = (const float*)d_in[5];
  const float* b1     = (const float*)d_in[6];
  const float* g2     = (const float*)d_in[7];
  const float* b2     = (const float*)d_in[8];
  const float* W1     = (const float*)d_in[9];
  const float* bfc1   = (const float*)d_in[10];
  const float* W2     = (const float*)d_in[11];
  const float* bfc2   = (const float*)d_in[12];

  float* out_h   = (float*)d_out;
  float* out_res = out_h + (size_t)4096 * 1024;

  char* ws = (char*)d_ws;
  auto alloc = [&](size_t bytes) {
    char* p = ws;
    ws += (bytes + 255) & ~(size_t)255;
    return p;
  };
  bf16_t* X1      = (bf16_t*)alloc((size_t)4096 * 1024 * 2);
  bf16_t* Wqkv_bf = (bf16_t*)alloc((size_t)1152 * 1024 * 2);  // [q(1024); k_red(64); v_red(64)] x 1024
  float*  bias_r  = (float*)alloc(1152 * 4);
  bf16_t* qb      = (bf16_t*)alloc((size_t)4096 * 1024 * 2);
  bf16_t* ksum    = (bf16_t*)alloc((size_t)2 * 2048 * 64 * 2);
  bf16_t* vT      = (bf16_t*)alloc((size_t)2 * 64 * 2048 * 2);
  bf16_t* Ob      = (bf16_t*)alloc((size_t)4096 * 1024 * 2);
  bf16_t* Wout_bf = (bf16_t*)alloc((size_t)1024 * 1024 * 2);
  bf16_t* X2      = (bf16_t*)alloc((size_t)4096 * 1024 * 2);
  bf16_t* W1_bf   = (bf16_t*)alloc((size_t)4096 * 1024 * 2);
  bf16_t* W2_bf   = (bf16_t*)alloc((size_t)1024 * 4096 * 2);
  bf16_t* H1      = (bf16_t*)alloc((size_t)4096 * 4096 * 2);

  // weight prep
  cast_bf16_k<<<512,  256, 0, stream>>>(Wqkv, Wqkv_bf, 1024 * 1024);  // q rows only
  cast_bf16_k<<<512,  256, 0, stream>>>(Wout, Wout_bf, 1024 * 1024);
  cast_bf16_k<<<2048, 256, 0, stream>>>(W1, W1_bf, 4096 * 1024);
  cast_bf16_k<<<2048, 256, 0, stream>>>(W2, W2_bf, 1024 * 4096);
  reduce_kv_k<<<128, 256, 0, stream>>>(Wqkv, Wqkv_bf + (size_t)1024 * 1024);
  bias_prep_k<<<5, 256, 0, stream>>>(bqkv, bias_r);

  // LN1
  ln_cast_k<<<4096, 256, 0, stream>>>(hidden, g1, b1, X1);
  // QKV (reduced): M=4096, N=1152, K=1024
  gemm_bt<0><<<dim3(9, 32), 256, 0, stream>>>(X1, Wqkv_bf, bias_r, qb, nullptr, ksum, vT,
                                              4096, 1152, 1024);
  // attention
  attn_k<<<1024, 256, 0, stream>>>(qb, ksum, vT, Ob);
  // Wout + residual -> out_res (f32)
  gemm_bt<1><<<dim3(8, 32), 256, 0, stream>>>(Ob, Wout_bf, bout, out_res, hidden, nullptr,
                                              nullptr, 4096, 1024, 1024);
  // LN2
  ln_cast_k<<<4096, 256, 0, stream>>>(out_res, g2, b2, X2);
  // FC1 + tanh
  gemm_bt<2><<<dim3(32, 32), 256, 0, stream>>>(X2, W1_bf, bfc1, H1, nullptr, nullptr, nullptr,
                                               4096, 4096, 1024);
  // FC2 -> out_h (f32)
  gemm_bt<3><<<dim3(8, 32), 256, 0, stream>>>(H1, W2_bf, bfc2, out_h, nullptr, nullptr, nullptr,
                                              4096, 1024, 4096);
}

// Round 2
// 387.521 us; speedup vs baseline: 1.2325x; 1.2325x over previous
//
#include <hip/hip_runtime.h>
#include <hip/hip_bf16.h>

typedef __attribute__((ext_vector_type(8))) short s16x8;
typedef __attribute__((ext_vector_type(4))) float f32x4;
typedef __hip_bfloat16 bf16_t;

// ---------------------------------------------------------------- helpers
__device__ __forceinline__ void gload_lds16(const void* g, void* l) {
  __builtin_amdgcn_global_load_lds(
      (__attribute__((address_space(1))) void*)(g),
      (__attribute__((address_space(3))) void*)(l), 16, 0, 0);
}

// ---------------------------------------------------------------- weight prep
__global__ void cast_bf16_k(const float* __restrict__ x, bf16_t* __restrict__ y, int n) {
  int i = (blockIdx.x * 256 + threadIdx.x) * 8;
  if (i >= n) return;
  float4 a = *(const float4*)(x + i);
  float4 b = *(const float4*)(x + i + 4);
  union { bf16_t h[8]; s16x8 v; } u;
  u.h[0] = __float2bfloat16(a.x); u.h[1] = __float2bfloat16(a.y);
  u.h[2] = __float2bfloat16(a.z); u.h[3] = __float2bfloat16(a.w);
  u.h[4] = __float2bfloat16(b.x); u.h[5] = __float2bfloat16(b.y);
  u.h[6] = __float2bfloat16(b.z); u.h[7] = __float2bfloat16(b.w);
  *(s16x8*)(y + i) = u.v;
}

// Wk_red[d][:] = sum_h Wqkv[1024+h*64+d][:]; likewise Wv_red from rows 2048+.
__global__ void reduce_kv_k(const float* __restrict__ Wqkv, bf16_t* __restrict__ Wred) {
  int d   = blockIdx.x & 63;
  int isv = blockIdx.x >> 6;            // 0 = k, 1 = v
  int col = threadIdx.x * 4;
  const float* base = Wqkv + (size_t)(1024 + isv * 1024 + d) * 1024 + col;
  float4 s = {0.f, 0.f, 0.f, 0.f};
#pragma unroll
  for (int h = 0; h < 16; ++h) {
    float4 t = *(const float4*)(base + (size_t)h * 64 * 1024);
    s.x += t.x; s.y += t.y; s.z += t.z; s.w += t.w;
  }
  union { bf16_t h[4]; uint2 u; } o;
  o.h[0] = __float2bfloat16(s.x); o.h[1] = __float2bfloat16(s.y);
  o.h[2] = __float2bfloat16(s.z); o.h[3] = __float2bfloat16(s.w);
  *(uint2*)(Wred + (size_t)(isv * 64 + d) * 1024 + col) = o.u;
}

__global__ void bias_prep_k(const float* __restrict__ bqkv, float* __restrict__ br) {
  int i = blockIdx.x * 256 + threadIdx.x;
  if (i >= 1152) return;
  if (i < 1024) { br[i] = bqkv[i]; return; }
  int d = i - 1024;
  int off = (d < 64) ? (1024 + d) : (2048 + (d - 64));
  float s = 0.f;
#pragma unroll
  for (int h = 0; h < 16; ++h) s += bqkv[off + h * 64];
  br[i] = s;
}

// ---------------------------------------------------------------- layernorm + cast
__global__ __launch_bounds__(256) void ln_cast_k(const float* __restrict__ x,
                                                 const float* __restrict__ g,
                                                 const float* __restrict__ bb,
                                                 bf16_t* __restrict__ y) {
  int row = blockIdx.x, tid = threadIdx.x;
  float4 v = *(const float4*)(x + (size_t)row * 1024 + tid * 4);
  float s = v.x + v.y + v.z + v.w;
  float q = v.x * v.x + v.y * v.y + v.z * v.z + v.w * v.w;
#pragma unroll
  for (int off = 1; off < 64; off <<= 1) {
    s += __shfl_xor(s, off, 64);
    q += __shfl_xor(q, off, 64);
  }
  __shared__ float ss[4], qq[4];
  int wave = tid >> 6, lane = tid & 63;
  if (lane == 0) { ss[wave] = s; qq[wave] = q; }
  __syncthreads();
  s = ss[0] + ss[1] + ss[2] + ss[3];
  q = qq[0] + qq[1] + qq[2] + qq[3];
  float mu  = s * (1.0f / 1024.0f);
  float var = q * (1.0f / 1024.0f) - mu * mu;
  float rstd = rsqrtf(var + 1e-5f);
  float4 gg = *(const float4*)(g + tid * 4);
  float4 bv = *(const float4*)(bb + tid * 4);
  union { bf16_t h[4]; uint2 u; } o;
  o.h[0] = __float2bfloat16((v.x - mu) * rstd * gg.x + bv.x);
  o.h[1] = __float2bfloat16((v.y - mu) * rstd * gg.y + bv.y);
  o.h[2] = __float2bfloat16((v.z - mu) * rstd * gg.z + bv.z);
  o.h[3] = __float2bfloat16((v.w - mu) * rstd * gg.w + bv.w);
  *(uint2*)(y + (size_t)row * 1024 + tid * 4) = o.u;
}

// ---------------------------------------------------------------- GEMM (m97 structure)
template <int EPI>
__global__ __launch_bounds__(256) void gemm_bt(
    const bf16_t* __restrict__ A, const bf16_t* __restrict__ Bw,
    const float* __restrict__ bias, void* __restrict__ out0,
    const float* __restrict__ resid, bf16_t* __restrict__ oks,
    bf16_t* __restrict__ ovt, int M, int N, int K) {
  __shared__ __align__(16) bf16_t As[128 * 32];
  __shared__ __align__(16) bf16_t Bs[128 * 32];
  const int tid  = threadIdx.x;
  const int lane = tid & 63;
  const int wave = tid >> 6;
  const int l15 = lane & 15, lg = lane >> 4;
  const int wr = (wave >> 1) * 64, wc = (wave & 1) * 64;
  const int bm = blockIdx.y * 128, bn = blockIdx.x * 128;
  const size_t Kz = (size_t)K;
  const int srow = lane >> 2;        // 0..15
  const int scol = (lane & 3) * 8;   // 0,8,16,24

  f32x4 acc[4][4];
#pragma unroll
  for (int m = 0; m < 4; ++m)
#pragma unroll
    for (int n = 0; n < 4; ++n) acc[m][n] = (f32x4){0.f, 0.f, 0.f, 0.f};

  const bf16_t* Ab = A + (size_t)bm * Kz;
  const bf16_t* Bb = Bw + (size_t)bn * Kz;

  for (int k0 = 0; k0 < K; k0 += 32) {
    __syncthreads();
#pragma unroll
    for (int j = 0; j < 2; ++j) {
      const int cw = wave * 2 + j;
      gload_lds16(Ab + (size_t)(cw * 16 + srow) * Kz + k0 + scol, As + cw * 512);
      gload_lds16(Bb + (size_t)(cw * 16 + srow) * Kz + k0 + scol, Bs + cw * 512);
    }
    __syncthreads();
    s16x8 af[4], bfv[4];
#pragma unroll
    for (int m = 0; m < 4; ++m)
      af[m] = *(const s16x8*)&As[(wr + m * 16 + l15) * 32 + lg * 8];
#pragma unroll
    for (int n = 0; n < 4; ++n)
      bfv[n] = *(const s16x8*)&Bs[(wc + n * 16 + l15) * 32 + lg * 8];
#pragma unroll
    for (int m = 0; m < 4; ++m)
#pragma unroll
      for (int n = 0; n < 4; ++n)
        acc[m][n] = __builtin_amdgcn_mfma_f32_16x16x32_bf16(af[m], bfv[n], acc[m][n], 0, 0, 0);
  }

#pragma unroll
  for (int m = 0; m < 4; ++m) {
    const int row0 = bm + wr + m * 16 + lg * 4;
#pragma unroll
    for (int n = 0; n < 4; ++n) {
      const int col = bn + wc + n * 16 + l15;
      const float bcol = bias[col];
#pragma unroll
      for (int r = 0; r < 4; ++r) {
        const int rw = row0 + r;
        float c = acc[m][n][r] + bcol;
        if constexpr (EPI == 0) {
          if (col < 1024) {
            ((bf16_t*)out0)[(size_t)rw * 1024 + col] = __float2bfloat16(c);
          } else if (col < 1088) {
            int d = col - 1024, b = rw >> 11, t = rw & 2047;
            oks[((size_t)(b << 11) + t) * 64 + d] = __float2bfloat16(c);
          } else {
            int d = col - 1088, b = rw >> 11, t = rw & 2047;
            ovt[((size_t)b * 64 + d) * 2048 + t] = __float2bfloat16(c);
          }
        } else if constexpr (EPI == 1) {
          ((float*)out0)[(size_t)rw * N + col] = c + resid[(size_t)rw * N + col];
        } else if constexpr (EPI == 2) {
          ((bf16_t*)out0)[(size_t)rw * N + col] = __float2bfloat16(tanhf(c));
        } else {
          ((float*)out0)[(size_t)rw * N + col] = c;
        }
      }
    }
  }
}

// ---------------------------------------------------------------- flash attention
// Merged-head form: per batch, rows r = s*16+h give A = q[32768][64] contiguous,
// O same layout. One wave = one 16-row fragment = 16 heads at ONE s-position ->
// causal limit uniform per fragment. Each wave handles the complementary pair
// (p, 2047-p): exactly 2049 t-columns per wave -> perfect balance, no drain.
// P kept in wave-private LDS (stride 136 bf16 spreads b128 reads over banks).

template <int NJ, bool MASK>
__device__ __forceinline__ void attn_step(
    int t0, int p, const s16x8 (&qf)[2],
    const bf16_t* __restrict__ ksb, const bf16_t* __restrict__ vtb,
    bf16_t* __restrict__ Pl, int l15, int lg,
    float (&m_run)[4], float (&l_run)[4], f32x4 (&ao)[4]) {
  f32x4 sc[NJ][4];
#pragma unroll
  for (int j = 0; j < NJ; ++j)
#pragma unroll
    for (int n = 0; n < 4; ++n) sc[j][n] = (f32x4){0.f, 0.f, 0.f, 0.f};

  // QK^T: A = q rows (16 heads), B = k_sum rows (t)
#pragma unroll
  for (int j = 0; j < NJ; ++j)
#pragma unroll
    for (int ks2 = 0; ks2 < 2; ++ks2)
#pragma unroll
      for (int n = 0; n < 4; ++n) {
        s16x8 kf = *(const s16x8*)(ksb + (size_t)(t0 + j * 64 + n * 16 + l15) * 64 + ks2 * 32 + lg * 8);
        sc[j][n] = __builtin_amdgcn_mfma_f32_16x16x32_bf16(qf[ks2], kf, sc[j][n], 0, 0, 0);
      }

  // scale (+uniform causal mask on the final partial tile), row max
  float mx[4] = {-1e30f, -1e30f, -1e30f, -1e30f};
#pragma unroll
  for (int j = 0; j < NJ; ++j)
#pragma unroll
    for (int n = 0; n < 4; ++n) {
      const int tg = t0 + j * 64 + n * 16 + l15;
      const bool dead = MASK && (tg > p);
#pragma unroll
      for (int r = 0; r < 4; ++r) {
        float v = sc[j][n][r] * 0.125f;
        if (dead) v = -1e30f;
        sc[j][n][r] = v;
        mx[r] = fmaxf(mx[r], v);
      }
    }
#pragma unroll
  for (int r = 0; r < 4; ++r) {
#pragma unroll
    for (int off = 1; off < 16; off <<= 1) mx[r] = fmaxf(mx[r], __shfl_xor(mx[r], off, 64));
  }
  // online-softmax merge (4 independent row chains)
#pragma unroll
  for (int r = 0; r < 4; ++r) {
    float mn = fmaxf(m_run[r], mx[r]);
    float alpha = __expf(m_run[r] - mn);
    m_run[r] = mn;
    float srow = 0.f;
#pragma unroll
    for (int j = 0; j < NJ; ++j)
#pragma unroll
      for (int n = 0; n < 4; ++n) {
        float e = __expf(sc[j][n][r] - mn);
        sc[j][n][r] = e;
        srow += e;
      }
#pragma unroll
    for (int off = 1; off < 16; off <<= 1) srow += __shfl_xor(srow, off, 64);
    l_run[r] = l_run[r] * alpha + srow;
#pragma unroll
    for (int n2 = 0; n2 < 4; ++n2) ao[n2][r] *= alpha;
  }
  // P -> wave-private LDS (A-operand layout for PV)
#pragma unroll
  for (int j = 0; j < NJ; ++j)
#pragma unroll
    for (int n = 0; n < 4; ++n)
#pragma unroll
      for (int r = 0; r < 4; ++r)
        Pl[(lg * 4 + r) * 136 + j * 64 + n * 16 + l15] = __float2bfloat16(sc[j][n][r]);
  // PV
#pragma unroll
  for (int j = 0; j < NJ; ++j)
#pragma unroll
    for (int ks2 = 0; ks2 < 2; ++ks2) {
      s16x8 pa = *(const s16x8*)&Pl[l15 * 136 + j * 64 + ks2 * 32 + lg * 8];
#pragma unroll
      for (int n2 = 0; n2 < 4; ++n2) {
        s16x8 vf = *(const s16x8*)(vtb + (size_t)(n2 * 16 + l15) * 2048 + t0 + j * 64 + ks2 * 32 + lg * 8);
        ao[n2] = __builtin_amdgcn_mfma_f32_16x16x32_bf16(pa, vf, ao[n2], 0, 0, 0);
      }
    }
}

__global__ __launch_bounds__(256) void attn_k(const bf16_t* __restrict__ q,
                                              const bf16_t* __restrict__ ksp,
                                              const bf16_t* __restrict__ vtp,
                                              bf16_t* __restrict__ o) {
  __shared__ __align__(16) bf16_t Plds[4][16][136];
  const int tid = threadIdx.x, lane = tid & 63, wave = tid >> 6;
  const int l15 = lane & 15, lg = lane >> 4;
  const int gw = blockIdx.x * 4 + wave;   // 0..2047
  const int b  = gw >> 10;
  const int pr = gw & 1023;

  const bf16_t* qb_b = q   + (size_t)b * 32768 * 64;
  const bf16_t* ksb  = ksp + (size_t)b * 2048 * 64;
  const bf16_t* vtb  = vtp + (size_t)b * 64 * 2048;
  bf16_t*       ob   = o   + (size_t)b * 32768 * 64;
  bf16_t* Pl = &Plds[wave][0][0];

#pragma unroll
  for (int ph = 0; ph < 2; ++ph) {
    const int p = ph ? (2047 - pr) : pr;   // s-position for this phase
    s16x8 qf[2];
    {
      const bf16_t* qptr = qb_b + (size_t)(16 * p + l15) * 64;
      qf[0] = *(const s16x8*)(qptr + lg * 8);
      qf[1] = *(const s16x8*)(qptr + 32 + lg * 8);
    }
    float m_run[4] = {-1e30f, -1e30f, -1e30f, -1e30f};
    float l_run[4] = {0.f, 0.f, 0.f, 0.f};
    f32x4 ao[4];
#pragma unroll
    for (int n = 0; n < 4; ++n) ao[n] = (f32x4){0.f, 0.f, 0.f, 0.f};

    const int ntfull = (p + 1) >> 6;       // fully-unmasked 64-tiles
    int tt = 0;
    for (; tt + 2 <= ntfull; tt += 2)
      attn_step<2, false>(tt * 64, p, qf, ksb, vtb, Pl, l15, lg, m_run, l_run, ao);
    if (tt < ntfull)
      attn_step<1, false>(tt * 64, p, qf, ksb, vtb, Pl, l15, lg, m_run, l_run, ao);
    if ((p + 1) & 63)
      attn_step<1, true>(ntfull * 64, p, qf, ksb, vtb, Pl, l15, lg, m_run, l_run, ao);

#pragma unroll
    for (int n2 = 0; n2 < 4; ++n2) {
#pragma unroll
      for (int r = 0; r < 4; ++r) {
        const int row = 16 * p + lg * 4 + r;
        ob[(size_t)row * 64 + n2 * 16 + l15] = __float2bfloat16(ao[n2][r] / l_run[r]);
      }
    }
  }
}

// ---------------------------------------------------------------- launch
extern "C" void kernel_launch(void* const* d_in, const int* in_sizes, int n_in,
                              void* d_out, int out_size, void* d_ws, size_t ws_size,
                              hipStream_t stream) {
  (void)in_sizes; (void)n_in; (void)out_size; (void)ws_size;
  const float* hidden = (const float*)d_in[0];
  const float* Wqkv   = (const float*)d_in[1];
  const float* bqkv   = (const float*)d_in[2];
  const float* Wout   = (const float*)d_in[3];
  const float* bout   = (const float*)d_in[4];
  const float* g1     = (const float*)d_in[5];
  const float* b1     = (const float*)d_in[6];
  const float* g2     = (const float*)d_in[7];
  const float* b2     = (const float*)d_in[8];
  const float* W1     = (const float*)d_in[9];
  const float* bfc1   = (const float*)d_in[10];
  const float* W2     = (const float*)d_in[11];
  const float* bfc2   = (const float*)d_in[12];

  float* out_h   = (float*)d_out;
  float* out_res = out_h + (size_t)4096 * 1024;

  char* ws = (char*)d_ws;
  auto alloc = [&](size_t bytes) {
    char* p = ws;
    ws += (bytes + 255) & ~(size_t)255;
    return p;
  };
  bf16_t* X1      = (bf16_t*)alloc((size_t)4096 * 1024 * 2);
  bf16_t* Wqkv_bf = (bf16_t*)alloc((size_t)1152 * 1024 * 2);
  float*  bias_r  = (float*)alloc(1152 * 4);
  bf16_t* qb      = (bf16_t*)alloc((size_t)4096 * 1024 * 2);
  bf16_t* ksum    = (bf16_t*)alloc((size_t)2 * 2048 * 64 * 2);
  bf16_t* vT      = (bf16_t*)alloc((size_t)2 * 64 * 2048 * 2);
  bf16_t* Ob      = (bf16_t*)alloc((size_t)4096 * 1024 * 2);
  bf16_t* Wout_bf = (bf16_t*)alloc((size_t)1024 * 1024 * 2);
  bf16_t* X2      = (bf16_t*)alloc((size_t)4096 * 1024 * 2);
  bf16_t* W1_bf   = (bf16_t*)alloc((size_t)4096 * 1024 * 2);
  bf16_t* W2_bf   = (bf16_t*)alloc((size_t)1024 * 4096 * 2);
  bf16_t* H1      = (bf16_t*)alloc((size_t)4096 * 4096 * 2);

  // weight prep
  cast_bf16_k<<<512,  256, 0, stream>>>(Wqkv, Wqkv_bf, 1024 * 1024);
  cast_bf16_k<<<512,  256, 0, stream>>>(Wout, Wout_bf, 1024 * 1024);
  cast_bf16_k<<<2048, 256, 0, stream>>>(W1, W1_bf, 4096 * 1024);
  cast_bf16_k<<<2048, 256, 0, stream>>>(W2, W2_bf, 1024 * 4096);
  reduce_kv_k<<<128, 256, 0, stream>>>(Wqkv, Wqkv_bf + (size_t)1024 * 1024);
  bias_prep_k<<<5, 256, 0, stream>>>(bqkv, bias_r);

  // LN1
  ln_cast_k<<<4096, 256, 0, stream>>>(hidden, g1, b1, X1);
  // QKV (reduced): M=4096, N=1152, K=1024
  gemm_bt<0><<<dim3(9, 32), 256, 0, stream>>>(X1, Wqkv_bf, bias_r, qb, nullptr, ksum, vT,
                                              4096, 1152, 1024);
  // attention (merged heads, paired causal balance)
  attn_k<<<512, 256, 0, stream>>>(qb, ksum, vT, Ob);
  // Wout + residual -> out_res (f32)
  gemm_bt<1><<<dim3(8, 32), 256, 0, stream>>>(Ob, Wout_bf, bout, out_res, hidden, nullptr,
                                              nullptr, 4096, 1024, 1024);
  // LN2
  ln_cast_k<<<4096, 256, 0, stream>>>(out_res, g2, b2, X2);
  // FC1 + tanh
  gemm_bt<2><<<dim3(32, 32), 256, 0, stream>>>(X2, W1_bf, bfc1, H1, nullptr, nullptr, nullptr,
                                               4096, 4096, 1024);
  // FC2 -> out_h (f32)
  gemm_bt<3><<<dim3(8, 32), 256, 0, stream>>>(H1, W2_bf, bfc2, out_h, nullptr, nullptr, nullptr,
                                              4096, 1024, 4096);
}

// Round 4
// 377.585 us; speedup vs baseline: 1.2649x; 1.0263x over previous
//
#include <hip/hip_runtime.h>
#include <hip/hip_bf16.h>

typedef __attribute__((ext_vector_type(8))) short s16x8;
typedef __attribute__((ext_vector_type(4))) float f32x4;
typedef __hip_bfloat16 bf16_t;

// ---------------------------------------------------------------- helpers
__device__ __forceinline__ void gload_lds16(const void* g, void* l) {
  __builtin_amdgcn_global_load_lds(
      (__attribute__((address_space(1))) void*)(g),
      (__attribute__((address_space(3))) void*)(l), 16, 0, 0);
}

// ---------------------------------------------------------------- weight prep
__global__ void cast_bf16_k(const float* __restrict__ x, bf16_t* __restrict__ y, int n) {
  int i = (blockIdx.x * 256 + threadIdx.x) * 8;
  if (i >= n) return;
  float4 a = *(const float4*)(x + i);
  float4 b = *(const float4*)(x + i + 4);
  union { bf16_t h[8]; s16x8 v; } u;
  u.h[0] = __float2bfloat16(a.x); u.h[1] = __float2bfloat16(a.y);
  u.h[2] = __float2bfloat16(a.z); u.h[3] = __float2bfloat16(a.w);
  u.h[4] = __float2bfloat16(b.x); u.h[5] = __float2bfloat16(b.y);
  u.h[6] = __float2bfloat16(b.z); u.h[7] = __float2bfloat16(b.w);
  *(s16x8*)(y + i) = u.v;
}

// Wk_red[d][:] = sum_h Wqkv[1024+h*64+d][:]; likewise Wv_red from rows 2048+.
__global__ void reduce_kv_k(const float* __restrict__ Wqkv, bf16_t* __restrict__ Wred) {
  int d   = blockIdx.x & 63;
  int isv = blockIdx.x >> 6;            // 0 = k, 1 = v
  int col = threadIdx.x * 4;
  const float* base = Wqkv + (size_t)(1024 + isv * 1024 + d) * 1024 + col;
  float4 s = {0.f, 0.f, 0.f, 0.f};
#pragma unroll
  for (int h = 0; h < 16; ++h) {
    float4 t = *(const float4*)(base + (size_t)h * 64 * 1024);
    s.x += t.x; s.y += t.y; s.z += t.z; s.w += t.w;
  }
  union { bf16_t h[4]; uint2 u; } o;
  o.h[0] = __float2bfloat16(s.x); o.h[1] = __float2bfloat16(s.y);
  o.h[2] = __float2bfloat16(s.z); o.h[3] = __float2bfloat16(s.w);
  *(uint2*)(Wred + (size_t)(isv * 64 + d) * 1024 + col) = o.u;
}

__global__ void bias_prep_k(const float* __restrict__ bqkv, float* __restrict__ br) {
  int i = blockIdx.x * 256 + threadIdx.x;
  if (i >= 1152) return;
  if (i < 1024) { br[i] = bqkv[i]; return; }
  int d = i - 1024;
  int off = (d < 64) ? (1024 + d) : (2048 + (d - 64));
  float s = 0.f;
#pragma unroll
  for (int h = 0; h < 16; ++h) s += bqkv[off + h * 64];
  br[i] = s;
}

// ---------------------------------------------------------------- layernorm + cast
__global__ __launch_bounds__(256) void ln_cast_k(const float* __restrict__ x,
                                                 const float* __restrict__ g,
                                                 const float* __restrict__ bb,
                                                 bf16_t* __restrict__ y) {
  int row = blockIdx.x, tid = threadIdx.x;
  float4 v = *(const float4*)(x + (size_t)row * 1024 + tid * 4);
  float s = v.x + v.y + v.z + v.w;
  float q = v.x * v.x + v.y * v.y + v.z * v.z + v.w * v.w;
#pragma unroll
  for (int off = 1; off < 64; off <<= 1) {
    s += __shfl_xor(s, off, 64);
    q += __shfl_xor(q, off, 64);
  }
  __shared__ float ss[4], qq[4];
  int wave = tid >> 6, lane = tid & 63;
  if (lane == 0) { ss[wave] = s; qq[wave] = q; }
  __syncthreads();
  s = ss[0] + ss[1] + ss[2] + ss[3];
  q = qq[0] + qq[1] + qq[2] + qq[3];
  float mu  = s * (1.0f / 1024.0f);
  float var = q * (1.0f / 1024.0f) - mu * mu;
  float rstd = rsqrtf(var + 1e-5f);
  float4 gg = *(const float4*)(g + tid * 4);
  float4 bv = *(const float4*)(bb + tid * 4);
  union { bf16_t h[4]; uint2 u; } o;
  o.h[0] = __float2bfloat16((v.x - mu) * rstd * gg.x + bv.x);
  o.h[1] = __float2bfloat16((v.y - mu) * rstd * gg.y + bv.y);
  o.h[2] = __float2bfloat16((v.z - mu) * rstd * gg.z + bv.z);
  o.h[3] = __float2bfloat16((v.w - mu) * rstd * gg.w + bv.w);
  *(uint2*)(y + (size_t)row * 1024 + tid * 4) = o.u;
}

// ---------------------------------------------------------------- GEMM (m97 structure)
template <int EPI>
__global__ __launch_bounds__(256) void gemm_bt(
    const bf16_t* __restrict__ A, const bf16_t* __restrict__ Bw,
    const float* __restrict__ bias, void* __restrict__ out0,
    const float* __restrict__ resid, bf16_t* __restrict__ oks,
    bf16_t* __restrict__ ovt, int M, int N, int K) {
  __shared__ __align__(16) bf16_t As[128 * 32];
  __shared__ __align__(16) bf16_t Bs[128 * 32];
  const int tid  = threadIdx.x;
  const int lane = tid & 63;
  const int wave = tid >> 6;
  const int l15 = lane & 15, lg = lane >> 4;
  const int wr = (wave >> 1) * 64, wc = (wave & 1) * 64;
  const int bm = blockIdx.y * 128, bn = blockIdx.x * 128;
  const size_t Kz = (size_t)K;
  const int srow = lane >> 2;        // 0..15
  const int scol = (lane & 3) * 8;   // 0,8,16,24

  f32x4 acc[4][4];
#pragma unroll
  for (int m = 0; m < 4; ++m)
#pragma unroll
    for (int n = 0; n < 4; ++n) acc[m][n] = (f32x4){0.f, 0.f, 0.f, 0.f};

  const bf16_t* Ab = A + (size_t)bm * Kz;
  const bf16_t* Bb = Bw + (size_t)bn * Kz;

  for (int k0 = 0; k0 < K; k0 += 32) {
    __syncthreads();
#pragma unroll
    for (int j = 0; j < 2; ++j) {
      const int cw = wave * 2 + j;
      gload_lds16(Ab + (size_t)(cw * 16 + srow) * Kz + k0 + scol, As + cw * 512);
      gload_lds16(Bb + (size_t)(cw * 16 + srow) * Kz + k0 + scol, Bs + cw * 512);
    }
    __syncthreads();
    s16x8 af[4], bfv[4];
#pragma unroll
    for (int m = 0; m < 4; ++m)
      af[m] = *(const s16x8*)&As[(wr + m * 16 + l15) * 32 + lg * 8];
#pragma unroll
    for (int n = 0; n < 4; ++n)
      bfv[n] = *(const s16x8*)&Bs[(wc + n * 16 + l15) * 32 + lg * 8];
#pragma unroll
    for (int m = 0; m < 4; ++m)
#pragma unroll
      for (int n = 0; n < 4; ++n)
        acc[m][n] = __builtin_amdgcn_mfma_f32_16x16x32_bf16(af[m], bfv[n], acc[m][n], 0, 0, 0);
  }

#pragma unroll
  for (int m = 0; m < 4; ++m) {
    const int row0 = bm + wr + m * 16 + lg * 4;
#pragma unroll
    for (int n = 0; n < 4; ++n) {
      const int col = bn + wc + n * 16 + l15;
      const float bcol = bias[col];
#pragma unroll
      for (int r = 0; r < 4; ++r) {
        const int rw = row0 + r;
        float c = acc[m][n][r] + bcol;
        if constexpr (EPI == 0) {
          if (col < 1024) {
            ((bf16_t*)out0)[(size_t)rw * 1024 + col] = __float2bfloat16(c);
          } else if (col < 1088) {
            int d = col - 1024, b = rw >> 11, t = rw & 2047;
            oks[((size_t)(b << 11) + t) * 64 + d] = __float2bfloat16(c);
          } else {
            int d = col - 1088, b = rw >> 11, t = rw & 2047;
            ovt[((size_t)b * 64 + d) * 2048 + t] = __float2bfloat16(c);
          }
        } else if constexpr (EPI == 1) {
          ((float*)out0)[(size_t)rw * N + col] = c + resid[(size_t)rw * N + col];
        } else if constexpr (EPI == 2) {
          ((bf16_t*)out0)[(size_t)rw * N + col] = __float2bfloat16(tanhf(c));
        } else {
          ((float*)out0)[(size_t)rw * N + col] = c;
        }
      }
    }
  }
}

// ---------------------------------------------------------------- flash attention
// v3: merged heads (wave fragment = 16 heads at one s-position p), 2 waves
// split each position's t-range (flash-merge via LDS), 8-wave blocks, jobs
// sorted big-first. Softmax in log2 units; per-lane deferred l-sum; defer-max
// (T13) skips the rescale pass when the running max doesn't grow.

template <int NJ, bool MASK>
__device__ __forceinline__ void attn_step(
    int t0, int p, const s16x8 (&qf)[2],
    const bf16_t* __restrict__ ksb, const bf16_t* __restrict__ vtb,
    bf16_t* __restrict__ Pl, int l15, int lg,
    float (&m_run)[4], float (&l_part)[4], f32x4 (&ao)[4]) {
  constexpr float SCL = 0.125f * 1.44269504088896f;  // scale * log2(e)
  f32x4 sc[NJ][4];
#pragma unroll
  for (int j = 0; j < NJ; ++j)
#pragma unroll
    for (int n = 0; n < 4; ++n) sc[j][n] = (f32x4){0.f, 0.f, 0.f, 0.f};

  // QK^T: A = q rows (16 heads), B = k_sum rows (t)
#pragma unroll
  for (int j = 0; j < NJ; ++j)
#pragma unroll
    for (int ks2 = 0; ks2 < 2; ++ks2)
#pragma unroll
      for (int n = 0; n < 4; ++n) {
        s16x8 kf = *(const s16x8*)(ksb + (size_t)(t0 + j * 64 + n * 16 + l15) * 64 + ks2 * 32 + lg * 8);
        sc[j][n] = __builtin_amdgcn_mfma_f32_16x16x32_bf16(qf[ks2], kf, sc[j][n], 0, 0, 0);
      }

  // scale to log2 units (+uniform causal mask on the final partial tile), row max
  float mx[4] = {-1e30f, -1e30f, -1e30f, -1e30f};
#pragma unroll
  for (int j = 0; j < NJ; ++j)
#pragma unroll
    for (int n = 0; n < 4; ++n) {
      const int tg = t0 + j * 64 + n * 16 + l15;
      const bool dead = MASK && (tg > p);
#pragma unroll
      for (int r = 0; r < 4; ++r) {
        float v = sc[j][n][r] * SCL;
        if (dead) v = -1e30f;
        sc[j][n][r] = v;
        mx[r] = fmaxf(mx[r], v);
      }
    }
#pragma unroll
  for (int r = 0; r < 4; ++r) {
#pragma unroll
    for (int off = 1; off < 16; off <<= 1) mx[r] = fmaxf(mx[r], __shfl_xor(mx[r], off, 64));
  }
  // defer-max: rescale only when the running max grows past the headroom
  int need = 0;
#pragma unroll
  for (int r = 0; r < 4; ++r) need |= (mx[r] > m_run[r] + 11.5f) ? 1 : 0;
  if (__any(need)) {
#pragma unroll
    for (int r = 0; r < 4; ++r) {
      float mn = fmaxf(m_run[r], mx[r]);
      float al = exp2f(m_run[r] - mn);
      m_run[r] = mn;
      l_part[r] *= al;
#pragma unroll
      for (int n2 = 0; n2 < 4; ++n2) ao[n2][r] *= al;
    }
  }
  // exp2 + per-lane l partial + P -> wave-private LDS (A-operand layout)
#pragma unroll
  for (int j = 0; j < NJ; ++j)
#pragma unroll
    for (int n = 0; n < 4; ++n)
#pragma unroll
      for (int r = 0; r < 4; ++r) {
        float e = exp2f(sc[j][n][r] - m_run[r]);
        l_part[r] += e;
        Pl[(lg * 4 + r) * 136 + j * 64 + n * 16 + l15] = __float2bfloat16(e);
      }
  // PV
#pragma unroll
  for (int j = 0; j < NJ; ++j)
#pragma unroll
    for (int ks2 = 0; ks2 < 2; ++ks2) {
      s16x8 pa = *(const s16x8*)&Pl[l15 * 136 + j * 64 + ks2 * 32 + lg * 8];
#pragma unroll
      for (int n2 = 0; n2 < 4; ++n2) {
        s16x8 vf = *(const s16x8*)(vtb + (size_t)(n2 * 16 + l15) * 2048 + t0 + j * 64 + ks2 * 32 + lg * 8);
        ao[n2] = __builtin_amdgcn_mfma_f32_16x16x32_bf16(pa, vf, ao[n2], 0, 0, 0);
      }
    }
}

__global__ __launch_bounds__(512) void attn_k(const bf16_t* __restrict__ q,
                                              const bf16_t* __restrict__ ksp,
                                              const bf16_t* __restrict__ vtp,
                                              bf16_t* __restrict__ o) {
  // per-wave 4352 B: P tile during main loop, combine buffer afterwards
  __shared__ __align__(16) bf16_t Plds[8][16][136];
  const int tid = threadIdx.x, lane = tid & 63, wave = tid >> 6;
  const int l15 = lane & 15, lg = lane >> 4;
  const int jobq = blockIdx.x * 4 + (wave >> 1);  // 0..4095, big-p first
  const int p  = 2047 - (jobq >> 1);
  const int b  = jobq & 1;
  const int half = wave & 1;                       // 0: first t-half, 1: second
  const int pmask = (p + 1) & 63;                  // partial (masked) tail tile?
  const int nf = (p + 1) >> 6;                     // full 64-tiles
  const int na = (nf + 1) >> 1;                    // first wave's share

  const bf16_t* qb_b = q   + (size_t)b * 32768 * 64;
  const bf16_t* ksb  = ksp + (size_t)b * 2048 * 64;
  const bf16_t* vtb  = vtp + (size_t)b * 64 * 2048;
  bf16_t*       ob   = o   + (size_t)b * 32768 * 64;
  bf16_t* Pl = &Plds[wave][0][0];

  s16x8 qf[2];
  {
    const bf16_t* qptr = qb_b + (size_t)(16 * p + l15) * 64;
    qf[0] = *(const s16x8*)(qptr + lg * 8);
    qf[1] = *(const s16x8*)(qptr + 32 + lg * 8);
  }
  float m_run[4]  = {-1e30f, -1e30f, -1e30f, -1e30f};
  float l_part[4] = {0.f, 0.f, 0.f, 0.f};
  f32x4 ao[4];
#pragma unroll
  for (int n = 0; n < 4; ++n) ao[n] = (f32x4){0.f, 0.f, 0.f, 0.f};

  int tt         = half ? na : 0;
  const int tfin = half ? nf : na;
  for (; tt + 2 <= tfin; tt += 2)
    attn_step<2, false>(tt * 64, p, qf, ksb, vtb, Pl, l15, lg, m_run, l_part, ao);
  if (tt < tfin)
    attn_step<1, false>(tt * 64, p, qf, ksb, vtb, Pl, l15, lg, m_run, l_part, ao);
  if (half && pmask)
    attn_step<1, true>(nf * 64, p, qf, ksb, vtb, Pl, l15, lg, m_run, l_part, ao);

  // reduce per-lane l partials across the 16-lane group (once per wave)
#pragma unroll
  for (int r = 0; r < 4; ++r) {
#pragma unroll
    for (int off = 1; off < 16; off <<= 1) l_part[r] += __shfl_xor(l_part[r], off, 64);
  }
  // publish partials (reuse P area): ao f32[16][64] + m[16] + l[16]
  {
    float* cb = (float*)Pl;
#pragma unroll
    for (int n2 = 0; n2 < 4; ++n2)
#pragma unroll
      for (int r = 0; r < 4; ++r)
        cb[(lg * 4 + r) * 64 + n2 * 16 + l15] = ao[n2][r];
    if (l15 == 0) {
#pragma unroll
      for (int r = 0; r < 4; ++r) {
        cb[1024 + lg * 4 + r] = m_run[r];
        cb[1040 + lg * 4 + r] = l_part[r];
      }
    }
  }
  __syncthreads();
  if (half == 0) {
    const float* cB = (const float*)&Plds[wave + 1][0][0];
#pragma unroll
    for (int r = 0; r < 4; ++r) {
      const int row = lg * 4 + r;
      float mB = cB[1024 + row], lB = cB[1040 + row];
      float ms = fmaxf(m_run[r], mB);
      float fA = exp2f(m_run[r] - ms);
      float fB = exp2f(mB - ms);
      float li = 1.0f / (l_part[r] * fA + lB * fB);
#pragma unroll
      for (int n2 = 0; n2 < 4; ++n2) {
        float ov = (ao[n2][r] * fA + cB[row * 64 + n2 * 16 + l15] * fB) * li;
        ob[(size_t)(16 * p + row) * 64 + n2 * 16 + l15] = __float2bfloat16(ov);
      }
    }
  }
}

// ---------------------------------------------------------------- launch
extern "C" void kernel_launch(void* const* d_in, const int* in_sizes, int n_in,
                              void* d_out, int out_size, void* d_ws, size_t ws_size,
                              hipStream_t stream) {
  (void)in_sizes; (void)n_in; (void)out_size; (void)ws_size;
  const float* hidden = (const float*)d_in[0];
  const float* Wqkv   = (const float*)d_in[1];
  const float* bqkv   = (const float*)d_in[2];
  const float* Wout   = (const float*)d_in[3];
  const float* bout   = (const float*)d_in[4];
  const float* g1     = (const float*)d_in[5];
  const float* b1     = (const float*)d_in[6];
  const float* g2     = (const float*)d_in[7];
  const float* b2     = (const float*)d_in[8];
  const float* W1     = (const float*)d_in[9];
  const float* bfc1   = (const float*)d_in[10];
  const float* W2     = (const float*)d_in[11];
  const float* bfc2   = (const float*)d_in[12];

  float* out_h   = (float*)d_out;
  float* out_res = out_h + (size_t)4096 * 1024;

  char* ws = (char*)d_ws;
  auto alloc = [&](size_t bytes) {
    char* p = ws;
    ws += (bytes + 255) & ~(size_t)255;
    return p;
  };
  bf16_t* X1      = (bf16_t*)alloc((size_t)4096 * 1024 * 2);
  bf16_t* Wqkv_bf = (bf16_t*)alloc((size_t)1152 * 1024 * 2);
  float*  bias_r  = (float*)alloc(1152 * 4);
  bf16_t* qb      = (bf16_t*)alloc((size_t)4096 * 1024 * 2);
  bf16_t* ksum    = (bf16_t*)alloc((size_t)2 * 2048 * 64 * 2);
  bf16_t* vT      = (bf16_t*)alloc((size_t)2 * 64 * 2048 * 2);
  bf16_t* Ob      = (bf16_t*)alloc((size_t)4096 * 1024 * 2);
  bf16_t* Wout_bf = (bf16_t*)alloc((size_t)1024 * 1024 * 2);
  bf16_t* X2      = (bf16_t*)alloc((size_t)4096 * 1024 * 2);
  bf16_t* W1_bf   = (bf16_t*)alloc((size_t)4096 * 1024 * 2);
  bf16_t* W2_bf   = (bf16_t*)alloc((size_t)1024 * 4096 * 2);
  bf16_t* H1      = (bf16_t*)alloc((size_t)4096 * 4096 * 2);

  // weight prep
  cast_bf16_k<<<512,  256, 0, stream>>>(Wqkv, Wqkv_bf, 1024 * 1024);
  cast_bf16_k<<<512,  256, 0, stream>>>(Wout, Wout_bf, 1024 * 1024);
  cast_bf16_k<<<2048, 256, 0, stream>>>(W1, W1_bf, 4096 * 1024);
  cast_bf16_k<<<2048, 256, 0, stream>>>(W2, W2_bf, 1024 * 4096);
  reduce_kv_k<<<128, 256, 0, stream>>>(Wqkv, Wqkv_bf + (size_t)1024 * 1024);
  bias_prep_k<<<5, 256, 0, stream>>>(bqkv, bias_r);

  // LN1
  ln_cast_k<<<4096, 256, 0, stream>>>(hidden, g1, b1, X1);
  // QKV (reduced): M=4096, N=1152, K=1024
  gemm_bt<0><<<dim3(9, 32), 256, 0, stream>>>(X1, Wqkv_bf, bias_r, qb, nullptr, ksum, vT,
                                              4096, 1152, 1024);
  // attention: 4096 jobs x 2 waves, 8-wave blocks, big jobs first
  attn_k<<<1024, 512, 0, stream>>>(qb, ksum, vT, Ob);
  // Wout + residual -> out_res (f32)
  gemm_bt<1><<<dim3(8, 32), 256, 0, stream>>>(Ob, Wout_bf, bout, out_res, hidden, nullptr,
                                              nullptr, 4096, 1024, 1024);
  // LN2
  ln_cast_k<<<4096, 256, 0, stream>>>(out_res, g2, b2, X2);
  // FC1 + tanh
  gemm_bt<2><<<dim3(32, 32), 256, 0, stream>>>(X2, W1_bf, bfc1, H1, nullptr, nullptr, nullptr,
                                               4096, 4096, 1024);
  // FC2 -> out_h (f32)
  gemm_bt<3><<<dim3(8, 32), 256, 0, stream>>>(H1, W2_bf, bfc2, out_h, nullptr, nullptr, nullptr,
                                              4096, 1024, 4096);
}

// Round 5
// 305.795 us; speedup vs baseline: 1.5619x; 1.2348x over previous
//
#include <hip/hip_runtime.h>
#include <hip/hip_bf16.h>

typedef __attribute__((ext_vector_type(8))) short s16x8;
typedef __attribute__((ext_vector_type(4))) float f32x4;
typedef __hip_bfloat16 bf16_t;

// ---------------------------------------------------------------- helpers
__device__ __forceinline__ void gload_lds16(const void* g, void* l) {
  __builtin_amdgcn_global_load_lds(
      (__attribute__((address_space(1))) void*)(g),
      (__attribute__((address_space(3))) void*)(l), 16, 0, 0);
}

__device__ __forceinline__ unsigned cvt_pk_bf16(float lo, float hi) {
  unsigned r;
  asm("v_cvt_pk_bf16_f32 %0, %1, %2" : "=v"(r) : "v"(lo), "v"(hi));
  return r;
}

// ---------------------------------------------------------------- weight prep
__global__ void cast_bf16_k(const float* __restrict__ x, bf16_t* __restrict__ y, int n) {
  int i = (blockIdx.x * 256 + threadIdx.x) * 8;
  if (i >= n) return;
  float4 a = *(const float4*)(x + i);
  float4 b = *(const float4*)(x + i + 4);
  union { bf16_t h[8]; s16x8 v; } u;
  u.h[0] = __float2bfloat16(a.x); u.h[1] = __float2bfloat16(a.y);
  u.h[2] = __float2bfloat16(a.z); u.h[3] = __float2bfloat16(a.w);
  u.h[4] = __float2bfloat16(b.x); u.h[5] = __float2bfloat16(b.y);
  u.h[6] = __float2bfloat16(b.z); u.h[7] = __float2bfloat16(b.w);
  *(s16x8*)(y + i) = u.v;
}

// Wk_red[d][:] = sum_h Wqkv[1024+h*64+d][:]; likewise Wv_red from rows 2048+.
__global__ void reduce_kv_k(const float* __restrict__ Wqkv, bf16_t* __restrict__ Wred) {
  int d   = blockIdx.x & 63;
  int isv = blockIdx.x >> 6;            // 0 = k, 1 = v
  int col = threadIdx.x * 4;
  const float* base = Wqkv + (size_t)(1024 + isv * 1024 + d) * 1024 + col;
  float4 s = {0.f, 0.f, 0.f, 0.f};
#pragma unroll
  for (int h = 0; h < 16; ++h) {
    float4 t = *(const float4*)(base + (size_t)h * 64 * 1024);
    s.x += t.x; s.y += t.y; s.z += t.z; s.w += t.w;
  }
  union { bf16_t h[4]; uint2 u; } o;
  o.h[0] = __float2bfloat16(s.x); o.h[1] = __float2bfloat16(s.y);
  o.h[2] = __float2bfloat16(s.z); o.h[3] = __float2bfloat16(s.w);
  *(uint2*)(Wred + (size_t)(isv * 64 + d) * 1024 + col) = o.u;
}

__global__ void bias_prep_k(const float* __restrict__ bqkv, float* __restrict__ br) {
  int i = blockIdx.x * 256 + threadIdx.x;
  if (i >= 1152) return;
  if (i < 1024) { br[i] = bqkv[i]; return; }
  int d = i - 1024;
  int off = (d < 64) ? (1024 + d) : (2048 + (d - 64));
  float s = 0.f;
#pragma unroll
  for (int h = 0; h < 16; ++h) s += bqkv[off + h * 64];
  br[i] = s;
}

// ---------------------------------------------------------------- layernorm + cast
__global__ __launch_bounds__(256) void ln_cast_k(const float* __restrict__ x,
                                                 const float* __restrict__ g,
                                                 const float* __restrict__ bb,
                                                 bf16_t* __restrict__ y) {
  int row = blockIdx.x, tid = threadIdx.x;
  float4 v = *(const float4*)(x + (size_t)row * 1024 + tid * 4);
  float s = v.x + v.y + v.z + v.w;
  float q = v.x * v.x + v.y * v.y + v.z * v.z + v.w * v.w;
#pragma unroll
  for (int off = 1; off < 64; off <<= 1) {
    s += __shfl_xor(s, off, 64);
    q += __shfl_xor(q, off, 64);
  }
  __shared__ float ss[4], qq[4];
  int wave = tid >> 6, lane = tid & 63;
  if (lane == 0) { ss[wave] = s; qq[wave] = q; }
  __syncthreads();
  s = ss[0] + ss[1] + ss[2] + ss[3];
  q = qq[0] + qq[1] + qq[2] + qq[3];
  float mu  = s * (1.0f / 1024.0f);
  float var = q * (1.0f / 1024.0f) - mu * mu;
  float rstd = rsqrtf(var + 1e-5f);
  float4 gg = *(const float4*)(g + tid * 4);
  float4 bv = *(const float4*)(bb + tid * 4);
  union { bf16_t h[4]; uint2 u; } o;
  o.h[0] = __float2bfloat16((v.x - mu) * rstd * gg.x + bv.x);
  o.h[1] = __float2bfloat16((v.y - mu) * rstd * gg.y + bv.y);
  o.h[2] = __float2bfloat16((v.z - mu) * rstd * gg.z + bv.z);
  o.h[3] = __float2bfloat16((v.w - mu) * rstd * gg.w + bv.w);
  *(uint2*)(y + (size_t)row * 1024 + tid * 4) = o.u;
}

// ---------------------------------------------------------------- GEMM (m97 structure)
template <int EPI>
__global__ __launch_bounds__(256) void gemm_bt(
    const bf16_t* __restrict__ A, const bf16_t* __restrict__ Bw,
    const float* __restrict__ bias, void* __restrict__ out0,
    const float* __restrict__ resid, bf16_t* __restrict__ oks,
    bf16_t* __restrict__ ovt, int M, int N, int K) {
  __shared__ __align__(16) bf16_t As[128 * 32];
  __shared__ __align__(16) bf16_t Bs[128 * 32];
  const int tid  = threadIdx.x;
  const int lane = tid & 63;
  const int wave = tid >> 6;
  const int l15 = lane & 15, lg = lane >> 4;
  const int wr = (wave >> 1) * 64, wc = (wave & 1) * 64;
  const int bm = blockIdx.y * 128, bn = blockIdx.x * 128;
  const size_t Kz = (size_t)K;
  const int srow = lane >> 2;        // 0..15
  const int scol = (lane & 3) * 8;   // 0,8,16,24

  f32x4 acc[4][4];
#pragma unroll
  for (int m = 0; m < 4; ++m)
#pragma unroll
    for (int n = 0; n < 4; ++n) acc[m][n] = (f32x4){0.f, 0.f, 0.f, 0.f};

  const bf16_t* Ab = A + (size_t)bm * Kz;
  const bf16_t* Bb = Bw + (size_t)bn * Kz;

  for (int k0 = 0; k0 < K; k0 += 32) {
    __syncthreads();
#pragma unroll
    for (int j = 0; j < 2; ++j) {
      const int cw = wave * 2 + j;
      gload_lds16(Ab + (size_t)(cw * 16 + srow) * Kz + k0 + scol, As + cw * 512);
      gload_lds16(Bb + (size_t)(cw * 16 + srow) * Kz + k0 + scol, Bs + cw * 512);
    }
    __syncthreads();
    s16x8 af[4], bfv[4];
#pragma unroll
    for (int m = 0; m < 4; ++m)
      af[m] = *(const s16x8*)&As[(wr + m * 16 + l15) * 32 + lg * 8];
#pragma unroll
    for (int n = 0; n < 4; ++n)
      bfv[n] = *(const s16x8*)&Bs[(wc + n * 16 + l15) * 32 + lg * 8];
#pragma unroll
    for (int m = 0; m < 4; ++m)
#pragma unroll
      for (int n = 0; n < 4; ++n)
        acc[m][n] = __builtin_amdgcn_mfma_f32_16x16x32_bf16(af[m], bfv[n], acc[m][n], 0, 0, 0);
  }

#pragma unroll
  for (int m = 0; m < 4; ++m) {
    const int row0 = bm + wr + m * 16 + lg * 4;
#pragma unroll
    for (int n = 0; n < 4; ++n) {
      const int col = bn + wc + n * 16 + l15;
      const float bcol = bias[col];
#pragma unroll
      for (int r = 0; r < 4; ++r) {
        const int rw = row0 + r;
        float c = acc[m][n][r] + bcol;
        if constexpr (EPI == 0) {
          if (col < 1024) {
            ((bf16_t*)out0)[(size_t)rw * 1024 + col] = __float2bfloat16(c);
          } else if (col < 1088) {
            int d = col - 1024, b = rw >> 11, t = rw & 2047;
            oks[((size_t)(b << 11) + t) * 64 + d] = __float2bfloat16(c);
          } else {
            int d = col - 1088, b = rw >> 11, t = rw & 2047;
            ovt[((size_t)b * 64 + d) * 2048 + t] = __float2bfloat16(c);
          }
        } else if constexpr (EPI == 1) {
          ((float*)out0)[(size_t)rw * N + col] = c + resid[(size_t)rw * N + col];
        } else if constexpr (EPI == 2) {
          ((bf16_t*)out0)[(size_t)rw * N + col] = __float2bfloat16(tanhf(c));
        } else {
          ((float*)out0)[(size_t)rw * N + col] = c;
        }
      }
    }
  }
}

// ---------------------------------------------------------------- flash attention v4
// Block-cooperative: 8 waves = 8 consecutive p (same batch) share K/V tiles
// staged in LDS (global_load_lds, pre-swizzled source + XOR-swizzled reads).
// Swapped QK (mfma(K,Q)): head = lane&15 -> per-lane softmax state, no
// shfl-max in the common path (defer-max check), P exchange via ds_write_b64
// + v_cvt_pk_bf16_f32.

template <bool MASK>
__device__ __forceinline__ void attn_tile(
    int t0, int p, const s16x8 (&qf)[2],
    const bf16_t* __restrict__ Ks, const bf16_t* __restrict__ Vs,
    bf16_t* __restrict__ Pl, int l15, int lg,
    float& m_run, float& l_part, f32x4 (&ao)[4]) {
  constexpr float SCL = 0.125f * 1.44269504088896f;  // scale * log2(e)
  const int sw7 = l15 & 7;

  // QK^T (swapped): A = K rows (t), B = q cols (head) -> sc row=t, col=head
  f32x4 sc[4];
#pragma unroll
  for (int n = 0; n < 4; ++n) sc[n] = (f32x4){0.f, 0.f, 0.f, 0.f};
#pragma unroll
  for (int ks2 = 0; ks2 < 2; ++ks2) {
#pragma unroll
    for (int n = 0; n < 4; ++n) {
      s16x8 kf = *(const s16x8*)&Ks[(n * 16 + l15) * 64 + (((ks2 << 2) | lg) ^ sw7) * 8];
      sc[n] = __builtin_amdgcn_mfma_f32_16x16x32_bf16(kf, qf[ks2], sc[n], 0, 0, 0);
    }
  }

  // scale to log2 units (+causal mask on tail tile); per-lane max
  float mx = -1e30f;
#pragma unroll
  for (int n = 0; n < 4; ++n) {
#pragma unroll
    for (int r = 0; r < 4; ++r) {
      float v = sc[n][r] * SCL;
      if (MASK && (t0 + n * 16 + lg * 4 + r > p)) v = -1e30f;
      sc[n][r] = v;
      mx = fmaxf(mx, v);
    }
  }
  // defer-max: per-lane check only; full reduce + rescale when it fires
  if (__any(mx > m_run + 11.5f)) {
    float mxf = fmaxf(mx, __shfl_xor(mx, 16, 64));
    mxf = fmaxf(mxf, __shfl_xor(mxf, 32, 64));
    float mn = fmaxf(m_run, mxf);
    float alpha = exp2f(m_run - mn);   // per-lane, head = l15
    m_run = mn;
    l_part *= alpha;
#pragma unroll
    for (int r = 0; r < 4; ++r) {
      float ar = __shfl(alpha, lg * 4 + r, 64);  // alpha for head = lg*4+r
#pragma unroll
      for (int n2 = 0; n2 < 4; ++n2) ao[n2][r] *= ar;
    }
  }
  // exp2 + l partial + packed P store (row = head = l15)
#pragma unroll
  for (int n = 0; n < 4; ++n) {
    float e0 = exp2f(sc[n][0] - m_run);
    float e1 = exp2f(sc[n][1] - m_run);
    float e2 = exp2f(sc[n][2] - m_run);
    float e3 = exp2f(sc[n][3] - m_run);
    l_part += (e0 + e1) + (e2 + e3);
    uint2 d;
    d.x = cvt_pk_bf16(e0, e1);
    d.y = cvt_pk_bf16(e2, e3);
    *(uint2*)&Pl[l15 * 72 + n * 16 + lg * 4] = d;
  }
  // PV: A = P[head][t] (read own row l15), B = V^T from LDS (swizzled)
#pragma unroll
  for (int ks2 = 0; ks2 < 2; ++ks2) {
    s16x8 pa = *(const s16x8*)&Pl[l15 * 72 + ks2 * 32 + lg * 8];
#pragma unroll
    for (int n2 = 0; n2 < 4; ++n2) {
      s16x8 vf = *(const s16x8*)&Vs[(n2 * 16 + l15) * 64 + (((ks2 << 2) | lg) ^ sw7) * 8];
      ao[n2] = __builtin_amdgcn_mfma_f32_16x16x32_bf16(pa, vf, ao[n2], 0, 0, 0);
    }
  }
}

__global__ __launch_bounds__(512) void attn_k(const bf16_t* __restrict__ q,
                                              const bf16_t* __restrict__ ksp,
                                              const bf16_t* __restrict__ vtp,
                                              bf16_t* __restrict__ o) {
  __shared__ __align__(16) bf16_t Ks[64 * 64];
  __shared__ __align__(16) bf16_t Vs[64 * 64];
  __shared__ __align__(16) bf16_t Plds[8][16 * 72];
  const int tid = threadIdx.x, lane = tid & 63, wave = tid >> 6;
  const int l15 = lane & 15, lg = lane >> 4;
  const int grp = blockIdx.x >> 1;            // 0..255, big-p first
  const int b   = blockIdx.x & 1;
  const int pbase = 2040 - 8 * grp;
  const int p = pbase + wave;                  // this wave's s-position

  const bf16_t* qb_b = q   + (size_t)b * 32768 * 64;
  const bf16_t* ksb  = ksp + (size_t)b * 2048 * 64;
  const bf16_t* vtb  = vtp + (size_t)b * 64 * 2048;
  bf16_t*       ob   = o   + (size_t)b * 32768 * 64;
  bf16_t* Pl = &Plds[wave][0];

  // staging geometry: wave w stages rows w*8..w*8+7 of each 64x64 tile;
  // source column pre-swizzled so linear LDS + swizzled read = XOR layout.
  const int srow = lane >> 3;                 // 0..7
  const int scol = lane & 7;                  // 16B chunk
  const int grow = wave * 8 + srow;           // tile row
  const int gcol = scol ^ (grow & 7);         // pre-swizzled source chunk
  const bf16_t* ksrc0 = ksb + (size_t)grow * 64 + gcol * 8;
  const bf16_t* vsrc0 = vtb + (size_t)grow * 2048 + gcol * 8;
  bf16_t* kdst = Ks + wave * 512;
  bf16_t* vdst = Vs + wave * 512;

  // q fragment (B operand: col = head = l15, k = d)
  s16x8 qf[2];
  {
    const bf16_t* qptr = qb_b + (size_t)(16 * p + l15) * 64;
    qf[0] = *(const s16x8*)(qptr + lg * 8);
    qf[1] = *(const s16x8*)(qptr + 32 + lg * 8);
  }

  float m_run = -1e30f, l_part = 0.f;
  f32x4 ao[4];
#pragma unroll
  for (int n = 0; n < 4; ++n) ao[n] = (f32x4){0.f, 0.f, 0.f, 0.f};

  const int nsteps = (pbase + 71) >> 6;        // covers all 8 waves' ranges
  for (int tt = 0; tt < nsteps; ++tt) {
    const int t0 = tt * 64;
    __syncthreads();                           // everyone done with prev tiles
    gload_lds16(ksrc0 + (size_t)t0 * 64, kdst);
    gload_lds16(vsrc0 + t0, vdst);
    __syncthreads();                           // vmcnt drained -> tiles ready
    if (t0 <= p) {
      if (t0 + 63 <= p)
        attn_tile<false>(t0, p, qf, Ks, Vs, Pl, l15, lg, m_run, l_part, ao);
      else
        attn_tile<true>(t0, p, qf, Ks, Vs, Pl, l15, lg, m_run, l_part, ao);
    }
  }

  // l: reduce across the 4 lanes of each head (lanes differ in bits 4,5)
  float l2 = l_part + __shfl_xor(l_part, 16, 64);
  l2 += __shfl_xor(l2, 32, 64);
  float rl[4];
#pragma unroll
  for (int r = 0; r < 4; ++r) rl[r] = 1.0f / __shfl(l2, lg * 4 + r, 64);
#pragma unroll
  for (int n2 = 0; n2 < 4; ++n2) {
#pragma unroll
    for (int r = 0; r < 4; ++r) {
      const int row = 16 * p + lg * 4 + r;     // head = lg*4+r
      ob[(size_t)row * 64 + n2 * 16 + l15] = __float2bfloat16(ao[n2][r] * rl[r]);
    }
  }
}

// ---------------------------------------------------------------- launch
extern "C" void kernel_launch(void* const* d_in, const int* in_sizes, int n_in,
                              void* d_out, int out_size, void* d_ws, size_t ws_size,
                              hipStream_t stream) {
  (void)in_sizes; (void)n_in; (void)out_size; (void)ws_size;
  const float* hidden = (const float*)d_in[0];
  const float* Wqkv   = (const float*)d_in[1];
  const float* bqkv   = (const float*)d_in[2];
  const float* Wout   = (const float*)d_in[3];
  const float* bout   = (const float*)d_in[4];
  const float* g1     = (const float*)d_in[5];
  const float* b1     = (const float*)d_in[6];
  const float* g2     = (const float*)d_in[7];
  const float* b2     = (const float*)d_in[8];
  const float* W1     = (const float*)d_in[9];
  const float* bfc1   = (const float*)d_in[10];
  const float* W2     = (const float*)d_in[11];
  const float* bfc2   = (const float*)d_in[12];

  float* out_h   = (float*)d_out;
  float* out_res = out_h + (size_t)4096 * 1024;

  char* ws = (char*)d_ws;
  auto alloc = [&](size_t bytes) {
    char* p = ws;
    ws += (bytes + 255) & ~(size_t)255;
    return p;
  };
  bf16_t* X1      = (bf16_t*)alloc((size_t)4096 * 1024 * 2);
  bf16_t* Wqkv_bf = (bf16_t*)alloc((size_t)1152 * 1024 * 2);
  float*  bias_r  = (float*)alloc(1152 * 4);
  bf16_t* qb      = (bf16_t*)alloc((size_t)4096 * 1024 * 2);
  bf16_t* ksum    = (bf16_t*)alloc((size_t)2 * 2048 * 64 * 2);
  bf16_t* vT      = (bf16_t*)alloc((size_t)2 * 64 * 2048 * 2);
  bf16_t* Ob      = (bf16_t*)alloc((size_t)4096 * 1024 * 2);
  bf16_t* Wout_bf = (bf16_t*)alloc((size_t)1024 * 1024 * 2);
  bf16_t* X2      = (bf16_t*)alloc((size_t)4096 * 1024 * 2);
  bf16_t* W1_bf   = (bf16_t*)alloc((size_t)4096 * 1024 * 2);
  bf16_t* W2_bf   = (bf16_t*)alloc((size_t)1024 * 4096 * 2);
  bf16_t* H1      = (bf16_t*)alloc((size_t)4096 * 4096 * 2);

  // weight prep
  cast_bf16_k<<<512,  256, 0, stream>>>(Wqkv, Wqkv_bf, 1024 * 1024);
  cast_bf16_k<<<512,  256, 0, stream>>>(Wout, Wout_bf, 1024 * 1024);
  cast_bf16_k<<<2048, 256, 0, stream>>>(W1, W1_bf, 4096 * 1024);
  cast_bf16_k<<<2048, 256, 0, stream>>>(W2, W2_bf, 1024 * 4096);
  reduce_kv_k<<<128, 256, 0, stream>>>(Wqkv, Wqkv_bf + (size_t)1024 * 1024);
  bias_prep_k<<<5, 256, 0, stream>>>(bqkv, bias_r);

  // LN1
  ln_cast_k<<<4096, 256, 0, stream>>>(hidden, g1, b1, X1);
  // QKV (reduced): M=4096, N=1152, K=1024
  gemm_bt<0><<<dim3(9, 32), 256, 0, stream>>>(X1, Wqkv_bf, bias_r, qb, nullptr, ksum, vT,
                                              4096, 1152, 1024);
  // attention: 512 blocks x 8 waves; block shares staged K/V tiles
  attn_k<<<512, 512, 0, stream>>>(qb, ksum, vT, Ob);
  // Wout + residual -> out_res (f32)
  gemm_bt<1><<<dim3(8, 32), 256, 0, stream>>>(Ob, Wout_bf, bout, out_res, hidden, nullptr,
                                              nullptr, 4096, 1024, 1024);
  // LN2
  ln_cast_k<<<4096, 256, 0, stream>>>(out_res, g2, b2, X2);
  // FC1 + tanh
  gemm_bt<2><<<dim3(32, 32), 256, 0, stream>>>(X2, W1_bf, bfc1, H1, nullptr, nullptr, nullptr,
                                               4096, 4096, 1024);
  // FC2 -> out_h (f32)
  gemm_bt<3><<<dim3(8, 32), 256, 0, stream>>>(H1, W2_bf, bfc2, out_h, nullptr, nullptr, nullptr,
                                              4096, 1024, 4096);
}

// Round 6
// 267.578 us; speedup vs baseline: 1.7849x; 1.1428x over previous
//
#include <hip/hip_runtime.h>
#include <hip/hip_bf16.h>

typedef __attribute__((ext_vector_type(8))) short s16x8;
typedef __attribute__((ext_vector_type(4))) float f32x4;
typedef __hip_bfloat16 bf16_t;

// ---------------------------------------------------------------- helpers
__device__ __forceinline__ void gload_lds16(const void* g, void* l) {
  __builtin_amdgcn_global_load_lds(
      (__attribute__((address_space(1))) void*)(g),
      (__attribute__((address_space(3))) void*)(l), 16, 0, 0);
}

__device__ __forceinline__ unsigned cvt_pk_bf16(float lo, float hi) {
  unsigned r;
  asm("v_cvt_pk_bf16_f32 %0, %1, %2" : "=v"(r) : "v"(lo), "v"(hi));
  return r;
}

// ---------------------------------------------------------------- weight prep
__global__ void cast_bf16_k(const float* __restrict__ x, bf16_t* __restrict__ y, int n) {
  int i = (blockIdx.x * 256 + threadIdx.x) * 8;
  if (i >= n) return;
  float4 a = *(const float4*)(x + i);
  float4 b = *(const float4*)(x + i + 4);
  union { bf16_t h[8]; s16x8 v; } u;
  u.h[0] = __float2bfloat16(a.x); u.h[1] = __float2bfloat16(a.y);
  u.h[2] = __float2bfloat16(a.z); u.h[3] = __float2bfloat16(a.w);
  u.h[4] = __float2bfloat16(b.x); u.h[5] = __float2bfloat16(b.y);
  u.h[6] = __float2bfloat16(b.z); u.h[7] = __float2bfloat16(b.w);
  *(s16x8*)(y + i) = u.v;
}

// Wk_red[d][:] = sum_h Wqkv[1024+h*64+d][:]; likewise Wv_red from rows 2048+.
__global__ void reduce_kv_k(const float* __restrict__ Wqkv, bf16_t* __restrict__ Wred) {
  int d   = blockIdx.x & 63;
  int isv = blockIdx.x >> 6;            // 0 = k, 1 = v
  int col = threadIdx.x * 4;
  const float* base = Wqkv + (size_t)(1024 + isv * 1024 + d) * 1024 + col;
  float4 s = {0.f, 0.f, 0.f, 0.f};
#pragma unroll
  for (int h = 0; h < 16; ++h) {
    float4 t = *(const float4*)(base + (size_t)h * 64 * 1024);
    s.x += t.x; s.y += t.y; s.z += t.z; s.w += t.w;
  }
  union { bf16_t h[4]; uint2 u; } o;
  o.h[0] = __float2bfloat16(s.x); o.h[1] = __float2bfloat16(s.y);
  o.h[2] = __float2bfloat16(s.z); o.h[3] = __float2bfloat16(s.w);
  *(uint2*)(Wred + (size_t)(isv * 64 + d) * 1024 + col) = o.u;
}

__global__ void bias_prep_k(const float* __restrict__ bqkv, float* __restrict__ br) {
  int i = blockIdx.x * 256 + threadIdx.x;
  if (i >= 1152) return;
  if (i < 1024) { br[i] = bqkv[i]; return; }
  int d = i - 1024;
  int off = (d < 64) ? (1024 + d) : (2048 + (d - 64));
  float s = 0.f;
#pragma unroll
  for (int h = 0; h < 16; ++h) s += bqkv[off + h * 64];
  br[i] = s;
}

// ---------------------------------------------------------------- layernorm + cast
__global__ __launch_bounds__(256) void ln_cast_k(const float* __restrict__ x,
                                                 const float* __restrict__ g,
                                                 const float* __restrict__ bb,
                                                 bf16_t* __restrict__ y) {
  int row = blockIdx.x, tid = threadIdx.x;
  float4 v = *(const float4*)(x + (size_t)row * 1024 + tid * 4);
  float s = v.x + v.y + v.z + v.w;
  float q = v.x * v.x + v.y * v.y + v.z * v.z + v.w * v.w;
#pragma unroll
  for (int off = 1; off < 64; off <<= 1) {
    s += __shfl_xor(s, off, 64);
    q += __shfl_xor(q, off, 64);
  }
  __shared__ float ss[4], qq[4];
  int wave = tid >> 6, lane = tid & 63;
  if (lane == 0) { ss[wave] = s; qq[wave] = q; }
  __syncthreads();
  s = ss[0] + ss[1] + ss[2] + ss[3];
  q = qq[0] + qq[1] + qq[2] + qq[3];
  float mu  = s * (1.0f / 1024.0f);
  float var = q * (1.0f / 1024.0f) - mu * mu;
  float rstd = rsqrtf(var + 1e-5f);
  float4 gg = *(const float4*)(g + tid * 4);
  float4 bv = *(const float4*)(bb + tid * 4);
  union { bf16_t h[4]; uint2 u; } o;
  o.h[0] = __float2bfloat16((v.x - mu) * rstd * gg.x + bv.x);
  o.h[1] = __float2bfloat16((v.y - mu) * rstd * gg.y + bv.y);
  o.h[2] = __float2bfloat16((v.z - mu) * rstd * gg.z + bv.z);
  o.h[3] = __float2bfloat16((v.w - mu) * rstd * gg.w + bv.w);
  *(uint2*)(y + (size_t)row * 1024 + tid * 4) = o.u;
}

// ---------------------------------------------------------------- GEMM
// m97 structure + 2-phase double-buffered staging (stage t+1 while computing t,
// one barrier per K-step). Optional split-K via gridDim.z (Kslice = per-z K).
// EPI 0: QKV split; 1: f32 +resid; 2: tanh->bf16; 3: f32; 4: f32 partial (no bias)
template <int EPI>
__global__ __launch_bounds__(256) void gemm_bt(
    const bf16_t* __restrict__ A, const bf16_t* __restrict__ Bw,
    const float* __restrict__ bias, void* __restrict__ out0,
    const float* __restrict__ resid, bf16_t* __restrict__ oks,
    bf16_t* __restrict__ ovt, int M, int N, int K, int Kslice) {
  __shared__ __align__(16) bf16_t As[2 * 128 * 32];
  __shared__ __align__(16) bf16_t Bs[2 * 128 * 32];
  const int tid  = threadIdx.x;
  const int lane = tid & 63;
  const int wave = tid >> 6;
  const int l15 = lane & 15, lg = lane >> 4;
  const int wr = (wave >> 1) * 64, wc = (wave & 1) * 64;
  const int bm = blockIdx.y * 128, bn = blockIdx.x * 128;
  const size_t Kz = (size_t)K;
  const int kstart = blockIdx.z * Kslice;
  const int srow = lane >> 2;        // 0..15
  const int scol = (lane & 3) * 8;   // 0,8,16,24

  f32x4 acc[4][4];
#pragma unroll
  for (int m = 0; m < 4; ++m)
#pragma unroll
    for (int n = 0; n < 4; ++n) acc[m][n] = (f32x4){0.f, 0.f, 0.f, 0.f};

  const bf16_t* Ab = A + (size_t)bm * Kz + kstart;
  const bf16_t* Bb = Bw + (size_t)bn * Kz + kstart;

  auto stage = [&](int t, int buf) {
    const int k0 = t * 32;
#pragma unroll
    for (int j = 0; j < 2; ++j) {
      const int cw = wave * 2 + j;
      gload_lds16(Ab + (size_t)(cw * 16 + srow) * Kz + k0 + scol, As + buf * 4096 + cw * 512);
      gload_lds16(Bb + (size_t)(cw * 16 + srow) * Kz + k0 + scol, Bs + buf * 4096 + cw * 512);
    }
  };

  const int NT = Kslice >> 5;
  stage(0, 0);
  __syncthreads();                 // vmcnt drained -> buf0 ready
  int buf = 0;
  for (int t = 0; t < NT; ++t) {
    if (t + 1 < NT) stage(t + 1, buf ^ 1);  // async loads fly during compute
    s16x8 af[4], bfv[4];
#pragma unroll
    for (int m = 0; m < 4; ++m)
      af[m] = *(const s16x8*)&As[buf * 4096 + (wr + m * 16 + l15) * 32 + lg * 8];
#pragma unroll
    for (int n = 0; n < 4; ++n)
      bfv[n] = *(const s16x8*)&Bs[buf * 4096 + (wc + n * 16 + l15) * 32 + lg * 8];
#pragma unroll
    for (int m = 0; m < 4; ++m)
#pragma unroll
      for (int n = 0; n < 4; ++n)
        acc[m][n] = __builtin_amdgcn_mfma_f32_16x16x32_bf16(af[m], bfv[n], acc[m][n], 0, 0, 0);
    __syncthreads();               // readers done with buf; vmcnt drained -> buf^1 ready
    buf ^= 1;
  }

#pragma unroll
  for (int m = 0; m < 4; ++m) {
    const int row0 = bm + wr + m * 16 + lg * 4;
#pragma unroll
    for (int n = 0; n < 4; ++n) {
      const int col = bn + wc + n * 16 + l15;
      const float bcol = (EPI == 4) ? 0.f : bias[col];
#pragma unroll
      for (int r = 0; r < 4; ++r) {
        const int rw = row0 + r;
        float c = acc[m][n][r] + bcol;
        if constexpr (EPI == 0) {
          if (col < 1024) {
            ((bf16_t*)out0)[(size_t)rw * 1024 + col] = __float2bfloat16(c);
          } else if (col < 1088) {
            int d = col - 1024, b = rw >> 11, t = rw & 2047;
            oks[((size_t)(b << 11) + t) * 64 + d] = __float2bfloat16(c);
          } else {
            int d = col - 1088, b = rw >> 11, t = rw & 2047;
            ovt[((size_t)b * 64 + d) * 2048 + t] = __float2bfloat16(c);
          }
        } else if constexpr (EPI == 1) {
          ((float*)out0)[(size_t)rw * N + col] = c + resid[(size_t)rw * N + col];
        } else if constexpr (EPI == 2) {
          ((bf16_t*)out0)[(size_t)rw * N + col] = __float2bfloat16(tanhf(c));
        } else if constexpr (EPI == 3) {
          ((float*)out0)[(size_t)rw * N + col] = c;
        } else {
          ((float*)out0)[((size_t)blockIdx.z * M + rw) * N + col] = c;
        }
      }
    }
  }
}

// out = p[0] + p[1] + bias  (FC2 split-K=2 combine)
__global__ __launch_bounds__(256) void fc2_reduce_k(const float* __restrict__ p,
                                                    const float* __restrict__ bias,
                                                    float* __restrict__ out) {
  int i = blockIdx.x * 256 + threadIdx.x;           // float4 index
  float4 a = ((const float4*)p)[i];
  float4 b = ((const float4*)(p + (size_t)4096 * 1024))[i];
  float4 bv = ((const float4*)bias)[i & 255];        // 1024 cols = 256 float4
  float4 o = {a.x + b.x + bv.x, a.y + b.y + bv.y, a.z + b.z + bv.z, a.w + b.w + bv.w};
  ((float4*)out)[i] = o;
}

// ---------------------------------------------------------------- flash attention v4
// Block-cooperative: 8 waves = 8 consecutive p (same batch) share K/V tiles
// staged in LDS (global_load_lds, pre-swizzled source + XOR-swizzled reads).
// Swapped QK (mfma(K,Q)): head = lane&15 -> per-lane softmax state.

template <bool MASK>
__device__ __forceinline__ void attn_tile(
    int t0, int p, const s16x8 (&qf)[2],
    const bf16_t* __restrict__ Ks, const bf16_t* __restrict__ Vs,
    bf16_t* __restrict__ Pl, int l15, int lg,
    float& m_run, float& l_part, f32x4 (&ao)[4]) {
  constexpr float SCL = 0.125f * 1.44269504088896f;  // scale * log2(e)
  const int sw7 = l15 & 7;

  f32x4 sc[4];
#pragma unroll
  for (int n = 0; n < 4; ++n) sc[n] = (f32x4){0.f, 0.f, 0.f, 0.f};
#pragma unroll
  for (int ks2 = 0; ks2 < 2; ++ks2) {
#pragma unroll
    for (int n = 0; n < 4; ++n) {
      s16x8 kf = *(const s16x8*)&Ks[(n * 16 + l15) * 64 + (((ks2 << 2) | lg) ^ sw7) * 8];
      sc[n] = __builtin_amdgcn_mfma_f32_16x16x32_bf16(kf, qf[ks2], sc[n], 0, 0, 0);
    }
  }

  float mx = -1e30f;
#pragma unroll
  for (int n = 0; n < 4; ++n) {
#pragma unroll
    for (int r = 0; r < 4; ++r) {
      float v = sc[n][r] * SCL;
      if (MASK && (t0 + n * 16 + lg * 4 + r > p)) v = -1e30f;
      sc[n][r] = v;
      mx = fmaxf(mx, v);
    }
  }
  if (__any(mx > m_run + 11.5f)) {
    float mxf = fmaxf(mx, __shfl_xor(mx, 16, 64));
    mxf = fmaxf(mxf, __shfl_xor(mxf, 32, 64));
    float mn = fmaxf(m_run, mxf);
    float alpha = exp2f(m_run - mn);   // per-lane, head = l15
    m_run = mn;
    l_part *= alpha;
#pragma unroll
    for (int r = 0; r < 4; ++r) {
      float ar = __shfl(alpha, lg * 4 + r, 64);  // alpha for head = lg*4+r
#pragma unroll
      for (int n2 = 0; n2 < 4; ++n2) ao[n2][r] *= ar;
    }
  }
#pragma unroll
  for (int n = 0; n < 4; ++n) {
    float e0 = exp2f(sc[n][0] - m_run);
    float e1 = exp2f(sc[n][1] - m_run);
    float e2 = exp2f(sc[n][2] - m_run);
    float e3 = exp2f(sc[n][3] - m_run);
    l_part += (e0 + e1) + (e2 + e3);
    uint2 d;
    d.x = cvt_pk_bf16(e0, e1);
    d.y = cvt_pk_bf16(e2, e3);
    *(uint2*)&Pl[l15 * 72 + n * 16 + lg * 4] = d;
  }
#pragma unroll
  for (int ks2 = 0; ks2 < 2; ++ks2) {
    s16x8 pa = *(const s16x8*)&Pl[l15 * 72 + ks2 * 32 + lg * 8];
#pragma unroll
    for (int n2 = 0; n2 < 4; ++n2) {
      s16x8 vf = *(const s16x8*)&Vs[(n2 * 16 + l15) * 64 + (((ks2 << 2) | lg) ^ sw7) * 8];
      ao[n2] = __builtin_amdgcn_mfma_f32_16x16x32_bf16(pa, vf, ao[n2], 0, 0, 0);
    }
  }
}

__global__ __launch_bounds__(512) void attn_k(const bf16_t* __restrict__ q,
                                              const bf16_t* __restrict__ ksp,
                                              const bf16_t* __restrict__ vtp,
                                              bf16_t* __restrict__ o) {
  __shared__ __align__(16) bf16_t Ks[64 * 64];
  __shared__ __align__(16) bf16_t Vs[64 * 64];
  __shared__ __align__(16) bf16_t Plds[8][16 * 72];
  const int tid = threadIdx.x, lane = tid & 63, wave = tid >> 6;
  const int l15 = lane & 15, lg = lane >> 4;
  const int grp = blockIdx.x >> 1;            // 0..255, big-p first
  const int b   = blockIdx.x & 1;
  const int pbase = 2040 - 8 * grp;
  const int p = pbase + wave;

  const bf16_t* qb_b = q   + (size_t)b * 32768 * 64;
  const bf16_t* ksb  = ksp + (size_t)b * 2048 * 64;
  const bf16_t* vtb  = vtp + (size_t)b * 64 * 2048;
  bf16_t*       ob   = o   + (size_t)b * 32768 * 64;
  bf16_t* Pl = &Plds[wave][0];

  const int srow = lane >> 3;
  const int scol = lane & 7;
  const int grow = wave * 8 + srow;
  const int gcol = scol ^ (grow & 7);
  const bf16_t* ksrc0 = ksb + (size_t)grow * 64 + gcol * 8;
  const bf16_t* vsrc0 = vtb + (size_t)grow * 2048 + gcol * 8;
  bf16_t* kdst = Ks + wave * 512;
  bf16_t* vdst = Vs + wave * 512;

  s16x8 qf[2];
  {
    const bf16_t* qptr = qb_b + (size_t)(16 * p + l15) * 64;
    qf[0] = *(const s16x8*)(qptr + lg * 8);
    qf[1] = *(const s16x8*)(qptr + 32 + lg * 8);
  }

  float m_run = -1e30f, l_part = 0.f;
  f32x4 ao[4];
#pragma unroll
  for (int n = 0; n < 4; ++n) ao[n] = (f32x4){0.f, 0.f, 0.f, 0.f};

  const int nsteps = (pbase + 71) >> 6;
  for (int tt = 0; tt < nsteps; ++tt) {
    const int t0 = tt * 64;
    __syncthreads();
    gload_lds16(ksrc0 + (size_t)t0 * 64, kdst);
    gload_lds16(vsrc0 + t0, vdst);
    __syncthreads();
    if (t0 <= p) {
      if (t0 + 63 <= p)
        attn_tile<false>(t0, p, qf, Ks, Vs, Pl, l15, lg, m_run, l_part, ao);
      else
        attn_tile<true>(t0, p, qf, Ks, Vs, Pl, l15, lg, m_run, l_part, ao);
    }
  }

  float l2 = l_part + __shfl_xor(l_part, 16, 64);
  l2 += __shfl_xor(l2, 32, 64);
  float rl[4];
#pragma unroll
  for (int r = 0; r < 4; ++r) rl[r] = 1.0f / __shfl(l2, lg * 4 + r, 64);
#pragma unroll
  for (int n2 = 0; n2 < 4; ++n2) {
#pragma unroll
    for (int r = 0; r < 4; ++r) {
      const int row = 16 * p + lg * 4 + r;
      ob[(size_t)row * 64 + n2 * 16 + l15] = __float2bfloat16(ao[n2][r] * rl[r]);
    }
  }
}

// ---------------------------------------------------------------- launch
extern "C" void kernel_launch(void* const* d_in, const int* in_sizes, int n_in,
                              void* d_out, int out_size, void* d_ws, size_t ws_size,
                              hipStream_t stream) {
  (void)in_sizes; (void)n_in; (void)out_size; (void)ws_size;
  const float* hidden = (const float*)d_in[0];
  const float* Wqkv   = (const float*)d_in[1];
  const float* bqkv   = (const float*)d_in[2];
  const float* Wout   = (const float*)d_in[3];
  const float* bout   = (const float*)d_in[4];
  const float* g1     = (const float*)d_in[5];
  const float* b1     = (const float*)d_in[6];
  const float* g2     = (const float*)d_in[7];
  const float* b2     = (const float*)d_in[8];
  const float* W1     = (const float*)d_in[9];
  const float* bfc1   = (const float*)d_in[10];
  const float* W2     = (const float*)d_in[11];
  const float* bfc2   = (const float*)d_in[12];

  float* out_h   = (float*)d_out;
  float* out_res = out_h + (size_t)4096 * 1024;

  char* ws = (char*)d_ws;
  auto alloc = [&](size_t bytes) {
    char* p = ws;
    ws += (bytes + 255) & ~(size_t)255;
    return p;
  };
  bf16_t* X1      = (bf16_t*)alloc((size_t)4096 * 1024 * 2);
  bf16_t* Wqkv_bf = (bf16_t*)alloc((size_t)1152 * 1024 * 2);
  float*  bias_r  = (float*)alloc(1152 * 4);
  bf16_t* qb      = (bf16_t*)alloc((size_t)4096 * 1024 * 2);
  bf16_t* ksum    = (bf16_t*)alloc((size_t)2 * 2048 * 64 * 2);
  bf16_t* vT      = (bf16_t*)alloc((size_t)2 * 64 * 2048 * 2);
  bf16_t* Ob      = (bf16_t*)alloc((size_t)4096 * 1024 * 2);
  bf16_t* Wout_bf = (bf16_t*)alloc((size_t)1024 * 1024 * 2);
  bf16_t* X2      = (bf16_t*)alloc((size_t)4096 * 1024 * 2);
  bf16_t* W1_bf   = (bf16_t*)alloc((size_t)4096 * 1024 * 2);
  bf16_t* W2_bf   = (bf16_t*)alloc((size_t)1024 * 4096 * 2);
  bf16_t* H1      = (bf16_t*)alloc((size_t)4096 * 4096 * 2);
  // FC2 split-K partials (2 x 16 MB f32) alias the ws head: X1..X2 are all
  // dead by FC2 time (stream order), H1/W2_bf live higher in ws.
  float* fc2_part = (float*)d_ws;

  // weight prep
  cast_bf16_k<<<512,  256, 0, stream>>>(Wqkv, Wqkv_bf, 1024 * 1024);
  cast_bf16_k<<<512,  256, 0, stream>>>(Wout, Wout_bf, 1024 * 1024);
  cast_bf16_k<<<2048, 256, 0, stream>>>(W1, W1_bf, 4096 * 1024);
  cast_bf16_k<<<2048, 256, 0, stream>>>(W2, W2_bf, 1024 * 4096);
  reduce_kv_k<<<128, 256, 0, stream>>>(Wqkv, Wqkv_bf + (size_t)1024 * 1024);
  bias_prep_k<<<5, 256, 0, stream>>>(bqkv, bias_r);

  // LN1
  ln_cast_k<<<4096, 256, 0, stream>>>(hidden, g1, b1, X1);
  // QKV (reduced): M=4096, N=1152, K=1024
  gemm_bt<0><<<dim3(9, 32), 256, 0, stream>>>(X1, Wqkv_bf, bias_r, qb, nullptr, ksum, vT,
                                              4096, 1152, 1024, 1024);
  // attention: 512 blocks x 8 waves; block shares staged K/V tiles
  attn_k<<<512, 512, 0, stream>>>(qb, ksum, vT, Ob);
  // Wout + residual -> out_res (f32)
  gemm_bt<1><<<dim3(8, 32), 256, 0, stream>>>(Ob, Wout_bf, bout, out_res, hidden, nullptr,
                                              nullptr, 4096, 1024, 1024, 1024);
  // LN2
  ln_cast_k<<<4096, 256, 0, stream>>>(out_res, g2, b2, X2);
  // FC1 + tanh
  gemm_bt<2><<<dim3(32, 32), 256, 0, stream>>>(X2, W1_bf, bfc1, H1, nullptr, nullptr, nullptr,
                                               4096, 4096, 1024, 1024);
  // FC2 split-K=2 -> f32 partials, then combine + bias -> out_h
  gemm_bt<4><<<dim3(8, 32, 2), 256, 0, stream>>>(H1, W2_bf, nullptr, fc2_part, nullptr, nullptr,
                                                 nullptr, 4096, 1024, 4096, 2048);
  fc2_reduce_k<<<4096, 256, 0, stream>>>(fc2_part, bfc2, out_h);
}

// Round 7
// 265.373 us; speedup vs baseline: 1.7998x; 1.0083x over previous
//
#include <hip/hip_runtime.h>
#include <hip/hip_bf16.h>

typedef __attribute__((ext_vector_type(8))) short s16x8;
typedef __attribute__((ext_vector_type(4))) float f32x4;
typedef __hip_bfloat16 bf16_t;

// ---------------------------------------------------------------- helpers
__device__ __forceinline__ void gload_lds16(const void* g, void* l) {
  __builtin_amdgcn_global_load_lds(
      (__attribute__((address_space(1))) void*)(g),
      (__attribute__((address_space(3))) void*)(l), 16, 0, 0);
}

__device__ __forceinline__ unsigned cvt_pk_bf16(float lo, float hi) {
  unsigned r;
  asm("v_cvt_pk_bf16_f32 %0, %1, %2" : "=v"(r) : "v"(lo), "v"(hi));
  return r;
}

// ---------------------------------------------------------------- weight prep
__global__ void cast_bf16_k(const float* __restrict__ x, bf16_t* __restrict__ y, int n) {
  int i = (blockIdx.x * 256 + threadIdx.x) * 8;
  if (i >= n) return;
  float4 a = *(const float4*)(x + i);
  float4 b = *(const float4*)(x + i + 4);
  union { bf16_t h[8]; s16x8 v; } u;
  u.h[0] = __float2bfloat16(a.x); u.h[1] = __float2bfloat16(a.y);
  u.h[2] = __float2bfloat16(a.z); u.h[3] = __float2bfloat16(a.w);
  u.h[4] = __float2bfloat16(b.x); u.h[5] = __float2bfloat16(b.y);
  u.h[6] = __float2bfloat16(b.z); u.h[7] = __float2bfloat16(b.w);
  *(s16x8*)(y + i) = u.v;
}

// Wk_red[d][:] = sum_h Wqkv[1024+h*64+d][:]; likewise Wv_red from rows 2048+.
__global__ void reduce_kv_k(const float* __restrict__ Wqkv, bf16_t* __restrict__ Wred) {
  int d   = blockIdx.x & 63;
  int isv = blockIdx.x >> 6;            // 0 = k, 1 = v
  int col = threadIdx.x * 4;
  const float* base = Wqkv + (size_t)(1024 + isv * 1024 + d) * 1024 + col;
  float4 s = {0.f, 0.f, 0.f, 0.f};
#pragma unroll
  for (int h = 0; h < 16; ++h) {
    float4 t = *(const float4*)(base + (size_t)h * 64 * 1024);
    s.x += t.x; s.y += t.y; s.z += t.z; s.w += t.w;
  }
  union { bf16_t h[4]; uint2 u; } o;
  o.h[0] = __float2bfloat16(s.x); o.h[1] = __float2bfloat16(s.y);
  o.h[2] = __float2bfloat16(s.z); o.h[3] = __float2bfloat16(s.w);
  *(uint2*)(Wred + (size_t)(isv * 64 + d) * 1024 + col) = o.u;
}

__global__ void bias_prep_k(const float* __restrict__ bqkv, float* __restrict__ br) {
  int i = blockIdx.x * 256 + threadIdx.x;
  if (i >= 1152) return;
  if (i < 1024) { br[i] = bqkv[i]; return; }
  int d = i - 1024;
  int off = (d < 64) ? (1024 + d) : (2048 + (d - 64));
  float s = 0.f;
#pragma unroll
  for (int h = 0; h < 16; ++h) s += bqkv[off + h * 64];
  br[i] = s;
}

// ---------------------------------------------------------------- layernorm + cast
__global__ __launch_bounds__(256) void ln_cast_k(const float* __restrict__ x,
                                                 const float* __restrict__ g,
                                                 const float* __restrict__ bb,
                                                 bf16_t* __restrict__ y) {
  int row = blockIdx.x, tid = threadIdx.x;
  float4 v = *(const float4*)(x + (size_t)row * 1024 + tid * 4);
  float s = v.x + v.y + v.z + v.w;
  float q = v.x * v.x + v.y * v.y + v.z * v.z + v.w * v.w;
#pragma unroll
  for (int off = 1; off < 64; off <<= 1) {
    s += __shfl_xor(s, off, 64);
    q += __shfl_xor(q, off, 64);
  }
  __shared__ float ss[4], qq[4];
  int wave = tid >> 6, lane = tid & 63;
  if (lane == 0) { ss[wave] = s; qq[wave] = q; }
  __syncthreads();
  s = ss[0] + ss[1] + ss[2] + ss[3];
  q = qq[0] + qq[1] + qq[2] + qq[3];
  float mu  = s * (1.0f / 1024.0f);
  float var = q * (1.0f / 1024.0f) - mu * mu;
  float rstd = rsqrtf(var + 1e-5f);
  float4 gg = *(const float4*)(g + tid * 4);
  float4 bv = *(const float4*)(bb + tid * 4);
  union { bf16_t h[4]; uint2 u; } o;
  o.h[0] = __float2bfloat16((v.x - mu) * rstd * gg.x + bv.x);
  o.h[1] = __float2bfloat16((v.y - mu) * rstd * gg.y + bv.y);
  o.h[2] = __float2bfloat16((v.z - mu) * rstd * gg.z + bv.z);
  o.h[3] = __float2bfloat16((v.w - mu) * rstd * gg.w + bv.w);
  *(uint2*)(y + (size_t)row * 1024 + tid * 4) = o.u;
}

// ---------------------------------------------------------------- GEMM
// m97 tile + 3-buffer counted-vmcnt pipeline (T4): stage(t+1),(t+2) stay in
// flight across raw s_barrier; never drain vmcnt to 0 in the loop. T2 swizzle:
// LDS slot (r,c) holds global chunk c^((r>>1)&3) (pre-swizzled source), reads
// XOR the same -> max bank load 2 (free). Optional split-K via gridDim.z.
// EPI 0: QKV split; 1: f32 +resid; 2: tanh->bf16; 3: f32; 4: f32 partial
template <int EPI>
__global__ __launch_bounds__(256) void gemm_bt(
    const bf16_t* __restrict__ A, const bf16_t* __restrict__ Bw,
    const float* __restrict__ bias, void* __restrict__ out0,
    const float* __restrict__ resid, bf16_t* __restrict__ oks,
    bf16_t* __restrict__ ovt, int M, int N, int K, int Kslice) {
  __shared__ __align__(16) bf16_t As[3 * 128 * 32];
  __shared__ __align__(16) bf16_t Bs[3 * 128 * 32];
  const int tid  = threadIdx.x;
  const int lane = tid & 63;
  const int wave = tid >> 6;
  const int l15 = lane & 15, lg = lane >> 4;
  const int wr = (wave >> 1) * 64, wc = (wave & 1) * 64;
  const int bm = blockIdx.y * 128, bn = blockIdx.x * 128;
  const size_t Kz = (size_t)K;
  const int kstart = blockIdx.z * Kslice;
  const int srow = lane >> 2;                            // 0..15
  const int scol = ((lane & 3) ^ ((lane >> 3) & 3)) * 8; // pre-swizzled chunk

  f32x4 acc[4][4];
#pragma unroll
  for (int m = 0; m < 4; ++m)
#pragma unroll
    for (int n = 0; n < 4; ++n) acc[m][n] = (f32x4){0.f, 0.f, 0.f, 0.f};

  const bf16_t* Ab = A + (size_t)bm * Kz + kstart;
  const bf16_t* Bb = Bw + (size_t)bn * Kz + kstart;

  auto stage = [&](int t, int buf) {
    const int k0 = t * 32;
#pragma unroll
    for (int j = 0; j < 2; ++j) {
      const int cw = wave * 2 + j;
      gload_lds16(Ab + (size_t)(cw * 16 + srow) * Kz + k0 + scol, As + buf * 4096 + cw * 512);
      gload_lds16(Bb + (size_t)(cw * 16 + srow) * Kz + k0 + scol, Bs + buf * 4096 + cw * 512);
    }
  };

  const int NT = Kslice >> 5;
  stage(0, 0);
  stage(1, 1);
  const int rdoff = (lg ^ ((l15 >> 1) & 3)) * 8;   // swizzled read chunk
  int rb = 0, nb = 1, stb = 2;
  for (int t = 0; t < NT; ++t) {
    // stage(t) complete everywhere; stage(t+1)/(t+2) keep flying (counted).
    if (t == NT - 1) asm volatile("s_waitcnt vmcnt(0) lgkmcnt(0)" ::: "memory");
    else             asm volatile("s_waitcnt vmcnt(4) lgkmcnt(0)" ::: "memory");
    __builtin_amdgcn_s_barrier();
    if (t + 2 < NT) stage(t + 2, stb);
    s16x8 af[4], bfv[4];
#pragma unroll
    for (int m = 0; m < 4; ++m)
      af[m] = *(const s16x8*)&As[rb * 4096 + (wr + m * 16 + l15) * 32 + rdoff];
#pragma unroll
    for (int n = 0; n < 4; ++n)
      bfv[n] = *(const s16x8*)&Bs[rb * 4096 + (wc + n * 16 + l15) * 32 + rdoff];
#pragma unroll
    for (int m = 0; m < 4; ++m)
#pragma unroll
      for (int n = 0; n < 4; ++n)
        acc[m][n] = __builtin_amdgcn_mfma_f32_16x16x32_bf16(af[m], bfv[n], acc[m][n], 0, 0, 0);
    int tmp = rb; rb = nb; nb = stb; stb = tmp;
  }

#pragma unroll
  for (int m = 0; m < 4; ++m) {
    const int row0 = bm + wr + m * 16 + lg * 4;
#pragma unroll
    for (int n = 0; n < 4; ++n) {
      const int col = bn + wc + n * 16 + l15;
      const float bcol = (EPI == 4) ? 0.f : bias[col];
#pragma unroll
      for (int r = 0; r < 4; ++r) {
        const int rw = row0 + r;
        float c = acc[m][n][r] + bcol;
        if constexpr (EPI == 0) {
          if (col < 1024) {
            ((bf16_t*)out0)[(size_t)rw * 1024 + col] = __float2bfloat16(c);
          } else if (col < 1088) {
            int d = col - 1024, b = rw >> 11, t = rw & 2047;
            oks[((size_t)(b << 11) + t) * 64 + d] = __float2bfloat16(c);
          } else {
            int d = col - 1088, b = rw >> 11, t = rw & 2047;
            ovt[((size_t)b * 64 + d) * 2048 + t] = __float2bfloat16(c);
          }
        } else if constexpr (EPI == 1) {
          ((float*)out0)[(size_t)rw * N + col] = c + resid[(size_t)rw * N + col];
        } else if constexpr (EPI == 2) {
          ((bf16_t*)out0)[(size_t)rw * N + col] = __float2bfloat16(tanhf(c));
        } else if constexpr (EPI == 3) {
          ((float*)out0)[(size_t)rw * N + col] = c;
        } else {
          ((float*)out0)[((size_t)blockIdx.z * M + rw) * N + col] = c;
        }
      }
    }
  }
}

// out = p[0] + p[1] + bias  (FC2 split-K=2 combine)
__global__ __launch_bounds__(256) void fc2_reduce_k(const float* __restrict__ p,
                                                    const float* __restrict__ bias,
                                                    float* __restrict__ out) {
  int i = blockIdx.x * 256 + threadIdx.x;           // float4 index
  float4 a = ((const float4*)p)[i];
  float4 b = ((const float4*)(p + (size_t)4096 * 1024))[i];
  float4 bv = ((const float4*)bias)[i & 255];        // 1024 cols = 256 float4
  float4 o = {a.x + b.x + bv.x, a.y + b.y + bv.y, a.z + b.z + bv.z, a.w + b.w + bv.w};
  ((float4*)out)[i] = o;
}

// ---------------------------------------------------------------- flash attention v4
// Block-cooperative: 8 waves = 8 consecutive p (same batch) share K/V tiles
// staged in LDS (global_load_lds, pre-swizzled source + XOR-swizzled reads).
// Swapped QK (mfma(K,Q)): head = lane&15 -> per-lane softmax state.

template <bool MASK>
__device__ __forceinline__ void attn_tile(
    int t0, int p, const s16x8 (&qf)[2],
    const bf16_t* __restrict__ Ks, const bf16_t* __restrict__ Vs,
    bf16_t* __restrict__ Pl, int l15, int lg,
    float& m_run, float& l_part, f32x4 (&ao)[4]) {
  constexpr float SCL = 0.125f * 1.44269504088896f;  // scale * log2(e)
  const int sw7 = l15 & 7;

  f32x4 sc[4];
#pragma unroll
  for (int n = 0; n < 4; ++n) sc[n] = (f32x4){0.f, 0.f, 0.f, 0.f};
#pragma unroll
  for (int ks2 = 0; ks2 < 2; ++ks2) {
#pragma unroll
    for (int n = 0; n < 4; ++n) {
      s16x8 kf = *(const s16x8*)&Ks[(n * 16 + l15) * 64 + (((ks2 << 2) | lg) ^ sw7) * 8];
      sc[n] = __builtin_amdgcn_mfma_f32_16x16x32_bf16(kf, qf[ks2], sc[n], 0, 0, 0);
    }
  }

  float mx = -1e30f;
#pragma unroll
  for (int n = 0; n < 4; ++n) {
#pragma unroll
    for (int r = 0; r < 4; ++r) {
      float v = sc[n][r] * SCL;
      if (MASK && (t0 + n * 16 + lg * 4 + r > p)) v = -1e30f;
      sc[n][r] = v;
      mx = fmaxf(mx, v);
    }
  }
  if (__any(mx > m_run + 11.5f)) {
    float mxf = fmaxf(mx, __shfl_xor(mx, 16, 64));
    mxf = fmaxf(mxf, __shfl_xor(mxf, 32, 64));
    float mn = fmaxf(m_run, mxf);
    float alpha = exp2f(m_run - mn);   // per-lane, head = l15
    m_run = mn;
    l_part *= alpha;
#pragma unroll
    for (int r = 0; r < 4; ++r) {
      float ar = __shfl(alpha, lg * 4 + r, 64);  // alpha for head = lg*4+r
#pragma unroll
      for (int n2 = 0; n2 < 4; ++n2) ao[n2][r] *= ar;
    }
  }
#pragma unroll
  for (int n = 0; n < 4; ++n) {
    float e0 = exp2f(sc[n][0] - m_run);
    float e1 = exp2f(sc[n][1] - m_run);
    float e2 = exp2f(sc[n][2] - m_run);
    float e3 = exp2f(sc[n][3] - m_run);
    l_part += (e0 + e1) + (e2 + e3);
    uint2 d;
    d.x = cvt_pk_bf16(e0, e1);
    d.y = cvt_pk_bf16(e2, e3);
    *(uint2*)&Pl[l15 * 72 + n * 16 + lg * 4] = d;
  }
#pragma unroll
  for (int ks2 = 0; ks2 < 2; ++ks2) {
    s16x8 pa = *(const s16x8*)&Pl[l15 * 72 + ks2 * 32 + lg * 8];
#pragma unroll
    for (int n2 = 0; n2 < 4; ++n2) {
      s16x8 vf = *(const s16x8*)&Vs[(n2 * 16 + l15) * 64 + (((ks2 << 2) | lg) ^ sw7) * 8];
      ao[n2] = __builtin_amdgcn_mfma_f32_16x16x32_bf16(pa, vf, ao[n2], 0, 0, 0);
    }
  }
}

__global__ __launch_bounds__(512) void attn_k(const bf16_t* __restrict__ q,
                                              const bf16_t* __restrict__ ksp,
                                              const bf16_t* __restrict__ vtp,
                                              bf16_t* __restrict__ o) {
  __shared__ __align__(16) bf16_t Ks[64 * 64];
  __shared__ __align__(16) bf16_t Vs[64 * 64];
  __shared__ __align__(16) bf16_t Plds[8][16 * 72];
  const int tid = threadIdx.x, lane = tid & 63, wave = tid >> 6;
  const int l15 = lane & 15, lg = lane >> 4;
  const int grp = blockIdx.x >> 1;            // 0..255, big-p first
  const int b   = blockIdx.x & 1;
  const int pbase = 2040 - 8 * grp;
  const int p = pbase + wave;

  const bf16_t* qb_b = q   + (size_t)b * 32768 * 64;
  const bf16_t* ksb  = ksp + (size_t)b * 2048 * 64;
  const bf16_t* vtb  = vtp + (size_t)b * 64 * 2048;
  bf16_t*       ob   = o   + (size_t)b * 32768 * 64;
  bf16_t* Pl = &Plds[wave][0];

  const int srow = lane >> 3;
  const int scol = lane & 7;
  const int grow = wave * 8 + srow;
  const int gcol = scol ^ (grow & 7);
  const bf16_t* ksrc0 = ksb + (size_t)grow * 64 + gcol * 8;
  const bf16_t* vsrc0 = vtb + (size_t)grow * 2048 + gcol * 8;
  bf16_t* kdst = Ks + wave * 512;
  bf16_t* vdst = Vs + wave * 512;

  s16x8 qf[2];
  {
    const bf16_t* qptr = qb_b + (size_t)(16 * p + l15) * 64;
    qf[0] = *(const s16x8*)(qptr + lg * 8);
    qf[1] = *(const s16x8*)(qptr + 32 + lg * 8);
  }

  float m_run = -1e30f, l_part = 0.f;
  f32x4 ao[4];
#pragma unroll
  for (int n = 0; n < 4; ++n) ao[n] = (f32x4){0.f, 0.f, 0.f, 0.f};

  const int nsteps = (pbase + 71) >> 6;
  for (int tt = 0; tt < nsteps; ++tt) {
    const int t0 = tt * 64;
    __syncthreads();
    gload_lds16(ksrc0 + (size_t)t0 * 64, kdst);
    gload_lds16(vsrc0 + t0, vdst);
    __syncthreads();
    if (t0 <= p) {
      if (t0 + 63 <= p)
        attn_tile<false>(t0, p, qf, Ks, Vs, Pl, l15, lg, m_run, l_part, ao);
      else
        attn_tile<true>(t0, p, qf, Ks, Vs, Pl, l15, lg, m_run, l_part, ao);
    }
  }

  float l2 = l_part + __shfl_xor(l_part, 16, 64);
  l2 += __shfl_xor(l2, 32, 64);
  float rl[4];
#pragma unroll
  for (int r = 0; r < 4; ++r) rl[r] = 1.0f / __shfl(l2, lg * 4 + r, 64);
#pragma unroll
  for (int n2 = 0; n2 < 4; ++n2) {
#pragma unroll
    for (int r = 0; r < 4; ++r) {
      const int row = 16 * p + lg * 4 + r;
      ob[(size_t)row * 64 + n2 * 16 + l15] = __float2bfloat16(ao[n2][r] * rl[r]);
    }
  }
}

// ---------------------------------------------------------------- launch
extern "C" void kernel_launch(void* const* d_in, const int* in_sizes, int n_in,
                              void* d_out, int out_size, void* d_ws, size_t ws_size,
                              hipStream_t stream) {
  (void)in_sizes; (void)n_in; (void)out_size; (void)ws_size;
  const float* hidden = (const float*)d_in[0];
  const float* Wqkv   = (const float*)d_in[1];
  const float* bqkv   = (const float*)d_in[2];
  const float* Wout   = (const float*)d_in[3];
  const float* bout   = (const float*)d_in[4];
  const float* g1     = (const float*)d_in[5];
  const float* b1     = (const float*)d_in[6];
  const float* g2     = (const float*)d_in[7];
  const float* b2     = (const float*)d_in[8];
  const float* W1     = (const float*)d_in[9];
  const float* bfc1   = (const float*)d_in[10];
  const float* W2     = (const float*)d_in[11];
  const float* bfc2   = (const float*)d_in[12];

  float* out_h   = (float*)d_out;
  float* out_res = out_h + (size_t)4096 * 1024;

  char* ws = (char*)d_ws;
  auto alloc = [&](size_t bytes) {
    char* p = ws;
    ws += (bytes + 255) & ~(size_t)255;
    return p;
  };
  bf16_t* X1      = (bf16_t*)alloc((size_t)4096 * 1024 * 2);
  bf16_t* Wqkv_bf = (bf16_t*)alloc((size_t)1152 * 1024 * 2);
  float*  bias_r  = (float*)alloc(1152 * 4);
  bf16_t* qb      = (bf16_t*)alloc((size_t)4096 * 1024 * 2);
  bf16_t* ksum    = (bf16_t*)alloc((size_t)2 * 2048 * 64 * 2);
  bf16_t* vT      = (bf16_t*)alloc((size_t)2 * 64 * 2048 * 2);
  bf16_t* Ob      = (bf16_t*)alloc((size_t)4096 * 1024 * 2);
  bf16_t* Wout_bf = (bf16_t*)alloc((size_t)1024 * 1024 * 2);
  bf16_t* X2      = (bf16_t*)alloc((size_t)4096 * 1024 * 2);
  bf16_t* W1_bf   = (bf16_t*)alloc((size_t)4096 * 1024 * 2);
  bf16_t* W2_bf   = (bf16_t*)alloc((size_t)1024 * 4096 * 2);
  bf16_t* H1      = (bf16_t*)alloc((size_t)4096 * 4096 * 2);
  // FC2 split-K partials (2 x 16 MB f32) alias the ws head: X1..X2 (~37 MB)
  // are all dead by FC2 time (stream order); H1/W1_bf/W2_bf live higher.
  float* fc2_part = (float*)d_ws;

  // weight prep
  cast_bf16_k<<<512,  256, 0, stream>>>(Wqkv, Wqkv_bf, 1024 * 1024);
  cast_bf16_k<<<512,  256, 0, stream>>>(Wout, Wout_bf, 1024 * 1024);
  cast_bf16_k<<<2048, 256, 0, stream>>>(W1, W1_bf, 4096 * 1024);
  cast_bf16_k<<<2048, 256, 0, stream>>>(W2, W2_bf, 1024 * 4096);
  reduce_kv_k<<<128, 256, 0, stream>>>(Wqkv, Wqkv_bf + (size_t)1024 * 1024);
  bias_prep_k<<<5, 256, 0, stream>>>(bqkv, bias_r);

  // LN1
  ln_cast_k<<<4096, 256, 0, stream>>>(hidden, g1, b1, X1);
  // QKV (reduced): M=4096, N=1152, K=1024
  gemm_bt<0><<<dim3(9, 32), 256, 0, stream>>>(X1, Wqkv_bf, bias_r, qb, nullptr, ksum, vT,
                                              4096, 1152, 1024, 1024);
  // attention: 512 blocks x 8 waves; block shares staged K/V tiles
  attn_k<<<512, 512, 0, stream>>>(qb, ksum, vT, Ob);
  // Wout + residual -> out_res (f32)
  gemm_bt<1><<<dim3(8, 32), 256, 0, stream>>>(Ob, Wout_bf, bout, out_res, hidden, nullptr,
                                              nullptr, 4096, 1024, 1024, 1024);
  // LN2
  ln_cast_k<<<4096, 256, 0, stream>>>(out_res, g2, b2, X2);
  // FC1 + tanh
  gemm_bt<2><<<dim3(32, 32), 256, 0, stream>>>(X2, W1_bf, bfc1, H1, nullptr, nullptr, nullptr,
                                               4096, 4096, 1024, 1024);
  // FC2 split-K=2 -> f32 partials, then combine + bias -> out_h
  gemm_bt<4><<<dim3(8, 32, 2), 256, 0, stream>>>(H1, W2_bf, nullptr, fc2_part, nullptr, nullptr,
                                                 nullptr, 4096, 1024, 4096, 2048);
  fc2_reduce_k<<<4096, 256, 0, stream>>>(fc2_part, bfc2, out_h);
}

// Round 8
// 257.865 us; speedup vs baseline: 1.8522x; 1.0291x over previous
//
#include <hip/hip_runtime.h>
#include <hip/hip_bf16.h>

typedef __attribute__((ext_vector_type(8))) short s16x8;
typedef __attribute__((ext_vector_type(4))) float f32x4;
typedef __hip_bfloat16 bf16_t;

// ---------------------------------------------------------------- helpers
__device__ __forceinline__ void gload_lds16(const void* g, void* l) {
  __builtin_amdgcn_global_load_lds(
      (__attribute__((address_space(1))) void*)(g),
      (__attribute__((address_space(3))) void*)(l), 16, 0, 0);
}

__device__ __forceinline__ unsigned cvt_pk_bf16(float lo, float hi) {
  unsigned r;
  asm("v_cvt_pk_bf16_f32 %0, %1, %2" : "=v"(r) : "v"(lo), "v"(hi));
  return r;
}

// ---------------------------------------------------------------- weight prep
// All four weight casts fused into one launch. Chunk = 8 elements.
__global__ void cast_all_k(const float* __restrict__ Wqkv, const float* __restrict__ Wout,
                           const float* __restrict__ W1, const float* __restrict__ W2,
                           bf16_t* __restrict__ Wqkv_bf, bf16_t* __restrict__ Wout_bf,
                           bf16_t* __restrict__ W1_bf, bf16_t* __restrict__ W2_bf) {
  int c = blockIdx.x * 256 + threadIdx.x;
  const float* src; bf16_t* dst; int off;
  if (c < 131072)      { src = Wqkv; dst = Wqkv_bf; off = c; }            // q rows: 1M elems
  else if (c < 262144) { src = Wout; dst = Wout_bf; off = c - 131072; }
  else if (c < 786432) { src = W1;   dst = W1_bf;   off = c - 262144; }
  else                 { src = W2;   dst = W2_bf;   off = c - 786432; }
  int i = off * 8;
  float4 a = *(const float4*)(src + i);
  float4 b = *(const float4*)(src + i + 4);
  union { bf16_t h[8]; s16x8 v; } u;
  u.h[0] = __float2bfloat16(a.x); u.h[1] = __float2bfloat16(a.y);
  u.h[2] = __float2bfloat16(a.z); u.h[3] = __float2bfloat16(a.w);
  u.h[4] = __float2bfloat16(b.x); u.h[5] = __float2bfloat16(b.y);
  u.h[6] = __float2bfloat16(b.z); u.h[7] = __float2bfloat16(b.w);
  *(s16x8*)(dst + i) = u.v;
}

// Wk_red[d][:] = sum_h Wqkv[1024+h*64+d][:]; likewise Wv_red from rows 2048+.
__global__ void reduce_kv_k(const float* __restrict__ Wqkv, bf16_t* __restrict__ Wred) {
  int d   = blockIdx.x & 63;
  int isv = blockIdx.x >> 6;            // 0 = k, 1 = v
  int col = threadIdx.x * 4;
  const float* base = Wqkv + (size_t)(1024 + isv * 1024 + d) * 1024 + col;
  float4 s = {0.f, 0.f, 0.f, 0.f};
#pragma unroll
  for (int h = 0; h < 16; ++h) {
    float4 t = *(const float4*)(base + (size_t)h * 64 * 1024);
    s.x += t.x; s.y += t.y; s.z += t.z; s.w += t.w;
  }
  union { bf16_t h[4]; uint2 u; } o;
  o.h[0] = __float2bfloat16(s.x); o.h[1] = __float2bfloat16(s.y);
  o.h[2] = __float2bfloat16(s.z); o.h[3] = __float2bfloat16(s.w);
  *(uint2*)(Wred + (size_t)(isv * 64 + d) * 1024 + col) = o.u;
}

__global__ void bias_prep_k(const float* __restrict__ bqkv, float* __restrict__ br) {
  int i = blockIdx.x * 256 + threadIdx.x;
  if (i >= 1152) return;
  if (i < 1024) { br[i] = bqkv[i]; return; }
  int d = i - 1024;
  int off = (d < 64) ? (1024 + d) : (2048 + (d - 64));
  float s = 0.f;
#pragma unroll
  for (int h = 0; h < 16; ++h) s += bqkv[off + h * 64];
  br[i] = s;
}

// ---------------------------------------------------------------- layernorm + cast
__global__ __launch_bounds__(256) void ln_cast_k(const float* __restrict__ x,
                                                 const float* __restrict__ g,
                                                 const float* __restrict__ bb,
                                                 bf16_t* __restrict__ y) {
  int row = blockIdx.x, tid = threadIdx.x;
  float4 v = *(const float4*)(x + (size_t)row * 1024 + tid * 4);
  float s = v.x + v.y + v.z + v.w;
  float q = v.x * v.x + v.y * v.y + v.z * v.z + v.w * v.w;
#pragma unroll
  for (int off = 1; off < 64; off <<= 1) {
    s += __shfl_xor(s, off, 64);
    q += __shfl_xor(q, off, 64);
  }
  __shared__ float ss[4], qq[4];
  int wave = tid >> 6, lane = tid & 63;
  if (lane == 0) { ss[wave] = s; qq[wave] = q; }
  __syncthreads();
  s = ss[0] + ss[1] + ss[2] + ss[3];
  q = qq[0] + qq[1] + qq[2] + qq[3];
  float mu  = s * (1.0f / 1024.0f);
  float var = q * (1.0f / 1024.0f) - mu * mu;
  float rstd = rsqrtf(var + 1e-5f);
  float4 gg = *(const float4*)(g + tid * 4);
  float4 bv = *(const float4*)(bb + tid * 4);
  union { bf16_t h[4]; uint2 u; } o;
  o.h[0] = __float2bfloat16((v.x - mu) * rstd * gg.x + bv.x);
  o.h[1] = __float2bfloat16((v.y - mu) * rstd * gg.y + bv.y);
  o.h[2] = __float2bfloat16((v.z - mu) * rstd * gg.z + bv.z);
  o.h[3] = __float2bfloat16((v.w - mu) * rstd * gg.w + bv.w);
  *(uint2*)(y + (size_t)row * 1024 + tid * 4) = o.u;
}

// ---------------------------------------------------------------- GEMM 128x128
// m97 tile, 2-buffer drain (compiler emits vmcnt0+lgkm0 before s_barrier),
// T2 swizzle both-sides (verified conflict-free R7). Split-K via gridDim.z.
// EPI 2: tanh->bf16 (FC1); EPI 4: bf16 partial, no bias (FC2 split-K)
template <int EPI>
__global__ __launch_bounds__(256) void gemm_bt(
    const bf16_t* __restrict__ A, const bf16_t* __restrict__ Bw,
    const float* __restrict__ bias, void* __restrict__ out0,
    int M, int N, int K, int Kslice) {
  __shared__ __align__(16) bf16_t As[2 * 128 * 32];
  __shared__ __align__(16) bf16_t Bs[2 * 128 * 32];
  const int tid  = threadIdx.x;
  const int lane = tid & 63;
  const int wave = tid >> 6;
  const int l15 = lane & 15, lg = lane >> 4;
  const int wr = (wave >> 1) * 64, wc = (wave & 1) * 64;
  const int bm = blockIdx.y * 128, bn = blockIdx.x * 128;
  const size_t Kz = (size_t)K;
  const int kstart = blockIdx.z * Kslice;
  const int srow = lane >> 2;                            // 0..15
  const int scol = ((lane & 3) ^ ((lane >> 3) & 3)) * 8; // pre-swizzled chunk

  f32x4 acc[4][4];
#pragma unroll
  for (int m = 0; m < 4; ++m)
#pragma unroll
    for (int n = 0; n < 4; ++n) acc[m][n] = (f32x4){0.f, 0.f, 0.f, 0.f};

  const bf16_t* Ab = A + (size_t)bm * Kz + kstart;
  const bf16_t* Bb = Bw + (size_t)bn * Kz + kstart;

  auto stage = [&](int t, int buf) {
    const int k0 = t * 32;
#pragma unroll
    for (int j = 0; j < 2; ++j) {
      const int cw = wave * 2 + j;
      gload_lds16(Ab + (size_t)(cw * 16 + srow) * Kz + k0 + scol, As + buf * 4096 + cw * 512);
      gload_lds16(Bb + (size_t)(cw * 16 + srow) * Kz + k0 + scol, Bs + buf * 4096 + cw * 512);
    }
  };

  const int NT = Kslice >> 5;
  const int rdoff = (lg ^ ((l15 >> 1) & 3)) * 8;   // swizzled read chunk
  stage(0, 0);
  __syncthreads();
  int buf = 0;
  for (int t = 0; t < NT; ++t) {
    if (t + 1 < NT) stage(t + 1, buf ^ 1);
    s16x8 af[4], bfv[4];
#pragma unroll
    for (int m = 0; m < 4; ++m)
      af[m] = *(const s16x8*)&As[buf * 4096 + (wr + m * 16 + l15) * 32 + rdoff];
#pragma unroll
    for (int n = 0; n < 4; ++n)
      bfv[n] = *(const s16x8*)&Bs[buf * 4096 + (wc + n * 16 + l15) * 32 + rdoff];
#pragma unroll
    for (int m = 0; m < 4; ++m)
#pragma unroll
      for (int n = 0; n < 4; ++n)
        acc[m][n] = __builtin_amdgcn_mfma_f32_16x16x32_bf16(af[m], bfv[n], acc[m][n], 0, 0, 0);
    __syncthreads();
    buf ^= 1;
  }

#pragma unroll
  for (int m = 0; m < 4; ++m) {
    const int row0 = bm + wr + m * 16 + lg * 4;
#pragma unroll
    for (int n = 0; n < 4; ++n) {
      const int col = bn + wc + n * 16 + l15;
      const float bcol = (EPI == 4) ? 0.f : bias[col];
#pragma unroll
      for (int r = 0; r < 4; ++r) {
        const int rw = row0 + r;
        float c = acc[m][n][r] + bcol;
        if constexpr (EPI == 2) {
          ((bf16_t*)out0)[(size_t)rw * N + col] = __float2bfloat16(tanhf(c));
        } else {
          ((bf16_t*)out0)[((size_t)blockIdx.z * M + rw) * N + col] = __float2bfloat16(c);
        }
      }
    }
  }
}

// ---------------------------------------------------------------- GEMM 64x128
// Small-M tile for grid-starved GEMMs (QKV, Wout): 4 waves x 32x64 output,
// 24 KB LDS, same staging/swizzle pattern. EPI 0: QKV split; 1: f32 +resid.
template <int EPI>
__global__ __launch_bounds__(256) void gemm64(
    const bf16_t* __restrict__ A, const bf16_t* __restrict__ Bw,
    const float* __restrict__ bias, void* __restrict__ out0,
    const float* __restrict__ resid, bf16_t* __restrict__ oks,
    bf16_t* __restrict__ ovt, int M, int N, int K) {
  __shared__ __align__(16) bf16_t As[2 * 64 * 32];
  __shared__ __align__(16) bf16_t Bs[2 * 128 * 32];
  const int tid  = threadIdx.x;
  const int lane = tid & 63;
  const int wave = tid >> 6;
  const int l15 = lane & 15, lg = lane >> 4;
  const int wr = (wave >> 1) * 32, wc = (wave & 1) * 64;
  const int bm = blockIdx.y * 64, bn = blockIdx.x * 128;
  const size_t Kz = (size_t)K;
  const int srow = lane >> 2;
  const int scol = ((lane & 3) ^ ((lane >> 3) & 3)) * 8;

  f32x4 acc[2][4];
#pragma unroll
  for (int m = 0; m < 2; ++m)
#pragma unroll
    for (int n = 0; n < 4; ++n) acc[m][n] = (f32x4){0.f, 0.f, 0.f, 0.f};

  const bf16_t* Ab = A + (size_t)bm * Kz;
  const bf16_t* Bb = Bw + (size_t)bn * Kz;

  auto stage = [&](int t, int buf) {
    const int k0 = t * 32;
    gload_lds16(Ab + (size_t)(wave * 16 + srow) * Kz + k0 + scol, As + buf * 2048 + wave * 512);
#pragma unroll
    for (int j = 0; j < 2; ++j) {
      const int cw = wave * 2 + j;
      gload_lds16(Bb + (size_t)(cw * 16 + srow) * Kz + k0 + scol, Bs + buf * 4096 + cw * 512);
    }
  };

  const int NT = K >> 5;
  const int rdoff = (lg ^ ((l15 >> 1) & 3)) * 8;
  stage(0, 0);
  __syncthreads();
  int buf = 0;
  for (int t = 0; t < NT; ++t) {
    if (t + 1 < NT) stage(t + 1, buf ^ 1);
    s16x8 af[2], bfv[4];
#pragma unroll
    for (int m = 0; m < 2; ++m)
      af[m] = *(const s16x8*)&As[buf * 2048 + (wr + m * 16 + l15) * 32 + rdoff];
#pragma unroll
    for (int n = 0; n < 4; ++n)
      bfv[n] = *(const s16x8*)&Bs[buf * 4096 + (wc + n * 16 + l15) * 32 + rdoff];
#pragma unroll
    for (int m = 0; m < 2; ++m)
#pragma unroll
      for (int n = 0; n < 4; ++n)
        acc[m][n] = __builtin_amdgcn_mfma_f32_16x16x32_bf16(af[m], bfv[n], acc[m][n], 0, 0, 0);
    __syncthreads();
    buf ^= 1;
  }

#pragma unroll
  for (int m = 0; m < 2; ++m) {
    const int row0 = bm + wr + m * 16 + lg * 4;
#pragma unroll
    for (int n = 0; n < 4; ++n) {
      const int col = bn + wc + n * 16 + l15;
      const float bcol = bias[col];
#pragma unroll
      for (int r = 0; r < 4; ++r) {
        const int rw = row0 + r;
        float c = acc[m][n][r] + bcol;
        if constexpr (EPI == 0) {
          if (col < 1024) {
            ((bf16_t*)out0)[(size_t)rw * 1024 + col] = __float2bfloat16(c);
          } else if (col < 1088) {
            int d = col - 1024, b = rw >> 11, t = rw & 2047;
            oks[((size_t)(b << 11) + t) * 64 + d] = __float2bfloat16(c);
          } else {
            int d = col - 1088, b = rw >> 11, t = rw & 2047;
            ovt[((size_t)b * 64 + d) * 2048 + t] = __float2bfloat16(c);
          }
        } else {
          ((float*)out0)[(size_t)rw * N + col] = c + resid[(size_t)rw * N + col];
        }
      }
    }
  }
}

// out = sum_z p[z] + bias  (FC2 split-K=4 combine, bf16 partials)
__global__ __launch_bounds__(256) void fc2_reduce_k(const bf16_t* __restrict__ p,
                                                    const float* __restrict__ bias,
                                                    float* __restrict__ out) {
  const size_t PL = (size_t)4096 * 1024;
  size_t i = ((size_t)blockIdx.x * 256 + threadIdx.x) * 8;
  float acc[8];
  {
    union { s16x8 v; bf16_t h[8]; } u;
    u.v = *(const s16x8*)(p + i);
#pragma unroll
    for (int j = 0; j < 8; ++j) acc[j] = __bfloat162float(u.h[j]);
  }
#pragma unroll
  for (int z = 1; z < 4; ++z) {
    union { s16x8 v; bf16_t h[8]; } u;
    u.v = *(const s16x8*)(p + z * PL + i);
#pragma unroll
    for (int j = 0; j < 8; ++j) acc[j] += __bfloat162float(u.h[j]);
  }
  const int col = (int)(i & 1023);
#pragma unroll
  for (int j = 0; j < 8; ++j) acc[j] += bias[col + j];
  *(float4*)(out + i)     = (float4){acc[0], acc[1], acc[2], acc[3]};
  *(float4*)(out + i + 4) = (float4){acc[4], acc[5], acc[6], acc[7]};
}

// ---------------------------------------------------------------- flash attention v4
// (frozen from R7) Block-cooperative: 8 waves share staged K/V tiles; swapped
// QK; per-lane softmax; defer-max; packed P via cvt_pk.

template <bool MASK>
__device__ __forceinline__ void attn_tile(
    int t0, int p, const s16x8 (&qf)[2],
    const bf16_t* __restrict__ Ks, const bf16_t* __restrict__ Vs,
    bf16_t* __restrict__ Pl, int l15, int lg,
    float& m_run, float& l_part, f32x4 (&ao)[4]) {
  constexpr float SCL = 0.125f * 1.44269504088896f;  // scale * log2(e)
  const int sw7 = l15 & 7;

  f32x4 sc[4];
#pragma unroll
  for (int n = 0; n < 4; ++n) sc[n] = (f32x4){0.f, 0.f, 0.f, 0.f};
#pragma unroll
  for (int ks2 = 0; ks2 < 2; ++ks2) {
#pragma unroll
    for (int n = 0; n < 4; ++n) {
      s16x8 kf = *(const s16x8*)&Ks[(n * 16 + l15) * 64 + (((ks2 << 2) | lg) ^ sw7) * 8];
      sc[n] = __builtin_amdgcn_mfma_f32_16x16x32_bf16(kf, qf[ks2], sc[n], 0, 0, 0);
    }
  }

  float mx = -1e30f;
#pragma unroll
  for (int n = 0; n < 4; ++n) {
#pragma unroll
    for (int r = 0; r < 4; ++r) {
      float v = sc[n][r] * SCL;
      if (MASK && (t0 + n * 16 + lg * 4 + r > p)) v = -1e30f;
      sc[n][r] = v;
      mx = fmaxf(mx, v);
    }
  }
  if (__any(mx > m_run + 11.5f)) {
    float mxf = fmaxf(mx, __shfl_xor(mx, 16, 64));
    mxf = fmaxf(mxf, __shfl_xor(mxf, 32, 64));
    float mn = fmaxf(m_run, mxf);
    float alpha = exp2f(m_run - mn);   // per-lane, head = l15
    m_run = mn;
    l_part *= alpha;
#pragma unroll
    for (int r = 0; r < 4; ++r) {
      float ar = __shfl(alpha, lg * 4 + r, 64);
#pragma unroll
      for (int n2 = 0; n2 < 4; ++n2) ao[n2][r] *= ar;
    }
  }
#pragma unroll
  for (int n = 0; n < 4; ++n) {
    float e0 = exp2f(sc[n][0] - m_run);
    float e1 = exp2f(sc[n][1] - m_run);
    float e2 = exp2f(sc[n][2] - m_run);
    float e3 = exp2f(sc[n][3] - m_run);
    l_part += (e0 + e1) + (e2 + e3);
    uint2 d;
    d.x = cvt_pk_bf16(e0, e1);
    d.y = cvt_pk_bf16(e2, e3);
    *(uint2*)&Pl[l15 * 72 + n * 16 + lg * 4] = d;
  }
#pragma unroll
  for (int ks2 = 0; ks2 < 2; ++ks2) {
    s16x8 pa = *(const s16x8*)&Pl[l15 * 72 + ks2 * 32 + lg * 8];
#pragma unroll
    for (int n2 = 0; n2 < 4; ++n2) {
      s16x8 vf = *(const s16x8*)&Vs[(n2 * 16 + l15) * 64 + (((ks2 << 2) | lg) ^ sw7) * 8];
      ao[n2] = __builtin_amdgcn_mfma_f32_16x16x32_bf16(pa, vf, ao[n2], 0, 0, 0);
    }
  }
}

__global__ __launch_bounds__(512) void attn_k(const bf16_t* __restrict__ q,
                                              const bf16_t* __restrict__ ksp,
                                              const bf16_t* __restrict__ vtp,
                                              bf16_t* __restrict__ o) {
  __shared__ __align__(16) bf16_t Ks[64 * 64];
  __shared__ __align__(16) bf16_t Vs[64 * 64];
  __shared__ __align__(16) bf16_t Plds[8][16 * 72];
  const int tid = threadIdx.x, lane = tid & 63, wave = tid >> 6;
  const int l15 = lane & 15, lg = lane >> 4;
  const int grp = blockIdx.x >> 1;
  const int b   = blockIdx.x & 1;
  const int pbase = 2040 - 8 * grp;
  const int p = pbase + wave;

  const bf16_t* qb_b = q   + (size_t)b * 32768 * 64;
  const bf16_t* ksb  = ksp + (size_t)b * 2048 * 64;
  const bf16_t* vtb  = vtp + (size_t)b * 64 * 2048;
  bf16_t*       ob   = o   + (size_t)b * 32768 * 64;
  bf16_t* Pl = &Plds[wave][0];

  const int srow = lane >> 3;
  const int scol = lane & 7;
  const int grow = wave * 8 + srow;
  const int gcol = scol ^ (grow & 7);
  const bf16_t* ksrc0 = ksb + (size_t)grow * 64 + gcol * 8;
  const bf16_t* vsrc0 = vtb + (size_t)grow * 2048 + gcol * 8;
  bf16_t* kdst = Ks + wave * 512;
  bf16_t* vdst = Vs + wave * 512;

  s16x8 qf[2];
  {
    const bf16_t* qptr = qb_b + (size_t)(16 * p + l15) * 64;
    qf[0] = *(const s16x8*)(qptr + lg * 8);
    qf[1] = *(const s16x8*)(qptr + 32 + lg * 8);
  }

  float m_run = -1e30f, l_part = 0.f;
  f32x4 ao[4];
#pragma unroll
  for (int n = 0; n < 4; ++n) ao[n] = (f32x4){0.f, 0.f, 0.f, 0.f};

  const int nsteps = (pbase + 71) >> 6;
  for (int tt = 0; tt < nsteps; ++tt) {
    const int t0 = tt * 64;
    __syncthreads();
    gload_lds16(ksrc0 + (size_t)t0 * 64, kdst);
    gload_lds16(vsrc0 + t0, vdst);
    __syncthreads();
    if (t0 <= p) {
      if (t0 + 63 <= p)
        attn_tile<false>(t0, p, qf, Ks, Vs, Pl, l15, lg, m_run, l_part, ao);
      else
        attn_tile<true>(t0, p, qf, Ks, Vs, Pl, l15, lg, m_run, l_part, ao);
    }
  }

  float l2 = l_part + __shfl_xor(l_part, 16, 64);
  l2 += __shfl_xor(l2, 32, 64);
  float rl[4];
#pragma unroll
  for (int r = 0; r < 4; ++r) rl[r] = 1.0f / __shfl(l2, lg * 4 + r, 64);
#pragma unroll
  for (int n2 = 0; n2 < 4; ++n2) {
#pragma unroll
    for (int r = 0; r < 4; ++r) {
      const int row = 16 * p + lg * 4 + r;
      ob[(size_t)row * 64 + n2 * 16 + l15] = __float2bfloat16(ao[n2][r] * rl[r]);
    }
  }
}

// ---------------------------------------------------------------- launch
extern "C" void kernel_launch(void* const* d_in, const int* in_sizes, int n_in,
                              void* d_out, int out_size, void* d_ws, size_t ws_size,
                              hipStream_t stream) {
  (void)in_sizes; (void)n_in; (void)out_size; (void)ws_size;
  const float* hidden = (const float*)d_in[0];
  const float* Wqkv   = (const float*)d_in[1];
  const float* bqkv   = (const float*)d_in[2];
  const float* Wout   = (const float*)d_in[3];
  const float* bout   = (const float*)d_in[4];
  const float* g1     = (const float*)d_in[5];
  const float* b1     = (const float*)d_in[6];
  const float* g2     = (const float*)d_in[7];
  const float* b2     = (const float*)d_in[8];
  const float* W1     = (const float*)d_in[9];
  const float* bfc1   = (const float*)d_in[10];
  const float* W2     = (const float*)d_in[11];
  const float* bfc2   = (const float*)d_in[12];

  float* out_h   = (float*)d_out;
  float* out_res = out_h + (size_t)4096 * 1024;

  char* ws = (char*)d_ws;
  auto alloc = [&](size_t bytes) {
    char* p = ws;
    ws += (bytes + 255) & ~(size_t)255;
    return p;
  };
  bf16_t* X1      = (bf16_t*)alloc((size_t)4096 * 1024 * 2);
  bf16_t* Wqkv_bf = (bf16_t*)alloc((size_t)1152 * 1024 * 2);
  float*  bias_r  = (float*)alloc(1152 * 4);
  bf16_t* qb      = (bf16_t*)alloc((size_t)4096 * 1024 * 2);
  bf16_t* ksum    = (bf16_t*)alloc((size_t)2 * 2048 * 64 * 2);
  bf16_t* vT      = (bf16_t*)alloc((size_t)2 * 64 * 2048 * 2);
  bf16_t* Ob      = (bf16_t*)alloc((size_t)4096 * 1024 * 2);
  bf16_t* Wout_bf = (bf16_t*)alloc((size_t)1024 * 1024 * 2);
  bf16_t* X2      = (bf16_t*)alloc((size_t)4096 * 1024 * 2);
  bf16_t* W1_bf   = (bf16_t*)alloc((size_t)4096 * 1024 * 2);
  bf16_t* W2_bf   = (bf16_t*)alloc((size_t)1024 * 4096 * 2);
  bf16_t* H1      = (bf16_t*)alloc((size_t)4096 * 4096 * 2);
  // FC2 split-K=4 bf16 partials (4 x 8 MB = 33.6 MB) alias the ws head:
  // X1..X2 (~37.3 MB) are all dead by FC2 time; W1_bf/W2_bf/H1 live higher.
  bf16_t* fc2_part = (bf16_t*)d_ws;

  // weight prep (one fused cast launch + 2 tiny kernels)
  cast_all_k<<<5120, 256, 0, stream>>>(Wqkv, Wout, W1, W2, Wqkv_bf, Wout_bf, W1_bf, W2_bf);
  reduce_kv_k<<<128, 256, 0, stream>>>(Wqkv, Wqkv_bf + (size_t)1024 * 1024);
  bias_prep_k<<<5, 256, 0, stream>>>(bqkv, bias_r);

  // LN1
  ln_cast_k<<<4096, 256, 0, stream>>>(hidden, g1, b1, X1);
  // QKV (reduced): M=4096, N=1152, K=1024 -- 64x128 tile, 576 blocks
  gemm64<0><<<dim3(9, 64), 256, 0, stream>>>(X1, Wqkv_bf, bias_r, qb, nullptr, ksum, vT,
                                             4096, 1152, 1024);
  // attention: 512 blocks x 8 waves; block shares staged K/V tiles
  attn_k<<<512, 512, 0, stream>>>(qb, ksum, vT, Ob);
  // Wout + residual -> out_res (f32) -- 64x128 tile, 512 blocks
  gemm64<1><<<dim3(8, 64), 256, 0, stream>>>(Ob, Wout_bf, bout, out_res, hidden, nullptr,
                                             nullptr, 4096, 1024, 1024);
  // LN2
  ln_cast_k<<<4096, 256, 0, stream>>>(out_res, g2, b2, X2);
  // FC1 + tanh -- 128x128, 1024 blocks, 2-buf -> 4 blocks/CU
  gemm_bt<2><<<dim3(32, 32), 256, 0, stream>>>(X2, W1_bf, bfc1, H1, 4096, 4096, 1024, 1024);
  // FC2 split-K=4 -> bf16 partials (1024 blocks = 4/CU), then combine + bias
  gemm_bt<4><<<dim3(8, 32, 4), 256, 0, stream>>>(H1, W2_bf, nullptr, fc2_part,
                                                 4096, 1024, 4096, 1024);
  fc2_reduce_k<<<2048, 256, 0, stream>>>(fc2_part, bfc2, out_h);
}

// Round 9
// 233.537 us; speedup vs baseline: 2.0451x; 1.1042x over previous
//
#include <hip/hip_runtime.h>
#include <hip/hip_bf16.h>

typedef __attribute__((ext_vector_type(8))) short s16x8;
typedef __attribute__((ext_vector_type(4))) float f32x4;
typedef __hip_bfloat16 bf16_t;

// ---------------------------------------------------------------- helpers
__device__ __forceinline__ void gload_lds16(const void* g, void* l) {
  __builtin_amdgcn_global_load_lds(
      (__attribute__((address_space(1))) void*)(g),
      (__attribute__((address_space(3))) void*)(l), 16, 0, 0);
}

__device__ __forceinline__ unsigned cvt_pk_bf16(float lo, float hi) {
  unsigned r;
  asm("v_cvt_pk_bf16_f32 %0, %1, %2" : "=v"(r) : "v"(lo), "v"(hi));
  return r;
}

// fast tanh: t=2^(2x*log2e); tanh = 1 - 2/(t+1).  |x| large saturates correctly.
__device__ __forceinline__ float fast_tanh(float x) {
  float t = exp2f(x * 2.885390082f);
  return 1.0f - 2.0f * __builtin_amdgcn_rcpf(t + 1.0f);
}

// ---------------------------------------------------------------- weight prep
__global__ void cast_all_k(const float* __restrict__ Wqkv, const float* __restrict__ Wout,
                           const float* __restrict__ W1, const float* __restrict__ W2,
                           bf16_t* __restrict__ Wqkv_bf, bf16_t* __restrict__ Wout_bf,
                           bf16_t* __restrict__ W1_bf, bf16_t* __restrict__ W2_bf) {
  int c = blockIdx.x * 256 + threadIdx.x;
  const float* src; bf16_t* dst; int off;
  if (c < 131072)      { src = Wqkv; dst = Wqkv_bf; off = c; }
  else if (c < 262144) { src = Wout; dst = Wout_bf; off = c - 131072; }
  else if (c < 786432) { src = W1;   dst = W1_bf;   off = c - 262144; }
  else                 { src = W2;   dst = W2_bf;   off = c - 786432; }
  int i = off * 8;
  float4 a = *(const float4*)(src + i);
  float4 b = *(const float4*)(src + i + 4);
  union { bf16_t h[8]; s16x8 v; } u;
  u.h[0] = __float2bfloat16(a.x); u.h[1] = __float2bfloat16(a.y);
  u.h[2] = __float2bfloat16(a.z); u.h[3] = __float2bfloat16(a.w);
  u.h[4] = __float2bfloat16(b.x); u.h[5] = __float2bfloat16(b.y);
  u.h[6] = __float2bfloat16(b.z); u.h[7] = __float2bfloat16(b.w);
  *(s16x8*)(dst + i) = u.v;
}

__global__ void reduce_kv_k(const float* __restrict__ Wqkv, bf16_t* __restrict__ Wred) {
  int d   = blockIdx.x & 63;
  int isv = blockIdx.x >> 6;
  int col = threadIdx.x * 4;
  const float* base = Wqkv + (size_t)(1024 + isv * 1024 + d) * 1024 + col;
  float4 s = {0.f, 0.f, 0.f, 0.f};
#pragma unroll
  for (int h = 0; h < 16; ++h) {
    float4 t = *(const float4*)(base + (size_t)h * 64 * 1024);
    s.x += t.x; s.y += t.y; s.z += t.z; s.w += t.w;
  }
  union { bf16_t h[4]; uint2 u; } o;
  o.h[0] = __float2bfloat16(s.x); o.h[1] = __float2bfloat16(s.y);
  o.h[2] = __float2bfloat16(s.z); o.h[3] = __float2bfloat16(s.w);
  *(uint2*)(Wred + (size_t)(isv * 64 + d) * 1024 + col) = o.u;
}

__global__ void bias_prep_k(const float* __restrict__ bqkv, float* __restrict__ br) {
  int i = blockIdx.x * 256 + threadIdx.x;
  if (i >= 1152) return;
  if (i < 1024) { br[i] = bqkv[i]; return; }
  int d = i - 1024;
  int off = (d < 64) ? (1024 + d) : (2048 + (d - 64));
  float s = 0.f;
#pragma unroll
  for (int h = 0; h < 16; ++h) s += bqkv[off + h * 64];
  br[i] = s;
}

// ---------------------------------------------------------------- layernorm + cast
__global__ __launch_bounds__(256) void ln_cast_k(const float* __restrict__ x,
                                                 const float* __restrict__ g,
                                                 const float* __restrict__ bb,
                                                 bf16_t* __restrict__ y) {
  int row = blockIdx.x, tid = threadIdx.x;
  float4 v = *(const float4*)(x + (size_t)row * 1024 + tid * 4);
  float s = v.x + v.y + v.z + v.w;
  float q = v.x * v.x + v.y * v.y + v.z * v.z + v.w * v.w;
#pragma unroll
  for (int off = 1; off < 64; off <<= 1) {
    s += __shfl_xor(s, off, 64);
    q += __shfl_xor(q, off, 64);
  }
  __shared__ float ss[4], qq[4];
  int wave = tid >> 6, lane = tid & 63;
  if (lane == 0) { ss[wave] = s; qq[wave] = q; }
  __syncthreads();
  s = ss[0] + ss[1] + ss[2] + ss[3];
  q = qq[0] + qq[1] + qq[2] + qq[3];
  float mu  = s * (1.0f / 1024.0f);
  float var = q * (1.0f / 1024.0f) - mu * mu;
  float rstd = rsqrtf(var + 1e-5f);
  float4 gg = *(const float4*)(g + tid * 4);
  float4 bv = *(const float4*)(bb + tid * 4);
  union { bf16_t h[4]; uint2 u; } o;
  o.h[0] = __float2bfloat16((v.x - mu) * rstd * gg.x + bv.x);
  o.h[1] = __float2bfloat16((v.y - mu) * rstd * gg.y + bv.y);
  o.h[2] = __float2bfloat16((v.z - mu) * rstd * gg.z + bv.z);
  o.h[3] = __float2bfloat16((v.w - mu) * rstd * gg.w + bv.w);
  *(uint2*)(y + (size_t)row * 1024 + tid * 4) = o.u;
}

// ---------------------------------------------------------------- GEMM 256x256
// 8 waves (2Mx4N), per-wave 128x64 out, BK=32, 3-buffer counted-vmcnt pipeline:
// one barrier per K-tile, vmcnt(4) keeps stage(t+1) in flight, stage(t+2)
// issued post-barrier (buffer (t+2)%3 == (t-1)%3 was finished by all waves at
// this barrier -> no race). T2 swizzle both-sides (0 conflicts, verified R7).
// EPI 2: fast-tanh -> bf16 (FC1); EPI 4: bf16 partial plane z (FC2 split-K)
template <int EPI>
__global__ __launch_bounds__(512) void gemm256(
    const bf16_t* __restrict__ A, const bf16_t* __restrict__ Bw,
    const float* __restrict__ bias, void* __restrict__ out0,
    int M, int N, int K, int Kslice) {
  __shared__ __align__(16) bf16_t As[3 * 8192];
  __shared__ __align__(16) bf16_t Bs[3 * 8192];
  const int tid  = threadIdx.x;
  const int lane = tid & 63;
  const int wave = tid >> 6;
  const int l15 = lane & 15, lg = lane >> 4;
  const int wm = wave >> 2, wn = wave & 3;     // 2 x 4 wave grid
  const int bm = blockIdx.y * 256, bn = blockIdx.x * 256;
  const size_t Kz = (size_t)K;
  const int kstart = blockIdx.z * Kslice;
  const int srow = lane >> 2;                            // 0..15
  const int scol = ((lane & 3) ^ ((lane >> 3) & 3)) * 8; // pre-swizzled chunk
  const int rdoff = (lg ^ ((l15 >> 1) & 3)) * 8;         // swizzled read chunk

  f32x4 acc[8][4];
#pragma unroll
  for (int f = 0; f < 8; ++f)
#pragma unroll
    for (int g = 0; g < 4; ++g) acc[f][g] = (f32x4){0.f, 0.f, 0.f, 0.f};

  const bf16_t* Ab = A + (size_t)bm * Kz + kstart;
  const bf16_t* Bb = Bw + (size_t)bn * Kz + kstart;

  // stage one BK=32 K-tile (A: 256x32, B: 256x32) into buffer buf.
  // wave w, instr j covers rows (w*2+j)*16..+15 (1024 B = one wave-instr).
  auto stage = [&](int t, int buf) {
    const int k0 = t * 32;
#pragma unroll
    for (int j = 0; j < 2; ++j) {
      const int blk = wave * 2 + j;
      gload_lds16(Ab + (size_t)(blk * 16 + srow) * Kz + k0 + scol, As + buf * 8192 + blk * 512);
      gload_lds16(Bb + (size_t)(blk * 16 + srow) * Kz + k0 + scol, Bs + buf * 8192 + blk * 512);
    }
  };

  const int NT = Kslice >> 5;
  stage(0, 0);
  stage(1, 1);
  int b0 = 0, b1 = 1, b2 = 2;    // read:b0, in-flight:b1, stage-into:b2
  for (int t = 0; t < NT; ++t) {
    // need stage(t) landed; stage(t+1) (4 instrs) may stay in flight.
    if (t + 1 < NT) asm volatile("s_waitcnt vmcnt(4)" ::: "memory");
    else            asm volatile("s_waitcnt vmcnt(0)" ::: "memory");
    __builtin_amdgcn_s_barrier();
    if (t + 2 < NT) stage(t + 2, b2);
    s16x8 af[8], bfv[4];
#pragma unroll
    for (int f = 0; f < 8; ++f)
      af[f] = *(const s16x8*)&As[b0 * 8192 + (wm * 128 + f * 16 + l15) * 32 + rdoff];
#pragma unroll
    for (int g = 0; g < 4; ++g)
      bfv[g] = *(const s16x8*)&Bs[b0 * 8192 + (wn * 64 + g * 16 + l15) * 32 + rdoff];
    __builtin_amdgcn_s_setprio(1);
#pragma unroll
    for (int f = 0; f < 8; ++f)
#pragma unroll
      for (int g = 0; g < 4; ++g)
        acc[f][g] = __builtin_amdgcn_mfma_f32_16x16x32_bf16(af[f], bfv[g], acc[f][g], 0, 0, 0);
    __builtin_amdgcn_s_setprio(0);
    int tmp = b0; b0 = b1; b1 = b2; b2 = tmp;
  }

#pragma unroll
  for (int f = 0; f < 8; ++f) {
    const int row0 = bm + wm * 128 + f * 16 + lg * 4;
#pragma unroll
    for (int g = 0; g < 4; ++g) {
      const int col = bn + wn * 64 + g * 16 + l15;
      const float bcol = (EPI == 4) ? 0.f : bias[col];
#pragma unroll
      for (int r = 0; r < 4; ++r) {
        const int rw = row0 + r;
        float c = acc[f][g][r] + bcol;
        if constexpr (EPI == 2) {
          ((bf16_t*)out0)[(size_t)rw * N + col] = __float2bfloat16(fast_tanh(c));
        } else {
          ((bf16_t*)out0)[((size_t)blockIdx.z * M + rw) * N + col] = __float2bfloat16(c);
        }
      }
    }
  }
}

// ---------------------------------------------------------------- GEMM 64x128
// (frozen R8) Small-M tile for grid-starved GEMMs (QKV, Wout).
template <int EPI>
__global__ __launch_bounds__(256) void gemm64(
    const bf16_t* __restrict__ A, const bf16_t* __restrict__ Bw,
    const float* __restrict__ bias, void* __restrict__ out0,
    const float* __restrict__ resid, bf16_t* __restrict__ oks,
    bf16_t* __restrict__ ovt, int M, int N, int K) {
  __shared__ __align__(16) bf16_t As[2 * 64 * 32];
  __shared__ __align__(16) bf16_t Bs[2 * 128 * 32];
  const int tid  = threadIdx.x;
  const int lane = tid & 63;
  const int wave = tid >> 6;
  const int l15 = lane & 15, lg = lane >> 4;
  const int wr = (wave >> 1) * 32, wc = (wave & 1) * 64;
  const int bm = blockIdx.y * 64, bn = blockIdx.x * 128;
  const size_t Kz = (size_t)K;
  const int srow = lane >> 2;
  const int scol = ((lane & 3) ^ ((lane >> 3) & 3)) * 8;

  f32x4 acc[2][4];
#pragma unroll
  for (int m = 0; m < 2; ++m)
#pragma unroll
    for (int n = 0; n < 4; ++n) acc[m][n] = (f32x4){0.f, 0.f, 0.f, 0.f};

  const bf16_t* Ab = A + (size_t)bm * Kz;
  const bf16_t* Bb = Bw + (size_t)bn * Kz;

  auto stage = [&](int t, int buf) {
    const int k0 = t * 32;
    gload_lds16(Ab + (size_t)(wave * 16 + srow) * Kz + k0 + scol, As + buf * 2048 + wave * 512);
#pragma unroll
    for (int j = 0; j < 2; ++j) {
      const int cw = wave * 2 + j;
      gload_lds16(Bb + (size_t)(cw * 16 + srow) * Kz + k0 + scol, Bs + buf * 4096 + cw * 512);
    }
  };

  const int NT = K >> 5;
  const int rdoff = (lg ^ ((l15 >> 1) & 3)) * 8;
  stage(0, 0);
  __syncthreads();
  int buf = 0;
  for (int t = 0; t < NT; ++t) {
    if (t + 1 < NT) stage(t + 1, buf ^ 1);
    s16x8 af[2], bfv[4];
#pragma unroll
    for (int m = 0; m < 2; ++m)
      af[m] = *(const s16x8*)&As[buf * 2048 + (wr + m * 16 + l15) * 32 + rdoff];
#pragma unroll
    for (int n = 0; n < 4; ++n)
      bfv[n] = *(const s16x8*)&Bs[buf * 4096 + (wc + n * 16 + l15) * 32 + rdoff];
#pragma unroll
    for (int m = 0; m < 2; ++m)
#pragma unroll
      for (int n = 0; n < 4; ++n)
        acc[m][n] = __builtin_amdgcn_mfma_f32_16x16x32_bf16(af[m], bfv[n], acc[m][n], 0, 0, 0);
    __syncthreads();
    buf ^= 1;
  }

#pragma unroll
  for (int m = 0; m < 2; ++m) {
    const int row0 = bm + wr + m * 16 + lg * 4;
#pragma unroll
    for (int n = 0; n < 4; ++n) {
      const int col = bn + wc + n * 16 + l15;
      const float bcol = bias[col];
#pragma unroll
      for (int r = 0; r < 4; ++r) {
        const int rw = row0 + r;
        float c = acc[m][n][r] + bcol;
        if constexpr (EPI == 0) {
          if (col < 1024) {
            ((bf16_t*)out0)[(size_t)rw * 1024 + col] = __float2bfloat16(c);
          } else if (col < 1088) {
            int d = col - 1024, b = rw >> 11, t = rw & 2047;
            oks[((size_t)(b << 11) + t) * 64 + d] = __float2bfloat16(c);
          } else {
            int d = col - 1088, b = rw >> 11, t = rw & 2047;
            ovt[((size_t)b * 64 + d) * 2048 + t] = __float2bfloat16(c);
          }
        } else {
          ((float*)out0)[(size_t)rw * N + col] = c + resid[(size_t)rw * N + col];
        }
      }
    }
  }
}

// out = sum_z p[z] + bias  (FC2 split-K=4 combine, bf16 partials)
__global__ __launch_bounds__(256) void fc2_reduce_k(const bf16_t* __restrict__ p,
                                                    const float* __restrict__ bias,
                                                    float* __restrict__ out) {
  const size_t PL = (size_t)4096 * 1024;
  size_t i = ((size_t)blockIdx.x * 256 + threadIdx.x) * 8;
  float acc[8];
  {
    union { s16x8 v; bf16_t h[8]; } u;
    u.v = *(const s16x8*)(p + i);
#pragma unroll
    for (int j = 0; j < 8; ++j) acc[j] = __bfloat162float(u.h[j]);
  }
#pragma unroll
  for (int z = 1; z < 4; ++z) {
    union { s16x8 v; bf16_t h[8]; } u;
    u.v = *(const s16x8*)(p + z * PL + i);
#pragma unroll
    for (int j = 0; j < 8; ++j) acc[j] += __bfloat162float(u.h[j]);
  }
  const int col = (int)(i & 1023);
#pragma unroll
  for (int j = 0; j < 8; ++j) acc[j] += bias[col + j];
  *(float4*)(out + i)     = (float4){acc[0], acc[1], acc[2], acc[3]};
  *(float4*)(out + i + 4) = (float4){acc[4], acc[5], acc[6], acc[7]};
}

// ---------------------------------------------------------------- flash attention v4
// (frozen R8)
template <bool MASK>
__device__ __forceinline__ void attn_tile(
    int t0, int p, const s16x8 (&qf)[2],
    const bf16_t* __restrict__ Ks, const bf16_t* __restrict__ Vs,
    bf16_t* __restrict__ Pl, int l15, int lg,
    float& m_run, float& l_part, f32x4 (&ao)[4]) {
  constexpr float SCL = 0.125f * 1.44269504088896f;
  const int sw7 = l15 & 7;

  f32x4 sc[4];
#pragma unroll
  for (int n = 0; n < 4; ++n) sc[n] = (f32x4){0.f, 0.f, 0.f, 0.f};
#pragma unroll
  for (int ks2 = 0; ks2 < 2; ++ks2) {
#pragma unroll
    for (int n = 0; n < 4; ++n) {
      s16x8 kf = *(const s16x8*)&Ks[(n * 16 + l15) * 64 + (((ks2 << 2) | lg) ^ sw7) * 8];
      sc[n] = __builtin_amdgcn_mfma_f32_16x16x32_bf16(kf, qf[ks2], sc[n], 0, 0, 0);
    }
  }

  float mx = -1e30f;
#pragma unroll
  for (int n = 0; n < 4; ++n) {
#pragma unroll
    for (int r = 0; r < 4; ++r) {
      float v = sc[n][r] * SCL;
      if (MASK && (t0 + n * 16 + lg * 4 + r > p)) v = -1e30f;
      sc[n][r] = v;
      mx = fmaxf(mx, v);
    }
  }
  if (__any(mx > m_run + 11.5f)) {
    float mxf = fmaxf(mx, __shfl_xor(mx, 16, 64));
    mxf = fmaxf(mxf, __shfl_xor(mxf, 32, 64));
    float mn = fmaxf(m_run, mxf);
    float alpha = exp2f(m_run - mn);
    m_run = mn;
    l_part *= alpha;
#pragma unroll
    for (int r = 0; r < 4; ++r) {
      float ar = __shfl(alpha, lg * 4 + r, 64);
#pragma unroll
      for (int n2 = 0; n2 < 4; ++n2) ao[n2][r] *= ar;
    }
  }
#pragma unroll
  for (int n = 0; n < 4; ++n) {
    float e0 = exp2f(sc[n][0] - m_run);
    float e1 = exp2f(sc[n][1] - m_run);
    float e2 = exp2f(sc[n][2] - m_run);
    float e3 = exp2f(sc[n][3] - m_run);
    l_part += (e0 + e1) + (e2 + e3);
    uint2 d;
    d.x = cvt_pk_bf16(e0, e1);
    d.y = cvt_pk_bf16(e2, e3);
    *(uint2*)&Pl[l15 * 72 + n * 16 + lg * 4] = d;
  }
#pragma unroll
  for (int ks2 = 0; ks2 < 2; ++ks2) {
    s16x8 pa = *(const s16x8*)&Pl[l15 * 72 + ks2 * 32 + lg * 8];
#pragma unroll
    for (int n2 = 0; n2 < 4; ++n2) {
      s16x8 vf = *(const s16x8*)&Vs[(n2 * 16 + l15) * 64 + (((ks2 << 2) | lg) ^ sw7) * 8];
      ao[n2] = __builtin_amdgcn_mfma_f32_16x16x32_bf16(pa, vf, ao[n2], 0, 0, 0);
    }
  }
}

__global__ __launch_bounds__(512) void attn_k(const bf16_t* __restrict__ q,
                                              const bf16_t* __restrict__ ksp,
                                              const bf16_t* __restrict__ vtp,
                                              bf16_t* __restrict__ o) {
  __shared__ __align__(16) bf16_t Ks[64 * 64];
  __shared__ __align__(16) bf16_t Vs[64 * 64];
  __shared__ __align__(16) bf16_t Plds[8][16 * 72];
  const int tid = threadIdx.x, lane = tid & 63, wave = tid >> 6;
  const int l15 = lane & 15, lg = lane >> 4;
  const int grp = blockIdx.x >> 1;
  const int b   = blockIdx.x & 1;
  const int pbase = 2040 - 8 * grp;
  const int p = pbase + wave;

  const bf16_t* qb_b = q   + (size_t)b * 32768 * 64;
  const bf16_t* ksb  = ksp + (size_t)b * 2048 * 64;
  const bf16_t* vtb  = vtp + (size_t)b * 64 * 2048;
  bf16_t*       ob   = o   + (size_t)b * 32768 * 64;
  bf16_t* Pl = &Plds[wave][0];

  const int srow = lane >> 3;
  const int scol = lane & 7;
  const int grow = wave * 8 + srow;
  const int gcol = scol ^ (grow & 7);
  const bf16_t* ksrc0 = ksb + (size_t)grow * 64 + gcol * 8;
  const bf16_t* vsrc0 = vtb + (size_t)grow * 2048 + gcol * 8;
  bf16_t* kdst = Ks + wave * 512;
  bf16_t* vdst = Vs + wave * 512;

  s16x8 qf[2];
  {
    const bf16_t* qptr = qb_b + (size_t)(16 * p + l15) * 64;
    qf[0] = *(const s16x8*)(qptr + lg * 8);
    qf[1] = *(const s16x8*)(qptr + 32 + lg * 8);
  }

  float m_run = -1e30f, l_part = 0.f;
  f32x4 ao[4];
#pragma unroll
  for (int n = 0; n < 4; ++n) ao[n] = (f32x4){0.f, 0.f, 0.f, 0.f};

  const int nsteps = (pbase + 71) >> 6;
  for (int tt = 0; tt < nsteps; ++tt) {
    const int t0 = tt * 64;
    __syncthreads();
    gload_lds16(ksrc0 + (size_t)t0 * 64, kdst);
    gload_lds16(vsrc0 + t0, vdst);
    __syncthreads();
    if (t0 <= p) {
      if (t0 + 63 <= p)
        attn_tile<false>(t0, p, qf, Ks, Vs, Pl, l15, lg, m_run, l_part, ao);
      else
        attn_tile<true>(t0, p, qf, Ks, Vs, Pl, l15, lg, m_run, l_part, ao);
    }
  }

  float l2 = l_part + __shfl_xor(l_part, 16, 64);
  l2 += __shfl_xor(l2, 32, 64);
  float rl[4];
#pragma unroll
  for (int r = 0; r < 4; ++r) rl[r] = 1.0f / __shfl(l2, lg * 4 + r, 64);
#pragma unroll
  for (int n2 = 0; n2 < 4; ++n2) {
#pragma unroll
    for (int r = 0; r < 4; ++r) {
      const int row = 16 * p + lg * 4 + r;
      ob[(size_t)row * 64 + n2 * 16 + l15] = __float2bfloat16(ao[n2][r] * rl[r]);
    }
  }
}

// ---------------------------------------------------------------- launch
extern "C" void kernel_launch(void* const* d_in, const int* in_sizes, int n_in,
                              void* d_out, int out_size, void* d_ws, size_t ws_size,
                              hipStream_t stream) {
  (void)in_sizes; (void)n_in; (void)out_size; (void)ws_size;
  const float* hidden = (const float*)d_in[0];
  const float* Wqkv   = (const float*)d_in[1];
  const float* bqkv   = (const float*)d_in[2];
  const float* Wout   = (const float*)d_in[3];
  const float* bout   = (const float*)d_in[4];
  const float* g1     = (const float*)d_in[5];
  const float* b1     = (const float*)d_in[6];
  const float* g2     = (const float*)d_in[7];
  const float* b2     = (const float*)d_in[8];
  const float* W1     = (const float*)d_in[9];
  const float* bfc1   = (const float*)d_in[10];
  const float* W2     = (const float*)d_in[11];
  const float* bfc2   = (const float*)d_in[12];

  float* out_h   = (float*)d_out;
  float* out_res = out_h + (size_t)4096 * 1024;

  char* ws = (char*)d_ws;
  auto alloc = [&](size_t bytes) {
    char* p = ws;
    ws += (bytes + 255) & ~(size_t)255;
    return p;
  };
  bf16_t* X1      = (bf16_t*)alloc((size_t)4096 * 1024 * 2);
  bf16_t* Wqkv_bf = (bf16_t*)alloc((size_t)1152 * 1024 * 2);
  float*  bias_r  = (float*)alloc(1152 * 4);
  bf16_t* qb      = (bf16_t*)alloc((size_t)4096 * 1024 * 2);
  bf16_t* ksum    = (bf16_t*)alloc((size_t)2 * 2048 * 64 * 2);
  bf16_t* vT      = (bf16_t*)alloc((size_t)2 * 64 * 2048 * 2);
  bf16_t* Ob      = (bf16_t*)alloc((size_t)4096 * 1024 * 2);
  bf16_t* Wout_bf = (bf16_t*)alloc((size_t)1024 * 1024 * 2);
  bf16_t* X2      = (bf16_t*)alloc((size_t)4096 * 1024 * 2);
  bf16_t* W1_bf   = (bf16_t*)alloc((size_t)4096 * 1024 * 2);
  bf16_t* W2_bf   = (bf16_t*)alloc((size_t)1024 * 4096 * 2);
  bf16_t* H1      = (bf16_t*)alloc((size_t)4096 * 4096 * 2);
  // FC2 split-K=4 bf16 partials (33.6 MB) alias the ws head: X1..X2 (~37.3 MB)
  // are dead by FC2 time; W1_bf/W2_bf/H1 live higher.
  bf16_t* fc2_part = (bf16_t*)d_ws;

  // weight prep
  cast_all_k<<<5120, 256, 0, stream>>>(Wqkv, Wout, W1, W2, Wqkv_bf, Wout_bf, W1_bf, W2_bf);
  reduce_kv_k<<<128, 256, 0, stream>>>(Wqkv, Wqkv_bf + (size_t)1024 * 1024);
  bias_prep_k<<<5, 256, 0, stream>>>(bqkv, bias_r);

  // LN1
  ln_cast_k<<<4096, 256, 0, stream>>>(hidden, g1, b1, X1);
  // QKV (reduced): M=4096, N=1152, K=1024 -- 64x128 tile, 576 blocks
  gemm64<0><<<dim3(9, 64), 256, 0, stream>>>(X1, Wqkv_bf, bias_r, qb, nullptr, ksum, vT,
                                             4096, 1152, 1024);
  // attention
  attn_k<<<512, 512, 0, stream>>>(qb, ksum, vT, Ob);
  // Wout + residual -> out_res (f32)
  gemm64<1><<<dim3(8, 64), 256, 0, stream>>>(Ob, Wout_bf, bout, out_res, hidden, nullptr,
                                             nullptr, 4096, 1024, 1024);
  // LN2
  ln_cast_k<<<4096, 256, 0, stream>>>(out_res, g2, b2, X2);
  // FC1 + tanh -- 256x256 pipelined, 256 blocks = 1/CU
  gemm256<2><<<dim3(16, 16), 512, 0, stream>>>(X2, W1_bf, bfc1, H1, 4096, 4096, 1024, 1024);
  // FC2 split-K=4 -> bf16 partials (256 blocks), then combine + bias
  gemm256<4><<<dim3(4, 16, 4), 512, 0, stream>>>(H1, W2_bf, nullptr, fc2_part,
                                                 4096, 1024, 4096, 1024);
  fc2_reduce_k<<<2048, 256, 0, stream>>>(fc2_part, bfc2, out_h);
}

// Round 10
// 227.864 us; speedup vs baseline: 2.0960x; 1.0249x over previous
//
#include <hip/hip_runtime.h>
#include <hip/hip_bf16.h>

typedef __attribute__((ext_vector_type(8))) short s16x8;
typedef __attribute__((ext_vector_type(4))) float f32x4;
typedef __hip_bfloat16 bf16_t;

// ---------------------------------------------------------------- helpers
__device__ __forceinline__ void gload_lds16(const void* g, void* l) {
  __builtin_amdgcn_global_load_lds(
      (__attribute__((address_space(1))) void*)(g),
      (__attribute__((address_space(3))) void*)(l), 16, 0, 0);
}

__device__ __forceinline__ unsigned cvt_pk_bf16(float lo, float hi) {
  unsigned r;
  asm("v_cvt_pk_bf16_f32 %0, %1, %2" : "=v"(r) : "v"(lo), "v"(hi));
  return r;
}

// fast tanh: t=2^(2x*log2e); tanh = 1 - 2/(t+1).
__device__ __forceinline__ float fast_tanh(float x) {
  float t = exp2f(x * 2.885390082f);
  return 1.0f - 2.0f * __builtin_amdgcn_rcpf(t + 1.0f);
}

// ---------------------------------------------------------------- weight prep
__global__ void cast_all_k(const float* __restrict__ Wqkv, const float* __restrict__ Wout,
                           const float* __restrict__ W1, const float* __restrict__ W2,
                           bf16_t* __restrict__ Wqkv_bf, bf16_t* __restrict__ Wout_bf,
                           bf16_t* __restrict__ W1_bf, bf16_t* __restrict__ W2_bf) {
  int c = blockIdx.x * 256 + threadIdx.x;
  const float* src; bf16_t* dst; int off;
  if (c < 131072)      { src = Wqkv; dst = Wqkv_bf; off = c; }
  else if (c < 262144) { src = Wout; dst = Wout_bf; off = c - 131072; }
  else if (c < 786432) { src = W1;   dst = W1_bf;   off = c - 262144; }
  else                 { src = W2;   dst = W2_bf;   off = c - 786432; }
  int i = off * 8;
  float4 a = *(const float4*)(src + i);
  float4 b = *(const float4*)(src + i + 4);
  union { bf16_t h[8]; s16x8 v; } u;
  u.h[0] = __float2bfloat16(a.x); u.h[1] = __float2bfloat16(a.y);
  u.h[2] = __float2bfloat16(a.z); u.h[3] = __float2bfloat16(a.w);
  u.h[4] = __float2bfloat16(b.x); u.h[5] = __float2bfloat16(b.y);
  u.h[6] = __float2bfloat16(b.z); u.h[7] = __float2bfloat16(b.w);
  *(s16x8*)(dst + i) = u.v;
}

__global__ void reduce_kv_k(const float* __restrict__ Wqkv, bf16_t* __restrict__ Wred) {
  int d   = blockIdx.x & 63;
  int isv = blockIdx.x >> 6;
  int col = threadIdx.x * 4;
  const float* base = Wqkv + (size_t)(1024 + isv * 1024 + d) * 1024 + col;
  float4 s = {0.f, 0.f, 0.f, 0.f};
#pragma unroll
  for (int h = 0; h < 16; ++h) {
    float4 t = *(const float4*)(base + (size_t)h * 64 * 1024);
    s.x += t.x; s.y += t.y; s.z += t.z; s.w += t.w;
  }
  union { bf16_t h[4]; uint2 u; } o;
  o.h[0] = __float2bfloat16(s.x); o.h[1] = __float2bfloat16(s.y);
  o.h[2] = __float2bfloat16(s.z); o.h[3] = __float2bfloat16(s.w);
  *(uint2*)(Wred + (size_t)(isv * 64 + d) * 1024 + col) = o.u;
}

__global__ void bias_prep_k(const float* __restrict__ bqkv, float* __restrict__ br) {
  int i = blockIdx.x * 256 + threadIdx.x;
  if (i >= 1152) return;
  if (i < 1024) { br[i] = bqkv[i]; return; }
  int d = i - 1024;
  int off = (d < 64) ? (1024 + d) : (2048 + (d - 64));
  float s = 0.f;
#pragma unroll
  for (int h = 0; h < 16; ++h) s += bqkv[off + h * 64];
  br[i] = s;
}

// ---------------------------------------------------------------- layernorm + cast
__global__ __launch_bounds__(256) void ln_cast_k(const float* __restrict__ x,
                                                 const float* __restrict__ g,
                                                 const float* __restrict__ bb,
                                                 bf16_t* __restrict__ y) {
  int row = blockIdx.x, tid = threadIdx.x;
  float4 v = *(const float4*)(x + (size_t)row * 1024 + tid * 4);
  float s = v.x + v.y + v.z + v.w;
  float q = v.x * v.x + v.y * v.y + v.z * v.z + v.w * v.w;
#pragma unroll
  for (int off = 1; off < 64; off <<= 1) {
    s += __shfl_xor(s, off, 64);
    q += __shfl_xor(q, off, 64);
  }
  __shared__ float ss[4], qq[4];
  int wave = tid >> 6, lane = tid & 63;
  if (lane == 0) { ss[wave] = s; qq[wave] = q; }
  __syncthreads();
  s = ss[0] + ss[1] + ss[2] + ss[3];
  q = qq[0] + qq[1] + qq[2] + qq[3];
  float mu  = s * (1.0f / 1024.0f);
  float var = q * (1.0f / 1024.0f) - mu * mu;
  float rstd = rsqrtf(var + 1e-5f);
  float4 gg = *(const float4*)(g + tid * 4);
  float4 bv = *(const float4*)(bb + tid * 4);
  union { bf16_t h[4]; uint2 u; } o;
  o.h[0] = __float2bfloat16((v.x - mu) * rstd * gg.x + bv.x);
  o.h[1] = __float2bfloat16((v.y - mu) * rstd * gg.y + bv.y);
  o.h[2] = __float2bfloat16((v.z - mu) * rstd * gg.z + bv.z);
  o.h[3] = __float2bfloat16((v.w - mu) * rstd * gg.w + bv.w);
  *(uint2*)(y + (size_t)row * 1024 + tid * 4) = o.u;
}

// ---------------------------------------------------------------- GEMM 256x256
// (frozen R9) 8 waves, BK=32, 3-buffer counted-vmcnt pipeline + T2 swizzle + T5.
template <int EPI>
__global__ __launch_bounds__(512) void gemm256(
    const bf16_t* __restrict__ A, const bf16_t* __restrict__ Bw,
    const float* __restrict__ bias, void* __restrict__ out0,
    int M, int N, int K, int Kslice) {
  __shared__ __align__(16) bf16_t As[3 * 8192];
  __shared__ __align__(16) bf16_t Bs[3 * 8192];
  const int tid  = threadIdx.x;
  const int lane = tid & 63;
  const int wave = tid >> 6;
  const int l15 = lane & 15, lg = lane >> 4;
  const int wm = wave >> 2, wn = wave & 3;
  const int bm = blockIdx.y * 256, bn = blockIdx.x * 256;
  const size_t Kz = (size_t)K;
  const int kstart = blockIdx.z * Kslice;
  const int srow = lane >> 2;
  const int scol = ((lane & 3) ^ ((lane >> 3) & 3)) * 8;
  const int rdoff = (lg ^ ((l15 >> 1) & 3)) * 8;

  f32x4 acc[8][4];
#pragma unroll
  for (int f = 0; f < 8; ++f)
#pragma unroll
    for (int g = 0; g < 4; ++g) acc[f][g] = (f32x4){0.f, 0.f, 0.f, 0.f};

  const bf16_t* Ab = A + (size_t)bm * Kz + kstart;
  const bf16_t* Bb = Bw + (size_t)bn * Kz + kstart;

  auto stage = [&](int t, int buf) {
    const int k0 = t * 32;
#pragma unroll
    for (int j = 0; j < 2; ++j) {
      const int blk = wave * 2 + j;
      gload_lds16(Ab + (size_t)(blk * 16 + srow) * Kz + k0 + scol, As + buf * 8192 + blk * 512);
      gload_lds16(Bb + (size_t)(blk * 16 + srow) * Kz + k0 + scol, Bs + buf * 8192 + blk * 512);
    }
  };

  const int NT = Kslice >> 5;
  stage(0, 0);
  stage(1, 1);
  int b0 = 0, b1 = 1, b2 = 2;
  for (int t = 0; t < NT; ++t) {
    if (t + 1 < NT) asm volatile("s_waitcnt vmcnt(4)" ::: "memory");
    else            asm volatile("s_waitcnt vmcnt(0)" ::: "memory");
    __builtin_amdgcn_s_barrier();
    if (t + 2 < NT) stage(t + 2, b2);
    s16x8 af[8], bfv[4];
#pragma unroll
    for (int f = 0; f < 8; ++f)
      af[f] = *(const s16x8*)&As[b0 * 8192 + (wm * 128 + f * 16 + l15) * 32 + rdoff];
#pragma unroll
    for (int g = 0; g < 4; ++g)
      bfv[g] = *(const s16x8*)&Bs[b0 * 8192 + (wn * 64 + g * 16 + l15) * 32 + rdoff];
    __builtin_amdgcn_s_setprio(1);
#pragma unroll
    for (int f = 0; f < 8; ++f)
#pragma unroll
      for (int g = 0; g < 4; ++g)
        acc[f][g] = __builtin_amdgcn_mfma_f32_16x16x32_bf16(af[f], bfv[g], acc[f][g], 0, 0, 0);
    __builtin_amdgcn_s_setprio(0);
    int tmp = b0; b0 = b1; b1 = b2; b2 = tmp;
  }

#pragma unroll
  for (int f = 0; f < 8; ++f) {
    const int row0 = bm + wm * 128 + f * 16 + lg * 4;
#pragma unroll
    for (int g = 0; g < 4; ++g) {
      const int col = bn + wn * 64 + g * 16 + l15;
      const float bcol = (EPI == 4) ? 0.f : bias[col];
#pragma unroll
      for (int r = 0; r < 4; ++r) {
        const int rw = row0 + r;
        float c = acc[f][g][r] + bcol;
        if constexpr (EPI == 2) {
          ((bf16_t*)out0)[(size_t)rw * N + col] = __float2bfloat16(fast_tanh(c));
        } else {
          ((bf16_t*)out0)[((size_t)blockIdx.z * M + rw) * N + col] = __float2bfloat16(c);
        }
      }
    }
  }
}

// ---------------------------------------------------------------- GEMM 64x128
// (frozen R8; EPI0 q-output now pre-scaled by 0.125*log2(e) for attention)
template <int EPI>
__global__ __launch_bounds__(256) void gemm64(
    const bf16_t* __restrict__ A, const bf16_t* __restrict__ Bw,
    const float* __restrict__ bias, void* __restrict__ out0,
    const float* __restrict__ resid, bf16_t* __restrict__ oks,
    bf16_t* __restrict__ ovt, int M, int N, int K) {
  __shared__ __align__(16) bf16_t As[2 * 64 * 32];
  __shared__ __align__(16) bf16_t Bs[2 * 128 * 32];
  const int tid  = threadIdx.x;
  const int lane = tid & 63;
  const int wave = tid >> 6;
  const int l15 = lane & 15, lg = lane >> 4;
  const int wr = (wave >> 1) * 32, wc = (wave & 1) * 64;
  const int bm = blockIdx.y * 64, bn = blockIdx.x * 128;
  const size_t Kz = (size_t)K;
  const int srow = lane >> 2;
  const int scol = ((lane & 3) ^ ((lane >> 3) & 3)) * 8;

  f32x4 acc[2][4];
#pragma unroll
  for (int m = 0; m < 2; ++m)
#pragma unroll
    for (int n = 0; n < 4; ++n) acc[m][n] = (f32x4){0.f, 0.f, 0.f, 0.f};

  const bf16_t* Ab = A + (size_t)bm * Kz;
  const bf16_t* Bb = Bw + (size_t)bn * Kz;

  auto stage = [&](int t, int buf) {
    const int k0 = t * 32;
    gload_lds16(Ab + (size_t)(wave * 16 + srow) * Kz + k0 + scol, As + buf * 2048 + wave * 512);
#pragma unroll
    for (int j = 0; j < 2; ++j) {
      const int cw = wave * 2 + j;
      gload_lds16(Bb + (size_t)(cw * 16 + srow) * Kz + k0 + scol, Bs + buf * 4096 + cw * 512);
    }
  };

  const int NT = K >> 5;
  const int rdoff = (lg ^ ((l15 >> 1) & 3)) * 8;
  stage(0, 0);
  __syncthreads();
  int buf = 0;
  for (int t = 0; t < NT; ++t) {
    if (t + 1 < NT) stage(t + 1, buf ^ 1);
    s16x8 af[2], bfv[4];
#pragma unroll
    for (int m = 0; m < 2; ++m)
      af[m] = *(const s16x8*)&As[buf * 2048 + (wr + m * 16 + l15) * 32 + rdoff];
#pragma unroll
    for (int n = 0; n < 4; ++n)
      bfv[n] = *(const s16x8*)&Bs[buf * 4096 + (wc + n * 16 + l15) * 32 + rdoff];
#pragma unroll
    for (int m = 0; m < 2; ++m)
#pragma unroll
      for (int n = 0; n < 4; ++n)
        acc[m][n] = __builtin_amdgcn_mfma_f32_16x16x32_bf16(af[m], bfv[n], acc[m][n], 0, 0, 0);
    __syncthreads();
    buf ^= 1;
  }

#pragma unroll
  for (int m = 0; m < 2; ++m) {
    const int row0 = bm + wr + m * 16 + lg * 4;
#pragma unroll
    for (int n = 0; n < 4; ++n) {
      const int col = bn + wc + n * 16 + l15;
      const float bcol = bias[col];
#pragma unroll
      for (int r = 0; r < 4; ++r) {
        const int rw = row0 + r;
        float c = acc[m][n][r] + bcol;
        if constexpr (EPI == 0) {
          if (col < 1024) {
            // q: pre-scale by 0.125*log2(e) so QK^T lands in log2 units
            ((bf16_t*)out0)[(size_t)rw * 1024 + col] =
                __float2bfloat16(c * 0.1803368801f);
          } else if (col < 1088) {
            int d = col - 1024, b = rw >> 11, t = rw & 2047;
            oks[((size_t)(b << 11) + t) * 64 + d] = __float2bfloat16(c);
          } else {
            int d = col - 1088, b = rw >> 11, t = rw & 2047;
            ovt[((size_t)b * 64 + d) * 2048 + t] = __float2bfloat16(c);
          }
        } else {
          ((float*)out0)[(size_t)rw * N + col] = c + resid[(size_t)rw * N + col];
        }
      }
    }
  }
}

// out = sum_z p[z] + bias  (FC2 split-K=4 combine, bf16 partials)
__global__ __launch_bounds__(256) void fc2_reduce_k(const bf16_t* __restrict__ p,
                                                    const float* __restrict__ bias,
                                                    float* __restrict__ out) {
  const size_t PL = (size_t)4096 * 1024;
  size_t i = ((size_t)blockIdx.x * 256 + threadIdx.x) * 8;
  float acc[8];
  {
    union { s16x8 v; bf16_t h[8]; } u;
    u.v = *(const s16x8*)(p + i);
#pragma unroll
    for (int j = 0; j < 8; ++j) acc[j] = __bfloat162float(u.h[j]);
  }
#pragma unroll
  for (int z = 1; z < 4; ++z) {
    union { s16x8 v; bf16_t h[8]; } u;
    u.v = *(const s16x8*)(p + z * PL + i);
#pragma unroll
    for (int j = 0; j < 8; ++j) acc[j] += __bfloat162float(u.h[j]);
  }
  const int col = (int)(i & 1023);
#pragma unroll
  for (int j = 0; j < 8; ++j) acc[j] += bias[col + j];
  *(float4*)(out + i)     = (float4){acc[0], acc[1], acc[2], acc[3]};
  *(float4*)(out + i + 4) = (float4){acc[4], acc[5], acc[6], acc[7]};
}

// ---------------------------------------------------------------- flash attention v5
// v4 + 3-buffer counted-vmcnt K/V pipeline (stage issued AFTER the barrier:
// barrier proves all waves finished compute(t-1), the buffer being overwritten;
// vmcnt(2) at loop top = stage(t) landed, stage(t+1)'s 2 loads keep flying).
// Q is pre-scaled (log2 units) by the QKV epilogue.

template <bool MASK>
__device__ __forceinline__ void attn_tile(
    int t0, int p, const s16x8 (&qf)[2],
    const bf16_t* __restrict__ Ks, const bf16_t* __restrict__ Vs,
    bf16_t* __restrict__ Pl, int l15, int lg,
    float& m_run, float& l_part, f32x4 (&ao)[4]) {
  const int sw7 = l15 & 7;

  f32x4 sc[4];
#pragma unroll
  for (int n = 0; n < 4; ++n) sc[n] = (f32x4){0.f, 0.f, 0.f, 0.f};
#pragma unroll
  for (int ks2 = 0; ks2 < 2; ++ks2) {
#pragma unroll
    for (int n = 0; n < 4; ++n) {
      s16x8 kf = *(const s16x8*)&Ks[(n * 16 + l15) * 64 + (((ks2 << 2) | lg) ^ sw7) * 8];
      sc[n] = __builtin_amdgcn_mfma_f32_16x16x32_bf16(kf, qf[ks2], sc[n], 0, 0, 0);
    }
  }

  float mx = -1e30f;
#pragma unroll
  for (int n = 0; n < 4; ++n) {
#pragma unroll
    for (int r = 0; r < 4; ++r) {
      float v = sc[n][r];                       // already log2-scaled via Q
      if (MASK && (t0 + n * 16 + lg * 4 + r > p)) v = -1e30f;
      sc[n][r] = v;
      mx = fmaxf(mx, v);
    }
  }
  if (__any(mx > m_run + 11.5f)) {
    float mxf = fmaxf(mx, __shfl_xor(mx, 16, 64));
    mxf = fmaxf(mxf, __shfl_xor(mxf, 32, 64));
    float mn = fmaxf(m_run, mxf);
    float alpha = exp2f(m_run - mn);
    m_run = mn;
    l_part *= alpha;
#pragma unroll
    for (int r = 0; r < 4; ++r) {
      float ar = __shfl(alpha, lg * 4 + r, 64);
#pragma unroll
      for (int n2 = 0; n2 < 4; ++n2) ao[n2][r] *= ar;
    }
  }
#pragma unroll
  for (int n = 0; n < 4; ++n) {
    float e0 = exp2f(sc[n][0] - m_run);
    float e1 = exp2f(sc[n][1] - m_run);
    float e2 = exp2f(sc[n][2] - m_run);
    float e3 = exp2f(sc[n][3] - m_run);
    l_part += (e0 + e1) + (e2 + e3);
    uint2 d;
    d.x = cvt_pk_bf16(e0, e1);
    d.y = cvt_pk_bf16(e2, e3);
    *(uint2*)&Pl[l15 * 72 + n * 16 + lg * 4] = d;
  }
#pragma unroll
  for (int ks2 = 0; ks2 < 2; ++ks2) {
    s16x8 pa = *(const s16x8*)&Pl[l15 * 72 + ks2 * 32 + lg * 8];
#pragma unroll
    for (int n2 = 0; n2 < 4; ++n2) {
      s16x8 vf = *(const s16x8*)&Vs[(n2 * 16 + l15) * 64 + (((ks2 << 2) | lg) ^ sw7) * 8];
      ao[n2] = __builtin_amdgcn_mfma_f32_16x16x32_bf16(pa, vf, ao[n2], 0, 0, 0);
    }
  }
}

__global__ __launch_bounds__(512) void attn_k(const bf16_t* __restrict__ q,
                                              const bf16_t* __restrict__ ksp,
                                              const bf16_t* __restrict__ vtp,
                                              bf16_t* __restrict__ o) {
  __shared__ __align__(16) bf16_t Ks[3 * 4096];
  __shared__ __align__(16) bf16_t Vs[3 * 4096];
  __shared__ __align__(16) bf16_t Plds[8][16 * 72];
  const int tid = threadIdx.x, lane = tid & 63, wave = tid >> 6;
  const int l15 = lane & 15, lg = lane >> 4;
  const int grp = blockIdx.x >> 1;
  const int b   = blockIdx.x & 1;
  const int pbase = 2040 - 8 * grp;
  const int p = pbase + wave;

  const bf16_t* qb_b = q   + (size_t)b * 32768 * 64;
  const bf16_t* ksb  = ksp + (size_t)b * 2048 * 64;
  const bf16_t* vtb  = vtp + (size_t)b * 64 * 2048;
  bf16_t*       ob   = o   + (size_t)b * 32768 * 64;
  bf16_t* Pl = &Plds[wave][0];

  const int srow = lane >> 3;
  const int scol = lane & 7;
  const int grow = wave * 8 + srow;
  const int gcol = scol ^ (grow & 7);
  const bf16_t* ksrc0 = ksb + (size_t)grow * 64 + gcol * 8;
  const bf16_t* vsrc0 = vtb + (size_t)grow * 2048 + gcol * 8;

  auto stageKV = [&](int t, int buf) {
    const int t0 = t * 64;
    gload_lds16(ksrc0 + (size_t)t0 * 64, Ks + buf * 4096 + wave * 512);
    gload_lds16(vsrc0 + t0, Vs + buf * 4096 + wave * 512);
  };

  s16x8 qf[2];
  {
    const bf16_t* qptr = qb_b + (size_t)(16 * p + l15) * 64;
    qf[0] = *(const s16x8*)(qptr + lg * 8);
    qf[1] = *(const s16x8*)(qptr + 32 + lg * 8);
  }

  float m_run = -1e30f, l_part = 0.f;
  f32x4 ao[4];
#pragma unroll
  for (int n = 0; n < 4; ++n) ao[n] = (f32x4){0.f, 0.f, 0.f, 0.f};

  const int nst = (pbase + 71) >> 6;
  stageKV(0, 0);
  if (nst > 1) stageKV(1, 1);
  int b0 = 0, b1 = 1, b2 = 2;
  for (int tt = 0; tt < nst; ++tt) {
    if (tt + 1 < nst) asm volatile("s_waitcnt vmcnt(2)" ::: "memory");
    else              asm volatile("s_waitcnt vmcnt(0)" ::: "memory");
    __builtin_amdgcn_s_barrier();
    if (tt + 2 < nst) stageKV(tt + 2, b2);
    const int t0 = tt * 64;
    if (t0 <= p) {
      const bf16_t* Kc = Ks + b0 * 4096;
      const bf16_t* Vc = Vs + b0 * 4096;
      if (t0 + 63 <= p)
        attn_tile<false>(t0, p, qf, Kc, Vc, Pl, l15, lg, m_run, l_part, ao);
      else
        attn_tile<true>(t0, p, qf, Kc, Vc, Pl, l15, lg, m_run, l_part, ao);
    }
    int tmp = b0; b0 = b1; b1 = b2; b2 = tmp;
  }

  float l2 = l_part + __shfl_xor(l_part, 16, 64);
  l2 += __shfl_xor(l2, 32, 64);
  float rl[4];
#pragma unroll
  for (int r = 0; r < 4; ++r) rl[r] = 1.0f / __shfl(l2, lg * 4 + r, 64);
#pragma unroll
  for (int n2 = 0; n2 < 4; ++n2) {
#pragma unroll
    for (int r = 0; r < 4; ++r) {
      const int row = 16 * p + lg * 4 + r;
      ob[(size_t)row * 64 + n2 * 16 + l15] = __float2bfloat16(ao[n2][r] * rl[r]);
    }
  }
}

// ---------------------------------------------------------------- launch
extern "C" void kernel_launch(void* const* d_in, const int* in_sizes, int n_in,
                              void* d_out, int out_size, void* d_ws, size_t ws_size,
                              hipStream_t stream) {
  (void)in_sizes; (void)n_in; (void)out_size; (void)ws_size;
  const float* hidden = (const float*)d_in[0];
  const float* Wqkv   = (const float*)d_in[1];
  const float* bqkv   = (const float*)d_in[2];
  const float* Wout   = (const float*)d_in[3];
  const float* bout   = (const float*)d_in[4];
  const float* g1     = (const float*)d_in[5];
  const float* b1     = (const float*)d_in[6];
  const float* g2     = (const float*)d_in[7];
  const float* b2     = (const float*)d_in[8];
  const float* W1     = (const float*)d_in[9];
  const float* bfc1   = (const float*)d_in[10];
  const float* W2     = (const float*)d_in[11];
  const float* bfc2   = (const float*)d_in[12];

  float* out_h   = (float*)d_out;
  float* out_res = out_h + (size_t)4096 * 1024;

  char* ws = (char*)d_ws;
  auto alloc = [&](size_t bytes) {
    char* p = ws;
    ws += (bytes + 255) & ~(size_t)255;
    return p;
  };
  bf16_t* X1      = (bf16_t*)alloc((size_t)4096 * 1024 * 2);
  bf16_t* Wqkv_bf = (bf16_t*)alloc((size_t)1152 * 1024 * 2);
  float*  bias_r  = (float*)alloc(1152 * 4);
  bf16_t* qb      = (bf16_t*)alloc((size_t)4096 * 1024 * 2);
  bf16_t* ksum    = (bf16_t*)alloc((size_t)2 * 2048 * 64 * 2);
  bf16_t* vT      = (bf16_t*)alloc((size_t)2 * 64 * 2048 * 2);
  bf16_t* Ob      = (bf16_t*)alloc((size_t)4096 * 1024 * 2);
  bf16_t* Wout_bf = (bf16_t*)alloc((size_t)1024 * 1024 * 2);
  bf16_t* X2      = (bf16_t*)alloc((size_t)4096 * 1024 * 2);
  bf16_t* W1_bf   = (bf16_t*)alloc((size_t)4096 * 1024 * 2);
  bf16_t* W2_bf   = (bf16_t*)alloc((size_t)1024 * 4096 * 2);
  bf16_t* H1      = (bf16_t*)alloc((size_t)4096 * 4096 * 2);
  bf16_t* fc2_part = (bf16_t*)d_ws;   // aliases dead X1..X2 region at FC2 time

  // weight prep
  cast_all_k<<<5120, 256, 0, stream>>>(Wqkv, Wout, W1, W2, Wqkv_bf, Wout_bf, W1_bf, W2_bf);
  reduce_kv_k<<<128, 256, 0, stream>>>(Wqkv, Wqkv_bf + (size_t)1024 * 1024);
  bias_prep_k<<<5, 256, 0, stream>>>(bqkv, bias_r);

  // LN1
  ln_cast_k<<<4096, 256, 0, stream>>>(hidden, g1, b1, X1);
  // QKV (reduced): M=4096, N=1152, K=1024
  gemm64<0><<<dim3(9, 64), 256, 0, stream>>>(X1, Wqkv_bf, bias_r, qb, nullptr, ksum, vT,
                                             4096, 1152, 1024);
  // attention (3-buffer pipelined staging)
  attn_k<<<512, 512, 0, stream>>>(qb, ksum, vT, Ob);
  // Wout + residual -> out_res (f32)
  gemm64<1><<<dim3(8, 64), 256, 0, stream>>>(Ob, Wout_bf, bout, out_res, hidden, nullptr,
                                             nullptr, 4096, 1024, 1024);
  // LN2
  ln_cast_k<<<4096, 256, 0, stream>>>(out_res, g2, b2, X2);
  // FC1 + tanh
  gemm256<2><<<dim3(16, 16), 512, 0, stream>>>(X2, W1_bf, bfc1, H1, 4096, 4096, 1024, 1024);
  // FC2 split-K=4 -> bf16 partials, combine + bias
  gemm256<4><<<dim3(4, 16, 4), 512, 0, stream>>>(H1, W2_bf, nullptr, fc2_part,
                                                 4096, 1024, 4096, 1024);
  fc2_reduce_k<<<2048, 256, 0, stream>>>(fc2_part, bfc2, out_h);
}